// Round 5
// baseline (696.211 us; speedup 1.0000x reference)
//
#include <hip/hip_runtime.h>

// Problem constants
#define N_NODES 100000
#define N_EDGES 1600000
#define EPAD    (N_EDGES + N_NODES)      // padded record capacity (even starts)
#define HDIM    64
#define NGRAPH  64
#define BLK_NODES 8
#define ALPHA_C 0.5f
#define BETA_C  0.5f
#define BW      256                      // bucket width (nodes); shift = 8
#define NB      391                      // ceil(N_NODES / BW)

// ---------------------------------------------------------------- histogram
__global__ __launch_bounds__(256) void hist_kernel(const int* __restrict__ ei,
                                                   int* __restrict__ deg_out,
                                                   int* __restrict__ deg_in) {
    int e = blockIdx.x * 256 + threadIdx.x;
    if (e < N_EDGES) {
        int r = ei[e];
        int c = ei[N_EDGES + e];
        atomicAdd(&deg_out[r], 1);
        atomicAdd(&deg_in[c], 1);
    }
}

// ------------------------------------------------------------------- rsqrt
__global__ __launch_bounds__(256) void rsq_kernel(const int* __restrict__ deg_out,
                                                  const int* __restrict__ deg_in,
                                                  float* __restrict__ r_out,
                                                  float* __restrict__ r_in) {
    int i = blockIdx.x * 256 + threadIdx.x;
    if (i < N_NODES) {
        int d0 = deg_out[i];
        int d1 = deg_in[i];
        r_out[i] = d0 > 0 ? 1.0f / sqrtf((float)d0) : 0.0f;
        r_in[i]  = d1 > 0 ? 1.0f / sqrtf((float)d1) : 0.0f;
    }
}

// --------------------------------------- block-level exclusive scan (padded degs)
// scans degP = deg + (deg&1) so every node's record run starts 16B-aligned
__global__ __launch_bounds__(1024) void scan_block(const int* __restrict__ deg0,
                                                   const int* __restrict__ deg1,
                                                   int* __restrict__ out0,
                                                   int* __restrict__ out1,
                                                   int* __restrict__ bsum0,
                                                   int* __restrict__ bsum1) {
    const int* deg = blockIdx.y ? deg1 : deg0;
    int* out  = blockIdx.y ? out1  : out0;
    int* bsum = blockIdx.y ? bsum1 : bsum0;

    __shared__ int s[1024];
    int tid = threadIdx.x;
    int i = blockIdx.x * 1024 + tid;
    int v = 0;
    if (i < N_NODES) { int d = deg[i]; v = d + (d & 1); }
    s[tid] = v;
    __syncthreads();
    for (int off = 1; off < 1024; off <<= 1) {
        int t = (tid >= off) ? s[tid - off] : 0;
        __syncthreads();
        s[tid] += t;
        __syncthreads();
    }
    if (i < N_NODES) out[i] = s[tid] - v;   // exclusive within block
    if (tid == 1023) bsum[blockIdx.x] = s[1023];
}

__global__ __launch_bounds__(128) void scan_bsums(int* __restrict__ bsum0,
                                                  int* __restrict__ bsum1,
                                                  int nb) {
    int* b = blockIdx.x ? bsum1 : bsum0;
    __shared__ int s[128];
    int tid = threadIdx.x;
    int v = (tid < nb) ? b[tid] : 0;
    s[tid] = v;
    __syncthreads();
    for (int off = 1; off < 128; off <<= 1) {
        int t = (tid >= off) ? s[tid - off] : 0;
        __syncthreads();
        s[tid] += t;
        __syncthreads();
    }
    if (tid < nb) b[tid] = s[tid] - v;      // exclusive
}

// also initializes per-bucket chunk allocators (cursors)
__global__ __launch_bounds__(256) void scan_add(int* __restrict__ out0,
                                                int* __restrict__ out1,
                                                const int* __restrict__ bsum0,
                                                const int* __restrict__ bsum1,
                                                int* __restrict__ curA,
                                                int* __restrict__ curT) {
    int i = blockIdx.x * 256 + threadIdx.x;
    if (i < N_NODES) {
        if (blockIdx.y == 0) {
            int v = out0[i] + bsum0[i >> 10];
            out0[i] = v;
            if ((i & (BW - 1)) == 0) curA[i >> 8] = v;
        } else {
            int v = out1[i] + bsum1[i >> 10];
            out1[i] = v;
            if ((i & (BW - 1)) == 0) curT[i >> 8] = v;
        }
    }
}

// --------------------------------------------------- phase 1: bucketize edges
// Per-bucket LDS histogram -> one global atomic per (block,bucket) reserves a
// contiguous chunk -> writes land in block-private chunks (merge in L2).
__global__ __launch_bounds__(512) void bucketize_kernel(const int* __restrict__ ei,
                                                        int* __restrict__ curA,
                                                        int* __restrict__ curT,
                                                        int2* __restrict__ bktA,
                                                        int2* __restrict__ bktT) {
    __shared__ int cntA[NB], cntT[NB], baseA[NB], baseT[NB];
    const int tid = threadIdx.x;
    const int CH = (N_EDGES + gridDim.x - 1) / gridDim.x;
    const int e0 = blockIdx.x * CH;
    const int e1 = min(e0 + CH, N_EDGES);

    for (int i = tid; i < NB; i += 512) { cntA[i] = 0; cntT[i] = 0; }
    __syncthreads();
    for (int e = e0 + tid; e < e1; e += 512) {
        int r = ei[e];
        int c = ei[N_EDGES + e];
        atomicAdd(&cntA[r >> 8], 1);
        atomicAdd(&cntT[c >> 8], 1);
    }
    __syncthreads();
    for (int b = tid; b < NB; b += 512) {
        baseA[b] = cntA[b] ? atomicAdd(&curA[b], cntA[b]) : 0;
        baseT[b] = cntT[b] ? atomicAdd(&curT[b], cntT[b]) : 0;
        cntA[b] = 0;
        cntT[b] = 0;
    }
    __syncthreads();
    for (int e = e0 + tid; e < e1; e += 512) {
        int r = ei[e];
        int c = ei[N_EDGES + e];
        int pA = baseA[r >> 8] + atomicAdd(&cntA[r >> 8], 1);
        bktA[pA] = make_int2(r, c);     // (target, source)
        int pT = baseT[c >> 8] + atomicAdd(&cntT[c >> 8], 1);
        bktT[pT] = make_int2(c, r);     // (target, source)
    }
}

// ------------------------------------- phase 2: within-bucket counting scatter
// One block per (bucket, dir). Cursors in LDS; computes per-edge norm weight
// (target scale from LDS, source scale from L2-resident r-array) and emits
// packed (src, w) records into the bucket's contiguous slice.
__global__ __launch_bounds__(512) void bucket_scatter_kernel(
        const int* __restrict__ rowptrP, const int* __restrict__ colptrP,
        const float* __restrict__ r_out, const float* __restrict__ r_in,
        const int* __restrict__ curFinA, const int* __restrict__ curFinT,
        const int2* __restrict__ bktA, const int2* __restrict__ bktT,
        int2* __restrict__ recA, int2* __restrict__ recT) {
    __shared__ int cur[BW];
    __shared__ float rwt[BW];
    const int b = blockIdx.x;
    const int dirT = blockIdx.y;
    const int* ptr = dirT ? colptrP : rowptrP;
    const float* rt = dirT ? r_in : r_out;    // target-side scale (bucket-local)
    const float* rs = dirT ? r_out : r_in;    // source-side scale (gathered)
    const int2* bkt = dirT ? bktT : bktA;
    int2* rec = dirT ? recT : recA;
    const int* curFin = dirT ? curFinT : curFinA;
    const int node0 = b * BW;
    const int tid = threadIdx.x;

    if (tid < BW) {
        int n = node0 + tid;
        cur[tid] = (n < N_NODES) ? ptr[n] : 0;
        rwt[tid] = (n < N_NODES) ? rt[n] : 0.0f;
    }
    __syncthreads();
    const int startb = ptr[node0];
    const int endb = curFin[b];               // padded start + actual count
    for (int i = startb + tid; i < endb; i += 512) {
        int2 e = bkt[i];
        float w = rwt[e.x - node0] * rs[e.y];
        int p = atomicAdd(&cur[e.x - node0], 1);
        rec[p] = make_int2(e.y, __float_as_int(w));
    }
}

// -------------------------------------------------------------- fused layer
__device__ __forceinline__ void fma4(float4& a, float w, const float4& f) {
    a.x = fmaf(w, f.x, a.x); a.y = fmaf(w, f.y, a.y);
    a.z = fmaf(w, f.z, a.z); a.w = fmaf(w, f.w, a.w);
}

__device__ __forceinline__ float4 red_s(float4 v) {
    v.x += __shfl_xor(v.x, 16); v.y += __shfl_xor(v.y, 16);
    v.z += __shfl_xor(v.z, 16); v.w += __shfl_xor(v.w, 16);
    v.x += __shfl_xor(v.x, 32); v.y += __shfl_xor(v.y, 32);
    v.z += __shfl_xor(v.z, 32); v.w += __shfl_xor(v.w, 32);
    return v;
}

// per-wave aggregation; lane (q,s): q = feature quad, s = edge-pair slot.
// records are (src, w) int2; node run starts are 16B-aligned (padded CSR) so
// each slot loads 2 records with one int4.
__device__ __forceinline__ float4 agg_dir(const float4* __restrict__ hv,
                                          const int2* __restrict__ rec,
                                          int start, int deg, int q, int s) {
    float4 a0 = {0.f,0.f,0.f,0.f}, a1 = {0.f,0.f,0.f,0.f};
    const int4* rec4 = (const int4*)(rec + start);
    int k = 0;
    for (; k + 8 <= deg; k += 8) {
        int4 p = rec4[(k >> 1) + s];          // records k+2s, k+2s+1
        float4 f0 = hv[(size_t)p.x * 16 + q];
        float4 f1 = hv[(size_t)p.z * 16 + q];
        fma4(a0, __int_as_float(p.y), f0);
        fma4(a1, __int_as_float(p.w), f1);
    }
    int r = deg - k;                          // 0..7 remaining
    if (2 * s < r) {
        int4 p = rec4[(k >> 1) + s];
        float4 f0 = hv[(size_t)p.x * 16 + q];
        fma4(a0, __int_as_float(p.y), f0);
        if (2 * s + 1 < r) {
            float4 f1 = hv[(size_t)p.z * 16 + q];
            fma4(a1, __int_as_float(p.w), f1);
        }
    }
    a0.x += a1.x; a0.y += a1.y; a0.z += a1.z; a0.w += a1.w;
    return red_s(a0);
}

__global__ __launch_bounds__(512, 8) void layer_kernel(
        const float* __restrict__ h_in, float* __restrict__ h_out,
        const int* __restrict__ rowptrP, const int* __restrict__ deg_out,
        const int2* __restrict__ recA,
        const int* __restrict__ colptrP, const int* __restrict__ deg_in,
        const int2* __restrict__ recT,
        const float* __restrict__ ws, const float* __restrict__ bs,
        const float* __restrict__ wd, const float* __restrict__ bd) {
    __shared__ float4 s_ws[HDIM * 16];                 // [k][q] 16KB
    __shared__ float4 s_wd[HDIM * 16];                 // 16KB
    __shared__ float4 s_accv[BLK_NODES][2][16];        // 4KB

    const int tid  = threadIdx.x;
    const int wave = tid >> 6;
    const int lane = tid & 63;
    const int q = lane & 15;
    const int s = lane >> 4;
    const int node = blockIdx.x * BLK_NODES + wave;

    // stage weights (1024 float4 each; 512 threads x 2)
    const float4* wsv = (const float4*)ws;
    const float4* wdv = (const float4*)wd;
    s_ws[tid] = wsv[tid]; s_ws[tid + 512] = wsv[tid + 512];
    s_wd[tid] = wdv[tid]; s_wd[tid + 512] = wdv[tid + 512];

    const float4* hv = (const float4*)h_in;

    float4 aA = agg_dir(hv, recA, rowptrP[node], deg_out[node], q, s);
    if (s == 0) s_accv[wave][0][q] = aA;
    float4 aT = agg_dir(hv, recT, colptrP[node], deg_in[node], q, s);
    if (s == 0) s_accv[wave][1][q] = aT;

    __syncthreads();

    // GEMM epilogue: thread -> feats 4q..4q+3 of its node, k in [16s, 16s+16)
    const float* accA = (const float*)&s_accv[wave][0][0];
    const float* accT = (const float*)&s_accv[wave][1][0];
    float4 oA = {0.f,0.f,0.f,0.f}, oT = {0.f,0.f,0.f,0.f};
    const int k0 = s * 16;
#pragma unroll
    for (int i = 0; i < 16; i++) {
        int k = k0 + i;
        float vA = accA[k];
        float vT = accT[k];
        float4 wA = s_ws[k * 16 + q];
        float4 wT = s_wd[k * 16 + q];
        fma4(oA, vA, wA);
        fma4(oT, vT, wT);
    }
    float4 o;
    o.x = ALPHA_C * oA.x + BETA_C * oT.x;
    o.y = ALPHA_C * oA.y + BETA_C * oT.y;
    o.z = ALPHA_C * oA.z + BETA_C * oT.z;
    o.w = ALPHA_C * oA.w + BETA_C * oT.w;
    o = red_s(o);
    if (s == 0) {
        float4 bA = ((const float4*)bs)[q];
        float4 bD = ((const float4*)bd)[q];
        o.x = fmaxf(o.x + ALPHA_C * bA.x + BETA_C * bD.x, 0.0f);
        o.y = fmaxf(o.y + ALPHA_C * bA.y + BETA_C * bD.y, 0.0f);
        o.z = fmaxf(o.z + ALPHA_C * bA.z + BETA_C * bD.z, 0.0f);
        o.w = fmaxf(o.w + ALPHA_C * bA.w + BETA_C * bD.w, 0.0f);
        ((float4*)h_out)[(size_t)node * 16 + q] = o;
    }
}

// ---------------------------------------------------------------- max pool
__global__ __launch_bounds__(256) void pool_kernel(const float* __restrict__ h,
                                                   const int* __restrict__ batch,
                                                   unsigned* __restrict__ g) {
    int t = blockIdx.x * 256 + threadIdx.x;
    const int ngroups = N_NODES / 16;   // 6250
    if (t >= ngroups * 64) return;
    int f = t & 63;
    int n0 = (t >> 6) * 16;
    int curg = batch[n0];
    float m = 0.0f;                      // post-ReLU values are >= 0
    for (int n = n0; n < n0 + 16; n++) {
        int b = batch[n];
        if (b != curg) {
            atomicMax(&g[curg * HDIM + f], __float_as_uint(m));
            curg = b;
            m = 0.0f;
        }
        m = fmaxf(m, h[n * HDIM + f]);
    }
    atomicMax(&g[curg * HDIM + f], __float_as_uint(m));
}

// -------------------------------------------------------------------- MLP head
__global__ __launch_bounds__(64) void mlp_kernel(const unsigned* __restrict__ g,
                                                 const float* __restrict__ wl1,
                                                 const float* __restrict__ bl1,
                                                 const float* __restrict__ wl2,
                                                 const float* __restrict__ bl2,
                                                 float* __restrict__ out) {
    int t = threadIdx.x;   // graph index, one block of 64
    float gv[HDIM];
#pragma unroll
    for (int k = 0; k < HDIM; k++) gv[k] = __uint_as_float(g[t * HDIM + k]);
    float o = bl2[0];
#pragma unroll
    for (int j = 0; j < 5; j++) {
        float hj = bl1[j];
#pragma unroll
        for (int k = 0; k < HDIM; k++) hj += gv[k] * wl1[k * 5 + j];
        hj = fmaxf(hj, 0.0f);
        o += hj * wl2[j];
    }
    out[t] = o;
}

// ------------------------------------------------------------------- launch
extern "C" void kernel_launch(void* const* d_in, const int* in_sizes, int n_in,
                              void* d_out, int out_size, void* d_ws, size_t ws_size,
                              hipStream_t stream) {
    const float* x   = (const float*)d_in[0];
    const int*   ei  = (const int*)d_in[1];
    const int*   bat = (const int*)d_in[2];
    const float* w1s = (const float*)d_in[3];
    const float* b1s = (const float*)d_in[4];
    const float* w1d = (const float*)d_in[5];
    const float* b1d = (const float*)d_in[6];
    const float* w2s = (const float*)d_in[7];
    const float* b2s = (const float*)d_in[8];
    const float* w2d = (const float*)d_in[9];
    const float* b2d = (const float*)d_in[10];
    const float* w3s = (const float*)d_in[11];
    const float* b3s = (const float*)d_in[12];
    const float* w3d = (const float*)d_in[13];
    const float* b3d = (const float*)d_in[14];
    const float* wl1 = (const float*)d_in[15];
    const float* bl1 = (const float*)d_in[16];
    const float* wl2 = (const float*)d_in[17];
    const float* bl2 = (const float*)d_in[18];
    float* out = (float*)d_out;

    // Workspace carve-up (16B-aligned chunks). bktA/bktT alias hA: buckets are
    // dead before the first layer_kernel writes hA.
    char* p = (char*)d_ws;
    int*   deg_out = (int*)p;              p += N_NODES * 4;
    int*   deg_in  = (int*)p;              p += N_NODES * 4;
    int*   rowptrP = (int*)p;              p += N_NODES * 4;
    int*   colptrP = (int*)p;              p += N_NODES * 4;
    float* r_out   = (float*)p;            p += N_NODES * 4;
    float* r_in    = (float*)p;            p += N_NODES * 4;
    int*   curA    = (int*)p;              p += 512 * 4;
    int*   curT    = (int*)p;              p += 512 * 4;
    int2*  recA    = (int2*)p;             p += (size_t)EPAD * 8;
    int2*  recT    = (int2*)p;             p += (size_t)EPAD * 8;
    int2*  bktA    = (int2*)p;             // aliased with hA
    float* hA      = (float*)p;
    int2*  bktT    = (int2*)((char*)bktA + (size_t)EPAD * 8);
    p = (char*)bktA + 2 * (size_t)EPAD * 8;   // 27.2MB covers hA's 25.6MB
    float* hB      = (float*)p;            p += (size_t)N_NODES * HDIM * 4;
    unsigned* g    = (unsigned*)p;         p += NGRAPH * HDIM * 4;
    int*   bsum0   = (int*)p;              p += 512;
    int*   bsum1   = (int*)p;              p += 512;

    const int nb = (N_NODES + 1023) / 1024;   // 98 scan blocks

    hipMemsetAsync(deg_out, 0, 2 * N_NODES * 4, stream);
    hipMemsetAsync(g, 0, NGRAPH * HDIM * 4, stream);

    hist_kernel<<<(N_EDGES + 255) / 256, 256, 0, stream>>>(ei, deg_out, deg_in);
    rsq_kernel<<<(N_NODES + 255) / 256, 256, 0, stream>>>(deg_out, deg_in, r_out, r_in);

    dim3 gs(nb, 2);
    scan_block<<<gs, 1024, 0, stream>>>(deg_out, deg_in, rowptrP, colptrP, bsum0, bsum1);
    scan_bsums<<<2, 128, 0, stream>>>(bsum0, bsum1, nb);
    dim3 ga((N_NODES + 255) / 256, 2);
    scan_add<<<ga, 256, 0, stream>>>(rowptrP, colptrP, bsum0, bsum1, curA, curT);

    bucketize_kernel<<<256, 512, 0, stream>>>(ei, curA, curT, bktA, bktT);
    dim3 gb(NB, 2);
    bucket_scatter_kernel<<<gb, 512, 0, stream>>>(
        rowptrP, colptrP, r_out, r_in, curA, curT, bktA, bktT, recA, recT);

    // Three fused conv layers: x -> hA -> hB -> hA
    layer_kernel<<<N_NODES / BLK_NODES, 512, 0, stream>>>(
        x, hA, rowptrP, deg_out, recA, colptrP, deg_in, recT, w1s, b1s, w1d, b1d);
    layer_kernel<<<N_NODES / BLK_NODES, 512, 0, stream>>>(
        hA, hB, rowptrP, deg_out, recA, colptrP, deg_in, recT, w2s, b2s, w2d, b2d);
    layer_kernel<<<N_NODES / BLK_NODES, 512, 0, stream>>>(
        hB, hA, rowptrP, deg_out, recA, colptrP, deg_in, recT, w3s, b3s, w3d, b3d);

    const int pool_threads = (N_NODES / 16) * 64;   // 400000
    pool_kernel<<<(pool_threads + 255) / 256, 256, 0, stream>>>(hA, bat, g);

    mlp_kernel<<<1, 64, 0, stream>>>(g, wl1, bl1, wl2, bl2, out);
}

// Round 6
// 688.424 us; speedup vs baseline: 1.0113x; 1.0113x over previous
//
#include <hip/hip_runtime.h>

// Problem constants
#define N_NODES 100000
#define N_EDGES 1600000
#define EPAD    (N_EDGES + N_NODES)      // padded record capacity (even starts)
#define HDIM    64
#define NGRAPH  64
#define BLK_NODES 8
#define ALPHA_C 0.5f
#define BETA_C  0.5f
#define BW      256                      // bucket width (nodes); shift = 8
#define NB      391                      // ceil(N_NODES / BW)
#define NBLK    256                      // edge-pass blocks
#define CHUNK   ((N_EDGES + NBLK - 1) / NBLK)

// ----------------------------------------- K1: per-(block,bucket) edge counts
__global__ __launch_bounds__(512) void bucket_count(const int* __restrict__ ei,
                                                    int* __restrict__ cntTabA,
                                                    int* __restrict__ cntTabT) {
    __shared__ int cA[NB], cT[NB];
    const int tid = threadIdx.x;
    for (int i = tid; i < NB; i += 512) { cA[i] = 0; cT[i] = 0; }
    __syncthreads();
    const int e0 = blockIdx.x * CHUNK, e1 = min(e0 + CHUNK, N_EDGES);
    for (int e = e0 + tid; e < e1; e += 512) {
        int r = ei[e];
        int c = ei[N_EDGES + e];
        atomicAdd(&cA[r >> 8], 1);
        atomicAdd(&cT[c >> 8], 1);
    }
    __syncthreads();
    for (int b = tid; b < NB; b += 512) {
        cntTabA[b * NBLK + blockIdx.x] = cA[b];
        cntTabT[b * NBLK + blockIdx.x] = cT[b];
    }
}

// ---------------- K2: bucket totals, bucket starts, per-(block,bucket) bases
__global__ __launch_bounds__(512) void bucket_prefix(int* __restrict__ cntTabA,
                                                     int* __restrict__ cntTabT,
                                                     int* __restrict__ bktStartA,
                                                     int* __restrict__ bktStartT) {
    __shared__ int totA[NB], totT[NB], stA[NB], stT[NB];
    const int tid = threadIdx.x;
    if (tid < NB) {
        int sA = 0, sT = 0;
        for (int i = 0; i < NBLK; i++) {
            sA += cntTabA[tid * NBLK + i];
            sT += cntTabT[tid * NBLK + i];
        }
        totA[tid] = sA; totT[tid] = sT;
    }
    __syncthreads();
    if (tid == 0) { int run = 0; for (int b = 0; b < NB; b++) { stA[b] = run; run += totA[b]; } }
    if (tid == 1) { int run = 0; for (int b = 0; b < NB; b++) { stT[b] = run; run += totT[b]; } }
    __syncthreads();
    if (tid < NB) {
        bktStartA[tid] = stA[tid];
        bktStartT[tid] = stT[tid];
        if (tid == 0) { bktStartA[NB] = N_EDGES; bktStartT[NB] = N_EDGES; }
        int run = stA[tid];
        for (int i = 0; i < NBLK; i++) {
            int t = cntTabA[tid * NBLK + i]; cntTabA[tid * NBLK + i] = run; run += t;
        }
        run = stT[tid];
        for (int i = 0; i < NBLK; i++) {
            int t = cntTabT[tid * NBLK + i]; cntTabT[tid * NBLK + i] = run; run += t;
        }
    }
}

// --------------------------- K3: bucketize write (bases pre-reserved, no global atomics)
__global__ __launch_bounds__(512) void bucketize_write(const int* __restrict__ ei,
                                                       const int* __restrict__ cntTabA,
                                                       const int* __restrict__ cntTabT,
                                                       int2* __restrict__ bktA,
                                                       int2* __restrict__ bktT) {
    __shared__ int bA[NB], bT[NB];
    const int tid = threadIdx.x;
    for (int i = tid; i < NB; i += 512) {
        bA[i] = cntTabA[i * NBLK + blockIdx.x];
        bT[i] = cntTabT[i * NBLK + blockIdx.x];
    }
    __syncthreads();
    const int e0 = blockIdx.x * CHUNK, e1 = min(e0 + CHUNK, N_EDGES);
    for (int e = e0 + tid; e < e1; e += 512) {
        int r = ei[e];
        int c = ei[N_EDGES + e];
        int pA = atomicAdd(&bA[r >> 8], 1);
        bktA[pA] = make_int2(r, c);          // (target, source)
        int pT = atomicAdd(&bT[c >> 8], 1);
        bktT[pT] = make_int2(c, r);          // (target, source)
    }
}

// ------------------- K4: per-bucket degrees + rsqrt norms + padded-size reduce
__global__ __launch_bounds__(256) void bucket_deg(const int* __restrict__ bktStartA,
                                                  const int* __restrict__ bktStartT,
                                                  const int2* __restrict__ bktA,
                                                  const int2* __restrict__ bktT,
                                                  int* __restrict__ deg_out,
                                                  int* __restrict__ deg_in,
                                                  float* __restrict__ r_out,
                                                  float* __restrict__ r_in,
                                                  int* __restrict__ padSum) {
    __shared__ int c[BW];
    __shared__ int red[256];
    const int b = blockIdx.x, d = blockIdx.y, tid = threadIdx.x;
    const int* bs = d ? bktStartT : bktStartA;
    const int2* bkt = d ? bktT : bktA;
    int* deg = d ? deg_in : deg_out;
    float* rr = d ? r_in : r_out;
    const int node0 = b * BW;
    c[tid] = 0;
    __syncthreads();
    const int i0 = bs[b], i1 = bs[b + 1];
    for (int i = i0 + tid; i < i1; i += 256) atomicAdd(&c[bkt[i].x - node0], 1);
    __syncthreads();
    int n = node0 + tid, dg = c[tid], pad = 0;
    if (n < N_NODES) {
        deg[n] = dg;
        rr[n] = dg > 0 ? rsqrtf((float)dg) : 0.0f;
        pad = dg + (dg & 1);
    }
    red[tid] = pad;
    __syncthreads();
    for (int off = 128; off > 0; off >>= 1) {
        if (tid < off) red[tid] += red[tid + off];
        __syncthreads();
    }
    if (tid == 0) padSum[d * 512 + b] = red[0];
}

// --------------------------------------- K5: padded bucket-start prefix (tiny)
__global__ __launch_bounds__(64) void pad_prefix(const int* __restrict__ padSum,
                                                 int* __restrict__ padStart) {
    if (threadIdx.x == 0) {
        int run = 0;
        for (int b = 0; b < NB; b++) { padStart[b] = run; run += padSum[b]; }
    }
    if (threadIdx.x == 1) {
        int run = 0;
        for (int b = 0; b < NB; b++) { padStart[512 + b] = run; run += padSum[512 + b]; }
    }
}

// ----------------------- K6: per-node padded CSR offsets (per-bucket LDS scan)
__global__ __launch_bounds__(256) void node_ptr(const int* __restrict__ padStart,
                                                const int* __restrict__ deg_out,
                                                const int* __restrict__ deg_in,
                                                int* __restrict__ rowptrP,
                                                int* __restrict__ colptrP) {
    __shared__ int s[256];
    const int b = blockIdx.x, d = blockIdx.y, tid = threadIdx.x;
    const int* deg = d ? deg_in : deg_out;
    int* ptr = d ? colptrP : rowptrP;
    int n = b * BW + tid;
    int pad = 0;
    if (n < N_NODES) { int dg = deg[n]; pad = dg + (dg & 1); }
    s[tid] = pad;
    __syncthreads();
    for (int off = 1; off < 256; off <<= 1) {
        int t = (tid >= off) ? s[tid - off] : 0;
        __syncthreads();
        s[tid] += t;
        __syncthreads();
    }
    if (n < N_NODES) ptr[n] = padStart[d * 512 + b] + s[tid] - pad;
}

// ------------------------------------- K7: within-bucket counting scatter
// Cursors in LDS; computes per-edge norm weight (target scale from LDS,
// source scale from L2-resident r-array) and emits packed (src, w) records.
__global__ __launch_bounds__(512) void bucket_scatter(
        const int* __restrict__ rowptrP, const int* __restrict__ colptrP,
        const float* __restrict__ r_out, const float* __restrict__ r_in,
        const int* __restrict__ bktStartA, const int* __restrict__ bktStartT,
        const int2* __restrict__ bktA, const int2* __restrict__ bktT,
        int2* __restrict__ recA, int2* __restrict__ recT) {
    __shared__ int cur[BW];
    __shared__ float rwt[BW];
    const int b = blockIdx.x, d = blockIdx.y, tid = threadIdx.x;
    const int* ptr = d ? colptrP : rowptrP;
    const float* rt = d ? r_in : r_out;       // target-side scale (bucket-local)
    const float* rs = d ? r_out : r_in;       // source-side scale (gathered)
    const int* bs = d ? bktStartT : bktStartA;
    const int2* bkt = d ? bktT : bktA;
    int2* rec = d ? recT : recA;
    const int node0 = b * BW;
    if (tid < BW) {
        int n = node0 + tid;
        cur[tid] = (n < N_NODES) ? ptr[n] : 0;
        rwt[tid] = (n < N_NODES) ? rt[n] : 0.0f;
    }
    __syncthreads();
    const int i0 = bs[b], i1 = bs[b + 1];
    for (int i = i0 + tid; i < i1; i += 512) {
        int2 e = bkt[i];
        float w = rwt[e.x - node0] * rs[e.y];
        int p = atomicAdd(&cur[e.x - node0], 1);
        rec[p] = make_int2(e.y, __float_as_int(w));
    }
}

// -------------------------------------------------------------- fused layer
__device__ __forceinline__ void fma4(float4& a, float w, const float4& f) {
    a.x = fmaf(w, f.x, a.x); a.y = fmaf(w, f.y, a.y);
    a.z = fmaf(w, f.z, a.z); a.w = fmaf(w, f.w, a.w);
}

__device__ __forceinline__ float4 red_s(float4 v) {
    v.x += __shfl_xor(v.x, 16); v.y += __shfl_xor(v.y, 16);
    v.z += __shfl_xor(v.z, 16); v.w += __shfl_xor(v.w, 16);
    v.x += __shfl_xor(v.x, 32); v.y += __shfl_xor(v.y, 32);
    v.z += __shfl_xor(v.z, 32); v.w += __shfl_xor(v.w, 32);
    return v;
}

// per-wave aggregation; lane (q,s): q = feature quad, s = edge-pair slot.
// records are (src, w) int2; node run starts are 16B-aligned (padded CSR) so
// each slot loads 2 records with one int4.
__device__ __forceinline__ float4 agg_dir(const float4* __restrict__ hv,
                                          const int2* __restrict__ rec,
                                          int start, int deg, int q, int s) {
    float4 a0 = {0.f,0.f,0.f,0.f}, a1 = {0.f,0.f,0.f,0.f};
    const int4* rec4 = (const int4*)(rec + start);
    int k = 0;
    for (; k + 8 <= deg; k += 8) {
        int4 p = rec4[(k >> 1) + s];          // records k+2s, k+2s+1
        float4 f0 = hv[(size_t)p.x * 16 + q];
        float4 f1 = hv[(size_t)p.z * 16 + q];
        fma4(a0, __int_as_float(p.y), f0);
        fma4(a1, __int_as_float(p.w), f1);
    }
    int r = deg - k;                          // 0..7 remaining
    if (2 * s < r) {
        int4 p = rec4[(k >> 1) + s];
        float4 f0 = hv[(size_t)p.x * 16 + q];
        fma4(a0, __int_as_float(p.y), f0);
        if (2 * s + 1 < r) {
            float4 f1 = hv[(size_t)p.z * 16 + q];
            fma4(a1, __int_as_float(p.w), f1);
        }
    }
    a0.x += a1.x; a0.y += a1.y; a0.z += a1.z; a0.w += a1.w;
    return red_s(a0);
}

__global__ __launch_bounds__(512, 8) void layer_kernel(
        const float* __restrict__ h_in, float* __restrict__ h_out,
        const int* __restrict__ rowptrP, const int* __restrict__ deg_out,
        const int2* __restrict__ recA,
        const int* __restrict__ colptrP, const int* __restrict__ deg_in,
        const int2* __restrict__ recT,
        const float* __restrict__ ws, const float* __restrict__ bs,
        const float* __restrict__ wd, const float* __restrict__ bd) {
    __shared__ float4 s_ws[HDIM * 16];                 // [k][q] 16KB
    __shared__ float4 s_wd[HDIM * 16];                 // 16KB
    __shared__ float4 s_accv[BLK_NODES][2][16];        // 4KB

    const int tid  = threadIdx.x;
    const int wave = tid >> 6;
    const int lane = tid & 63;
    const int q = lane & 15;
    const int s = lane >> 4;
    const int node = blockIdx.x * BLK_NODES + wave;

    // stage weights (1024 float4 each; 512 threads x 2)
    const float4* wsv = (const float4*)ws;
    const float4* wdv = (const float4*)wd;
    s_ws[tid] = wsv[tid]; s_ws[tid + 512] = wsv[tid + 512];
    s_wd[tid] = wdv[tid]; s_wd[tid + 512] = wdv[tid + 512];

    const float4* hv = (const float4*)h_in;

    float4 aA = agg_dir(hv, recA, rowptrP[node], deg_out[node], q, s);
    if (s == 0) s_accv[wave][0][q] = aA;
    float4 aT = agg_dir(hv, recT, colptrP[node], deg_in[node], q, s);
    if (s == 0) s_accv[wave][1][q] = aT;

    __syncthreads();

    // GEMM epilogue: thread -> feats 4q..4q+3 of its node, k in [16s, 16s+16)
    const float* accA = (const float*)&s_accv[wave][0][0];
    const float* accT = (const float*)&s_accv[wave][1][0];
    float4 oA = {0.f,0.f,0.f,0.f}, oT = {0.f,0.f,0.f,0.f};
    const int k0 = s * 16;
#pragma unroll
    for (int i = 0; i < 16; i++) {
        int k = k0 + i;
        float vA = accA[k];
        float vT = accT[k];
        float4 wA = s_ws[k * 16 + q];
        float4 wT = s_wd[k * 16 + q];
        fma4(oA, vA, wA);
        fma4(oT, vT, wT);
    }
    float4 o;
    o.x = ALPHA_C * oA.x + BETA_C * oT.x;
    o.y = ALPHA_C * oA.y + BETA_C * oT.y;
    o.z = ALPHA_C * oA.z + BETA_C * oT.z;
    o.w = ALPHA_C * oA.w + BETA_C * oT.w;
    o = red_s(o);
    if (s == 0) {
        float4 bA = ((const float4*)bs)[q];
        float4 bD = ((const float4*)bd)[q];
        o.x = fmaxf(o.x + ALPHA_C * bA.x + BETA_C * bD.x, 0.0f);
        o.y = fmaxf(o.y + ALPHA_C * bA.y + BETA_C * bD.y, 0.0f);
        o.z = fmaxf(o.z + ALPHA_C * bA.z + BETA_C * bD.z, 0.0f);
        o.w = fmaxf(o.w + ALPHA_C * bA.w + BETA_C * bD.w, 0.0f);
        ((float4*)h_out)[(size_t)node * 16 + q] = o;
    }
}

// ---------------------------------------------------------------- max pool
__global__ __launch_bounds__(256) void pool_kernel(const float* __restrict__ h,
                                                   const int* __restrict__ batch,
                                                   unsigned* __restrict__ g) {
    int t = blockIdx.x * 256 + threadIdx.x;
    const int ngroups = N_NODES / 16;   // 6250
    if (t >= ngroups * 64) return;
    int f = t & 63;
    int n0 = (t >> 6) * 16;
    int curg = batch[n0];
    float m = 0.0f;                      // post-ReLU values are >= 0
    for (int n = n0; n < n0 + 16; n++) {
        int b = batch[n];
        if (b != curg) {
            atomicMax(&g[curg * HDIM + f], __float_as_uint(m));
            curg = b;
            m = 0.0f;
        }
        m = fmaxf(m, h[n * HDIM + f]);
    }
    atomicMax(&g[curg * HDIM + f], __float_as_uint(m));
}

// -------------------------------------------------------------------- MLP head
__global__ __launch_bounds__(64) void mlp_kernel(const unsigned* __restrict__ g,
                                                 const float* __restrict__ wl1,
                                                 const float* __restrict__ bl1,
                                                 const float* __restrict__ wl2,
                                                 const float* __restrict__ bl2,
                                                 float* __restrict__ out) {
    int t = threadIdx.x;   // graph index, one block of 64
    float gv[HDIM];
#pragma unroll
    for (int k = 0; k < HDIM; k++) gv[k] = __uint_as_float(g[t * HDIM + k]);
    float o = bl2[0];
#pragma unroll
    for (int j = 0; j < 5; j++) {
        float hj = bl1[j];
#pragma unroll
        for (int k = 0; k < HDIM; k++) hj += gv[k] * wl1[k * 5 + j];
        hj = fmaxf(hj, 0.0f);
        o += hj * wl2[j];
    }
    out[t] = o;
}

// ------------------------------------------------------------------- launch
extern "C" void kernel_launch(void* const* d_in, const int* in_sizes, int n_in,
                              void* d_out, int out_size, void* d_ws, size_t ws_size,
                              hipStream_t stream) {
    const float* x   = (const float*)d_in[0];
    const int*   ei  = (const int*)d_in[1];
    const int*   bat = (const int*)d_in[2];
    const float* w1s = (const float*)d_in[3];
    const float* b1s = (const float*)d_in[4];
    const float* w1d = (const float*)d_in[5];
    const float* b1d = (const float*)d_in[6];
    const float* w2s = (const float*)d_in[7];
    const float* b2s = (const float*)d_in[8];
    const float* w2d = (const float*)d_in[9];
    const float* b2d = (const float*)d_in[10];
    const float* w3s = (const float*)d_in[11];
    const float* b3s = (const float*)d_in[12];
    const float* w3d = (const float*)d_in[13];
    const float* b3d = (const float*)d_in[14];
    const float* wl1 = (const float*)d_in[15];
    const float* bl1 = (const float*)d_in[16];
    const float* wl2 = (const float*)d_in[17];
    const float* bl2 = (const float*)d_in[18];
    float* out = (float*)d_out;

    // Workspace carve-up (16B-aligned chunks). bktA/bktT alias hA: buckets are
    // dead before the first layer_kernel writes hA.
    char* p = (char*)d_ws;
    int*   deg_out = (int*)p;              p += N_NODES * 4;
    int*   deg_in  = (int*)p;              p += N_NODES * 4;
    int*   rowptrP = (int*)p;              p += N_NODES * 4;
    int*   colptrP = (int*)p;              p += N_NODES * 4;
    float* r_out   = (float*)p;            p += N_NODES * 4;
    float* r_in    = (float*)p;            p += N_NODES * 4;
    int*   cntTabA = (int*)p;              p += (size_t)NB * NBLK * 4;
    int*   cntTabT = (int*)p;              p += (size_t)NB * NBLK * 4;
    int*   bktStartA = (int*)p;            p += 512 * 4;
    int*   bktStartT = (int*)p;            p += 512 * 4;
    int*   padSum  = (int*)p;              p += 1024 * 4;
    int*   padStart = (int*)p;             p += 1024 * 4;
    int2*  recA    = (int2*)p;             p += (size_t)EPAD * 8;
    int2*  recT    = (int2*)p;             p += (size_t)EPAD * 8;
    int2*  bktA    = (int2*)p;             // aliased with hA
    float* hA      = (float*)p;
    int2*  bktT    = (int2*)((char*)bktA + (size_t)N_EDGES * 8);
    p = (char*)bktA + 2 * (size_t)N_EDGES * 8;   // == 25.6MB == hA size
    float* hB      = (float*)p;            p += (size_t)N_NODES * HDIM * 4;
    unsigned* g    = (unsigned*)p;         p += NGRAPH * HDIM * 4;

    hipMemsetAsync(g, 0, NGRAPH * HDIM * 4, stream);

    bucket_count<<<NBLK, 512, 0, stream>>>(ei, cntTabA, cntTabT);
    bucket_prefix<<<1, 512, 0, stream>>>(cntTabA, cntTabT, bktStartA, bktStartT);
    bucketize_write<<<NBLK, 512, 0, stream>>>(ei, cntTabA, cntTabT, bktA, bktT);

    dim3 gb(NB, 2);
    bucket_deg<<<gb, 256, 0, stream>>>(bktStartA, bktStartT, bktA, bktT,
                                       deg_out, deg_in, r_out, r_in, padSum);
    pad_prefix<<<1, 64, 0, stream>>>(padSum, padStart);
    node_ptr<<<gb, 256, 0, stream>>>(padStart, deg_out, deg_in, rowptrP, colptrP);
    bucket_scatter<<<gb, 512, 0, stream>>>(
        rowptrP, colptrP, r_out, r_in, bktStartA, bktStartT, bktA, bktT, recA, recT);

    // Three fused conv layers: x -> hA -> hB -> hA
    layer_kernel<<<N_NODES / BLK_NODES, 512, 0, stream>>>(
        x, hA, rowptrP, deg_out, recA, colptrP, deg_in, recT, w1s, b1s, w1d, b1d);
    layer_kernel<<<N_NODES / BLK_NODES, 512, 0, stream>>>(
        hA, hB, rowptrP, deg_out, recA, colptrP, deg_in, recT, w2s, b2s, w2d, b2d);
    layer_kernel<<<N_NODES / BLK_NODES, 512, 0, stream>>>(
        hB, hA, rowptrP, deg_out, recA, colptrP, deg_in, recT, w3s, b3s, w3d, b3d);

    const int pool_threads = (N_NODES / 16) * 64;   // 400000
    pool_kernel<<<(pool_threads + 255) / 256, 256, 0, stream>>>(hA, bat, g);

    mlp_kernel<<<1, 64, 0, stream>>>(g, wl1, bl1, wl2, bl2, out);
}

// Round 7
// 581.462 us; speedup vs baseline: 1.1973x; 1.1840x over previous
//
#include <hip/hip_runtime.h>

// Problem constants
#define N_NODES 100000
#define N_EDGES 1600000
#define EPAD    (N_EDGES + N_NODES)      // padded record capacity (even starts)
#define HDIM    64
#define NGRAPH  64
#define BLK_NODES 8
#define ALPHA_C 0.5f
#define BETA_C  0.5f
#define BW      256                      // bucket width (nodes); shift = 8
#define NB      391                      // ceil(N_NODES / BW)
#define NBLK    256                      // edge-pass blocks
#define CHUNK   ((N_EDGES + NBLK - 1) / NBLK)

// ----------------------------------------- K1: per-(block,bucket) edge counts
__global__ __launch_bounds__(512) void bucket_count(const int* __restrict__ ei,
                                                    int* __restrict__ cntTabA,
                                                    int* __restrict__ cntTabT) {
    __shared__ int cA[NB], cT[NB];
    const int tid = threadIdx.x;
    for (int i = tid; i < NB; i += 512) { cA[i] = 0; cT[i] = 0; }
    __syncthreads();
    const int e0 = blockIdx.x * CHUNK, e1 = min(e0 + CHUNK, N_EDGES);
    for (int e = e0 + tid; e < e1; e += 512) {
        int r = ei[e];
        int c = ei[N_EDGES + e];
        atomicAdd(&cA[r >> 8], 1);
        atomicAdd(&cT[c >> 8], 1);
    }
    __syncthreads();
    for (int b = tid; b < NB; b += 512) {
        cntTabA[b * NBLK + blockIdx.x] = cA[b];
        cntTabT[b * NBLK + blockIdx.x] = cT[b];
    }
}

// ---------------- K2a: per-bucket LDS scan of the 256 per-block counts
// cntTab[b][*] -> exclusive relative bases (in place); tot[d*512+b] = total
__global__ __launch_bounds__(256) void chunk_scan(int* __restrict__ cntTabA,
                                                  int* __restrict__ cntTabT,
                                                  int* __restrict__ tot) {
    __shared__ int s[256];
    const int b = blockIdx.x, d = blockIdx.y, tid = threadIdx.x;
    int* tab = d ? cntTabT : cntTabA;
    int v = tab[b * NBLK + tid];
    s[tid] = v;
    __syncthreads();
    for (int off = 1; off < 256; off <<= 1) {
        int t = (tid >= off) ? s[tid - off] : 0;
        __syncthreads();
        s[tid] += t;
        __syncthreads();
    }
    tab[b * NBLK + tid] = s[tid] - v;       // exclusive within bucket
    if (tid == 255) tot[d * 512 + b] = s[255];
}

// ---------------- K2b: bucket-start scan (both dirs, one block, parallel)
__global__ __launch_bounds__(512) void start_scan(const int* __restrict__ tot,
                                                  int* __restrict__ bktStartA,
                                                  int* __restrict__ bktStartT) {
    __shared__ int s[512];
    const int tid = threadIdx.x;
    int v = (tid < NB) ? tot[tid] : 0;
    s[tid] = v;
    __syncthreads();
    for (int off = 1; off < 512; off <<= 1) {
        int t = (tid >= off) ? s[tid - off] : 0;
        __syncthreads();
        s[tid] += t;
        __syncthreads();
    }
    if (tid < NB) bktStartA[tid] = s[tid] - v;
    if (tid == 0) bktStartA[NB] = N_EDGES;
    __syncthreads();
    int v2 = (tid < NB) ? tot[512 + tid] : 0;
    s[tid] = v2;
    __syncthreads();
    for (int off = 1; off < 512; off <<= 1) {
        int t = (tid >= off) ? s[tid - off] : 0;
        __syncthreads();
        s[tid] += t;
        __syncthreads();
    }
    if (tid < NB) bktStartT[tid] = s[tid] - v2;
    if (tid == 0) bktStartT[NB] = N_EDGES;
}

// --------------------------- K3: bucketize write (bases pre-reserved)
__global__ __launch_bounds__(512) void bucketize_write(const int* __restrict__ ei,
                                                       const int* __restrict__ cntTabA,
                                                       const int* __restrict__ cntTabT,
                                                       const int* __restrict__ bktStartA,
                                                       const int* __restrict__ bktStartT,
                                                       int2* __restrict__ bktA,
                                                       int2* __restrict__ bktT) {
    __shared__ int bA[NB], bT[NB];
    const int tid = threadIdx.x;
    for (int i = tid; i < NB; i += 512) {
        bA[i] = bktStartA[i] + cntTabA[i * NBLK + blockIdx.x];
        bT[i] = bktStartT[i] + cntTabT[i * NBLK + blockIdx.x];
    }
    __syncthreads();
    const int e0 = blockIdx.x * CHUNK, e1 = min(e0 + CHUNK, N_EDGES);
    for (int e = e0 + tid; e < e1; e += 512) {
        int r = ei[e];
        int c = ei[N_EDGES + e];
        int pA = atomicAdd(&bA[r >> 8], 1);
        bktA[pA] = make_int2(r, c);          // (target, source)
        int pT = atomicAdd(&bT[c >> 8], 1);
        bktT[pT] = make_int2(c, r);          // (target, source)
    }
}

// ------------------- K4: per-bucket degrees + rsqrt norms + padded-size reduce
__global__ __launch_bounds__(256) void bucket_deg(const int* __restrict__ bktStartA,
                                                  const int* __restrict__ bktStartT,
                                                  const int2* __restrict__ bktA,
                                                  const int2* __restrict__ bktT,
                                                  int* __restrict__ deg_out,
                                                  int* __restrict__ deg_in,
                                                  float* __restrict__ r_out,
                                                  float* __restrict__ r_in,
                                                  int* __restrict__ padSum) {
    __shared__ int c[BW];
    __shared__ int red[256];
    const int b = blockIdx.x, d = blockIdx.y, tid = threadIdx.x;
    const int* bs = d ? bktStartT : bktStartA;
    const int2* bkt = d ? bktT : bktA;
    int* deg = d ? deg_in : deg_out;
    float* rr = d ? r_in : r_out;
    const int node0 = b * BW;
    c[tid] = 0;
    __syncthreads();
    const int i0 = bs[b], i1 = bs[b + 1];
    for (int i = i0 + tid; i < i1; i += 256) atomicAdd(&c[bkt[i].x - node0], 1);
    __syncthreads();
    int n = node0 + tid, dg = c[tid], pad = 0;
    if (n < N_NODES) {
        deg[n] = dg;
        rr[n] = dg > 0 ? rsqrtf((float)dg) : 0.0f;
        pad = dg + (dg & 1);
    }
    red[tid] = pad;
    __syncthreads();
    for (int off = 128; off > 0; off >>= 1) {
        if (tid < off) red[tid] += red[tid + off];
        __syncthreads();
    }
    if (tid == 0) padSum[d * 512 + b] = red[0];
}

// ---------------- K5: padded bucket-start scan (both dirs, one block, parallel)
__global__ __launch_bounds__(512) void pad_scan(const int* __restrict__ padSum,
                                                int* __restrict__ padStart) {
    __shared__ int s[512];
    const int tid = threadIdx.x;
    int v = (tid < NB) ? padSum[tid] : 0;
    s[tid] = v;
    __syncthreads();
    for (int off = 1; off < 512; off <<= 1) {
        int t = (tid >= off) ? s[tid - off] : 0;
        __syncthreads();
        s[tid] += t;
        __syncthreads();
    }
    if (tid < NB) padStart[tid] = s[tid] - v;
    __syncthreads();
    int v2 = (tid < NB) ? padSum[512 + tid] : 0;
    s[tid] = v2;
    __syncthreads();
    for (int off = 1; off < 512; off <<= 1) {
        int t = (tid >= off) ? s[tid - off] : 0;
        __syncthreads();
        s[tid] += t;
        __syncthreads();
    }
    if (tid < NB) padStart[512 + tid] = s[tid] - v2;
}

// ----------------------- K6: per-node padded CSR offsets (per-bucket LDS scan)
__global__ __launch_bounds__(256) void node_ptr(const int* __restrict__ padStart,
                                                const int* __restrict__ deg_out,
                                                const int* __restrict__ deg_in,
                                                int* __restrict__ rowptrP,
                                                int* __restrict__ colptrP) {
    __shared__ int s[256];
    const int b = blockIdx.x, d = blockIdx.y, tid = threadIdx.x;
    const int* deg = d ? deg_in : deg_out;
    int* ptr = d ? colptrP : rowptrP;
    int n = b * BW + tid;
    int pad = 0;
    if (n < N_NODES) { int dg = deg[n]; pad = dg + (dg & 1); }
    s[tid] = pad;
    __syncthreads();
    for (int off = 1; off < 256; off <<= 1) {
        int t = (tid >= off) ? s[tid - off] : 0;
        __syncthreads();
        s[tid] += t;
        __syncthreads();
    }
    if (n < N_NODES) ptr[n] = padStart[d * 512 + b] + s[tid] - pad;
}

// ------------------------------------- K7: within-bucket counting scatter
__global__ __launch_bounds__(512) void bucket_scatter(
        const int* __restrict__ rowptrP, const int* __restrict__ colptrP,
        const float* __restrict__ r_out, const float* __restrict__ r_in,
        const int* __restrict__ bktStartA, const int* __restrict__ bktStartT,
        const int2* __restrict__ bktA, const int2* __restrict__ bktT,
        int2* __restrict__ recA, int2* __restrict__ recT) {
    __shared__ int cur[BW];
    __shared__ float rwt[BW];
    const int b = blockIdx.x, d = blockIdx.y, tid = threadIdx.x;
    const int* ptr = d ? colptrP : rowptrP;
    const float* rt = d ? r_in : r_out;       // target-side scale (bucket-local)
    const float* rs = d ? r_out : r_in;       // source-side scale (gathered)
    const int* bs = d ? bktStartT : bktStartA;
    const int2* bkt = d ? bktT : bktA;
    int2* rec = d ? recT : recA;
    const int node0 = b * BW;
    if (tid < BW) {
        int n = node0 + tid;
        cur[tid] = (n < N_NODES) ? ptr[n] : 0;
        rwt[tid] = (n < N_NODES) ? rt[n] : 0.0f;
    }
    __syncthreads();
    const int i0 = bs[b], i1 = bs[b + 1];
    for (int i = i0 + tid; i < i1; i += 512) {
        int2 e = bkt[i];
        float w = rwt[e.x - node0] * rs[e.y];
        int p = atomicAdd(&cur[e.x - node0], 1);
        rec[p] = make_int2(e.y, __float_as_int(w));
    }
}

// -------------------------------------------------------------- fused layer
__device__ __forceinline__ void fma4(float4& a, float w, const float4& f) {
    a.x = fmaf(w, f.x, a.x); a.y = fmaf(w, f.y, a.y);
    a.z = fmaf(w, f.z, a.z); a.w = fmaf(w, f.w, a.w);
}

__device__ __forceinline__ float4 red_s(float4 v) {
    v.x += __shfl_xor(v.x, 16); v.y += __shfl_xor(v.y, 16);
    v.z += __shfl_xor(v.z, 16); v.w += __shfl_xor(v.w, 16);
    v.x += __shfl_xor(v.x, 32); v.y += __shfl_xor(v.y, 32);
    v.z += __shfl_xor(v.z, 32); v.w += __shfl_xor(v.w, 32);
    return v;
}

// per-wave aggregation; lane (q,s): q = feature quad, s = edge-pair slot.
__device__ __forceinline__ float4 agg_dir(const float4* __restrict__ hv,
                                          const int2* __restrict__ rec,
                                          int start, int deg, int q, int s) {
    float4 a0 = {0.f,0.f,0.f,0.f}, a1 = {0.f,0.f,0.f,0.f};
    const int4* rec4 = (const int4*)(rec + start);
    int k = 0;
    for (; k + 8 <= deg; k += 8) {
        int4 p = rec4[(k >> 1) + s];          // records k+2s, k+2s+1
        float4 f0 = hv[(size_t)p.x * 16 + q];
        float4 f1 = hv[(size_t)p.z * 16 + q];
        fma4(a0, __int_as_float(p.y), f0);
        fma4(a1, __int_as_float(p.w), f1);
    }
    int r = deg - k;                          // 0..7 remaining
    if (2 * s < r) {
        int4 p = rec4[(k >> 1) + s];
        float4 f0 = hv[(size_t)p.x * 16 + q];
        fma4(a0, __int_as_float(p.y), f0);
        if (2 * s + 1 < r) {
            float4 f1 = hv[(size_t)p.z * 16 + q];
            fma4(a1, __int_as_float(p.w), f1);
        }
    }
    a0.x += a1.x; a0.y += a1.y; a0.z += a1.z; a0.w += a1.w;
    return red_s(a0);
}

__global__ __launch_bounds__(512, 8) void layer_kernel(
        const float* __restrict__ h_in, float* __restrict__ h_out,
        const int* __restrict__ rowptrP, const int* __restrict__ deg_out,
        const int2* __restrict__ recA,
        const int* __restrict__ colptrP, const int* __restrict__ deg_in,
        const int2* __restrict__ recT,
        const float* __restrict__ ws, const float* __restrict__ bs,
        const float* __restrict__ wd, const float* __restrict__ bd) {
    __shared__ float4 s_ws[HDIM * 16];                 // [k][q] 16KB
    __shared__ float4 s_wd[HDIM * 16];                 // 16KB
    __shared__ float4 s_accv[BLK_NODES][2][16];        // 4KB

    const int tid  = threadIdx.x;
    const int wave = tid >> 6;
    const int lane = tid & 63;
    const int q = lane & 15;
    const int s = lane >> 4;
    const int node = blockIdx.x * BLK_NODES + wave;

    // stage weights (1024 float4 each; 512 threads x 2)
    const float4* wsv = (const float4*)ws;
    const float4* wdv = (const float4*)wd;
    s_ws[tid] = wsv[tid]; s_ws[tid + 512] = wsv[tid + 512];
    s_wd[tid] = wdv[tid]; s_wd[tid + 512] = wdv[tid + 512];

    const float4* hv = (const float4*)h_in;

    float4 aA = agg_dir(hv, recA, rowptrP[node], deg_out[node], q, s);
    if (s == 0) s_accv[wave][0][q] = aA;
    float4 aT = agg_dir(hv, recT, colptrP[node], deg_in[node], q, s);
    if (s == 0) s_accv[wave][1][q] = aT;

    __syncthreads();

    // GEMM epilogue: thread -> feats 4q..4q+3 of its node, k in [16s, 16s+16)
    const float* accA = (const float*)&s_accv[wave][0][0];
    const float* accT = (const float*)&s_accv[wave][1][0];
    float4 oA = {0.f,0.f,0.f,0.f}, oT = {0.f,0.f,0.f,0.f};
    const int k0 = s * 16;
#pragma unroll
    for (int i = 0; i < 16; i++) {
        int k = k0 + i;
        float vA = accA[k];
        float vT = accT[k];
        float4 wA = s_ws[k * 16 + q];
        float4 wT = s_wd[k * 16 + q];
        fma4(oA, vA, wA);
        fma4(oT, vT, wT);
    }
    float4 o;
    o.x = ALPHA_C * oA.x + BETA_C * oT.x;
    o.y = ALPHA_C * oA.y + BETA_C * oT.y;
    o.z = ALPHA_C * oA.z + BETA_C * oT.z;
    o.w = ALPHA_C * oA.w + BETA_C * oT.w;
    o = red_s(o);
    if (s == 0) {
        float4 bA = ((const float4*)bs)[q];
        float4 bD = ((const float4*)bd)[q];
        o.x = fmaxf(o.x + ALPHA_C * bA.x + BETA_C * bD.x, 0.0f);
        o.y = fmaxf(o.y + ALPHA_C * bA.y + BETA_C * bD.y, 0.0f);
        o.z = fmaxf(o.z + ALPHA_C * bA.z + BETA_C * bD.z, 0.0f);
        o.w = fmaxf(o.w + ALPHA_C * bA.w + BETA_C * bD.w, 0.0f);
        ((float4*)h_out)[(size_t)node * 16 + q] = o;
    }
}

// ---------------------------------------------------------------- max pool
__global__ __launch_bounds__(256) void pool_kernel(const float* __restrict__ h,
                                                   const int* __restrict__ batch,
                                                   unsigned* __restrict__ g) {
    int t = blockIdx.x * 256 + threadIdx.x;
    const int ngroups = N_NODES / 16;   // 6250
    if (t >= ngroups * 64) return;
    int f = t & 63;
    int n0 = (t >> 6) * 16;
    int curg = batch[n0];
    float m = 0.0f;                      // post-ReLU values are >= 0
    for (int n = n0; n < n0 + 16; n++) {
        int b = batch[n];
        if (b != curg) {
            atomicMax(&g[curg * HDIM + f], __float_as_uint(m));
            curg = b;
            m = 0.0f;
        }
        m = fmaxf(m, h[n * HDIM + f]);
    }
    atomicMax(&g[curg * HDIM + f], __float_as_uint(m));
}

// -------------------------------------------------------------------- MLP head
__global__ __launch_bounds__(64) void mlp_kernel(const unsigned* __restrict__ g,
                                                 const float* __restrict__ wl1,
                                                 const float* __restrict__ bl1,
                                                 const float* __restrict__ wl2,
                                                 const float* __restrict__ bl2,
                                                 float* __restrict__ out) {
    int t = threadIdx.x;   // graph index, one block of 64
    float gv[HDIM];
#pragma unroll
    for (int k = 0; k < HDIM; k++) gv[k] = __uint_as_float(g[t * HDIM + k]);
    float o = bl2[0];
#pragma unroll
    for (int j = 0; j < 5; j++) {
        float hj = bl1[j];
#pragma unroll
        for (int k = 0; k < HDIM; k++) hj += gv[k] * wl1[k * 5 + j];
        hj = fmaxf(hj, 0.0f);
        o += hj * wl2[j];
    }
    out[t] = o;
}

// ------------------------------------------------------------------- launch
extern "C" void kernel_launch(void* const* d_in, const int* in_sizes, int n_in,
                              void* d_out, int out_size, void* d_ws, size_t ws_size,
                              hipStream_t stream) {
    const float* x   = (const float*)d_in[0];
    const int*   ei  = (const int*)d_in[1];
    const int*   bat = (const int*)d_in[2];
    const float* w1s = (const float*)d_in[3];
    const float* b1s = (const float*)d_in[4];
    const float* w1d = (const float*)d_in[5];
    const float* b1d = (const float*)d_in[6];
    const float* w2s = (const float*)d_in[7];
    const float* b2s = (const float*)d_in[8];
    const float* w2d = (const float*)d_in[9];
    const float* b2d = (const float*)d_in[10];
    const float* w3s = (const float*)d_in[11];
    const float* b3s = (const float*)d_in[12];
    const float* w3d = (const float*)d_in[13];
    const float* b3d = (const float*)d_in[14];
    const float* wl1 = (const float*)d_in[15];
    const float* bl1 = (const float*)d_in[16];
    const float* wl2 = (const float*)d_in[17];
    const float* bl2 = (const float*)d_in[18];
    float* out = (float*)d_out;

    // Workspace carve-up (16B-aligned chunks). bktA/bktT alias hA: buckets are
    // dead before the first layer_kernel writes hA.
    char* p = (char*)d_ws;
    int*   deg_out = (int*)p;              p += N_NODES * 4;
    int*   deg_in  = (int*)p;              p += N_NODES * 4;
    int*   rowptrP = (int*)p;              p += N_NODES * 4;
    int*   colptrP = (int*)p;              p += N_NODES * 4;
    float* r_out   = (float*)p;            p += N_NODES * 4;
    float* r_in    = (float*)p;            p += N_NODES * 4;
    int*   cntTabA = (int*)p;              p += (size_t)NB * NBLK * 4;
    int*   cntTabT = (int*)p;              p += (size_t)NB * NBLK * 4;
    int*   totTab  = (int*)p;              p += 1024 * 4;
    int*   bktStartA = (int*)p;            p += 512 * 4;
    int*   bktStartT = (int*)p;            p += 512 * 4;
    int*   padSum  = (int*)p;              p += 1024 * 4;
    int*   padStart = (int*)p;             p += 1024 * 4;
    int2*  recA    = (int2*)p;             p += (size_t)EPAD * 8;
    int2*  recT    = (int2*)p;             p += (size_t)EPAD * 8;
    int2*  bktA    = (int2*)p;             // aliased with hA
    float* hA      = (float*)p;
    int2*  bktT    = (int2*)((char*)bktA + (size_t)N_EDGES * 8);
    p = (char*)bktA + 2 * (size_t)N_EDGES * 8;   // == 25.6MB == hA size
    float* hB      = (float*)p;            p += (size_t)N_NODES * HDIM * 4;
    unsigned* g    = (unsigned*)p;         p += NGRAPH * HDIM * 4;

    hipMemsetAsync(g, 0, NGRAPH * HDIM * 4, stream);

    bucket_count<<<NBLK, 512, 0, stream>>>(ei, cntTabA, cntTabT);
    dim3 gb2(NB, 2);
    chunk_scan<<<gb2, 256, 0, stream>>>(cntTabA, cntTabT, totTab);
    start_scan<<<1, 512, 0, stream>>>(totTab, bktStartA, bktStartT);
    bucketize_write<<<NBLK, 512, 0, stream>>>(ei, cntTabA, cntTabT,
                                              bktStartA, bktStartT, bktA, bktT);

    dim3 gb(NB, 2);
    bucket_deg<<<gb, 256, 0, stream>>>(bktStartA, bktStartT, bktA, bktT,
                                       deg_out, deg_in, r_out, r_in, padSum);
    pad_scan<<<1, 512, 0, stream>>>(padSum, padStart);
    node_ptr<<<gb, 256, 0, stream>>>(padStart, deg_out, deg_in, rowptrP, colptrP);
    bucket_scatter<<<gb, 512, 0, stream>>>(
        rowptrP, colptrP, r_out, r_in, bktStartA, bktStartT, bktA, bktT, recA, recT);

    // Three fused conv layers: x -> hA -> hB -> hA
    layer_kernel<<<N_NODES / BLK_NODES, 512, 0, stream>>>(
        x, hA, rowptrP, deg_out, recA, colptrP, deg_in, recT, w1s, b1s, w1d, b1d);
    layer_kernel<<<N_NODES / BLK_NODES, 512, 0, stream>>>(
        hA, hB, rowptrP, deg_out, recA, colptrP, deg_in, recT, w2s, b2s, w2d, b2d);
    layer_kernel<<<N_NODES / BLK_NODES, 512, 0, stream>>>(
        hB, hA, rowptrP, deg_out, recA, colptrP, deg_in, recT, w3s, b3s, w3d, b3d);

    const int pool_threads = (N_NODES / 16) * 64;   // 400000
    pool_kernel<<<(pool_threads + 255) / 256, 256, 0, stream>>>(hA, bat, g);

    mlp_kernel<<<1, 64, 0, stream>>>(g, wl1, bl1, wl2, bl2, out);
}

// Round 9
// 554.741 us; speedup vs baseline: 1.2550x; 1.0482x over previous
//
#include <hip/hip_runtime.h>

// Problem constants
#define N_NODES 100000
#define N_EDGES 1600000
#define EPAD    (N_EDGES + N_NODES)      // padded record capacity (even starts)
#define HDIM    64
#define NGRAPH  64
#define BLK_NODES 8
#define ALPHA_C 0.5f
#define BETA_C  0.5f
#define BW      256                      // bucket width (nodes); shift = 8
#define NB      391                      // ceil(N_NODES / BW)
#define NBLK    256                      // edge-pass blocks
#define CHUNK   ((N_EDGES + NBLK - 1) / NBLK)

// native fp16, no hip_fp16 header
typedef _Float16 h16;
typedef _Float16 h16x4 __attribute__((ext_vector_type(4)));

// ----------------------------------------- K1: per-(block,bucket) edge counts
__global__ __launch_bounds__(512) void bucket_count(const int* __restrict__ ei,
                                                    int* __restrict__ cntTabA,
                                                    int* __restrict__ cntTabT) {
    __shared__ int cA[NB], cT[NB];
    const int tid = threadIdx.x;
    for (int i = tid; i < NB; i += 512) { cA[i] = 0; cT[i] = 0; }
    __syncthreads();
    const int e0 = blockIdx.x * CHUNK, e1 = min(e0 + CHUNK, N_EDGES);
    for (int e = e0 + tid; e < e1; e += 512) {
        int r = ei[e];
        int c = ei[N_EDGES + e];
        atomicAdd(&cA[r >> 8], 1);
        atomicAdd(&cT[c >> 8], 1);
    }
    __syncthreads();
    for (int b = tid; b < NB; b += 512) {
        cntTabA[b * NBLK + blockIdx.x] = cA[b];
        cntTabT[b * NBLK + blockIdx.x] = cT[b];
    }
}

// ---------------- K2a: per-bucket LDS scan of the 256 per-block counts
__global__ __launch_bounds__(256) void chunk_scan(int* __restrict__ cntTabA,
                                                  int* __restrict__ cntTabT,
                                                  int* __restrict__ tot) {
    __shared__ int s[256];
    const int b = blockIdx.x, d = blockIdx.y, tid = threadIdx.x;
    int* tab = d ? cntTabT : cntTabA;
    int v = tab[b * NBLK + tid];
    s[tid] = v;
    __syncthreads();
    for (int off = 1; off < 256; off <<= 1) {
        int t = (tid >= off) ? s[tid - off] : 0;
        __syncthreads();
        s[tid] += t;
        __syncthreads();
    }
    tab[b * NBLK + tid] = s[tid] - v;       // exclusive within bucket
    if (tid == 255) tot[d * 512 + b] = s[255];
}

// ---------------- K2b: bucket-start scan (both dirs, one block, parallel)
__global__ __launch_bounds__(512) void start_scan(const int* __restrict__ tot,
                                                  int* __restrict__ bktStartA,
                                                  int* __restrict__ bktStartT) {
    __shared__ int s[512];
    const int tid = threadIdx.x;
    int v = (tid < NB) ? tot[tid] : 0;
    s[tid] = v;
    __syncthreads();
    for (int off = 1; off < 512; off <<= 1) {
        int t = (tid >= off) ? s[tid - off] : 0;
        __syncthreads();
        s[tid] += t;
        __syncthreads();
    }
    if (tid < NB) bktStartA[tid] = s[tid] - v;
    if (tid == 0) bktStartA[NB] = N_EDGES;
    __syncthreads();
    int v2 = (tid < NB) ? tot[512 + tid] : 0;
    s[tid] = v2;
    __syncthreads();
    for (int off = 1; off < 512; off <<= 1) {
        int t = (tid >= off) ? s[tid - off] : 0;
        __syncthreads();
        s[tid] += t;
        __syncthreads();
    }
    if (tid < NB) bktStartT[tid] = s[tid] - v2;
    if (tid == 0) bktStartT[NB] = N_EDGES;
}

// --------------------------- K3: bucketize write (bases pre-reserved)
__global__ __launch_bounds__(512) void bucketize_write(const int* __restrict__ ei,
                                                       const int* __restrict__ cntTabA,
                                                       const int* __restrict__ cntTabT,
                                                       const int* __restrict__ bktStartA,
                                                       const int* __restrict__ bktStartT,
                                                       int2* __restrict__ bktA,
                                                       int2* __restrict__ bktT) {
    __shared__ int bA[NB], bT[NB];
    const int tid = threadIdx.x;
    for (int i = tid; i < NB; i += 512) {
        bA[i] = bktStartA[i] + cntTabA[i * NBLK + blockIdx.x];
        bT[i] = bktStartT[i] + cntTabT[i * NBLK + blockIdx.x];
    }
    __syncthreads();
    const int e0 = blockIdx.x * CHUNK, e1 = min(e0 + CHUNK, N_EDGES);
    for (int e = e0 + tid; e < e1; e += 512) {
        int r = ei[e];
        int c = ei[N_EDGES + e];
        int pA = atomicAdd(&bA[r >> 8], 1);
        bktA[pA] = make_int2(r, c);          // (target, source)
        int pT = atomicAdd(&bT[c >> 8], 1);
        bktT[pT] = make_int2(c, r);          // (target, source)
    }
}

// ------------------- K4: per-bucket degrees + rsqrt norms + padded-size reduce
__global__ __launch_bounds__(256) void bucket_deg(const int* __restrict__ bktStartA,
                                                  const int* __restrict__ bktStartT,
                                                  const int2* __restrict__ bktA,
                                                  const int2* __restrict__ bktT,
                                                  int* __restrict__ deg_out,
                                                  int* __restrict__ deg_in,
                                                  float* __restrict__ r_out,
                                                  float* __restrict__ r_in,
                                                  int* __restrict__ padSum) {
    __shared__ int c[BW];
    __shared__ int red[256];
    const int b = blockIdx.x, d = blockIdx.y, tid = threadIdx.x;
    const int* bs = d ? bktStartT : bktStartA;
    const int2* bkt = d ? bktT : bktA;
    int* deg = d ? deg_in : deg_out;
    float* rr = d ? r_in : r_out;
    const int node0 = b * BW;
    c[tid] = 0;
    __syncthreads();
    const int i0 = bs[b], i1 = bs[b + 1];
    for (int i = i0 + tid; i < i1; i += 256) atomicAdd(&c[bkt[i].x - node0], 1);
    __syncthreads();
    int n = node0 + tid, dg = c[tid], pad = 0;
    if (n < N_NODES) {
        deg[n] = dg;
        rr[n] = dg > 0 ? rsqrtf((float)dg) : 0.0f;
        pad = dg + (dg & 1);
    }
    red[tid] = pad;
    __syncthreads();
    for (int off = 128; off > 0; off >>= 1) {
        if (tid < off) red[tid] += red[tid + off];
        __syncthreads();
    }
    if (tid == 0) padSum[d * 512 + b] = red[0];
}

// ---------------- K5: padded bucket-start scan (both dirs, one block, parallel)
__global__ __launch_bounds__(512) void pad_scan(const int* __restrict__ padSum,
                                                int* __restrict__ padStart) {
    __shared__ int s[512];
    const int tid = threadIdx.x;
    int v = (tid < NB) ? padSum[tid] : 0;
    s[tid] = v;
    __syncthreads();
    for (int off = 1; off < 512; off <<= 1) {
        int t = (tid >= off) ? s[tid - off] : 0;
        __syncthreads();
        s[tid] += t;
        __syncthreads();
    }
    if (tid < NB) padStart[tid] = s[tid] - v;
    __syncthreads();
    int v2 = (tid < NB) ? padSum[512 + tid] : 0;
    s[tid] = v2;
    __syncthreads();
    for (int off = 1; off < 512; off <<= 1) {
        int t = (tid >= off) ? s[tid - off] : 0;
        __syncthreads();
        s[tid] += t;
        __syncthreads();
    }
    if (tid < NB) padStart[512 + tid] = s[tid] - v2;
}

// ----------------------- K6: per-node padded CSR offsets (per-bucket LDS scan)
__global__ __launch_bounds__(256) void node_ptr(const int* __restrict__ padStart,
                                                const int* __restrict__ deg_out,
                                                const int* __restrict__ deg_in,
                                                int* __restrict__ rowptrP,
                                                int* __restrict__ colptrP) {
    __shared__ int s[256];
    const int b = blockIdx.x, d = blockIdx.y, tid = threadIdx.x;
    const int* deg = d ? deg_in : deg_out;
    int* ptr = d ? colptrP : rowptrP;
    int n = b * BW + tid;
    int pad = 0;
    if (n < N_NODES) { int dg = deg[n]; pad = dg + (dg & 1); }
    s[tid] = pad;
    __syncthreads();
    for (int off = 1; off < 256; off <<= 1) {
        int t = (tid >= off) ? s[tid - off] : 0;
        __syncthreads();
        s[tid] += t;
        __syncthreads();
    }
    if (n < N_NODES) ptr[n] = padStart[d * 512 + b] + s[tid] - pad;
}

// ------------------------------------- K7: within-bucket counting scatter
__global__ __launch_bounds__(512) void bucket_scatter(
        const int* __restrict__ rowptrP, const int* __restrict__ colptrP,
        const float* __restrict__ r_out, const float* __restrict__ r_in,
        const int* __restrict__ bktStartA, const int* __restrict__ bktStartT,
        const int2* __restrict__ bktA, const int2* __restrict__ bktT,
        int2* __restrict__ recA, int2* __restrict__ recT) {
    __shared__ int cur[BW];
    __shared__ float rwt[BW];
    const int b = blockIdx.x, d = blockIdx.y, tid = threadIdx.x;
    const int* ptr = d ? colptrP : rowptrP;
    const float* rt = d ? r_in : r_out;       // target-side scale (bucket-local)
    const float* rs = d ? r_out : r_in;       // source-side scale (gathered)
    const int* bs = d ? bktStartT : bktStartA;
    const int2* bkt = d ? bktT : bktA;
    int2* rec = d ? recT : recA;
    const int node0 = b * BW;
    if (tid < BW) {
        int n = node0 + tid;
        cur[tid] = (n < N_NODES) ? ptr[n] : 0;
        rwt[tid] = (n < N_NODES) ? rt[n] : 0.0f;
    }
    __syncthreads();
    const int i0 = bs[b], i1 = bs[b + 1];
    for (int i = i0 + tid; i < i1; i += 512) {
        int2 e = bkt[i];
        float w = rwt[e.x - node0] * rs[e.y];
        int p = atomicAdd(&cur[e.x - node0], 1);
        rec[p] = make_int2(e.y, __float_as_int(w));
    }
}

// ---------------------------------------------------- x -> fp16 cast
__global__ __launch_bounds__(256) void cast_kernel(const float4* __restrict__ x,
                                                   h16x4* __restrict__ xh) {
    int i = blockIdx.x * 256 + threadIdx.x;   // over N*64/4 float4s
    if (i < N_NODES * 16) {
        float4 v = x[i];
        h16x4 o;
        o.x = (h16)v.x; o.y = (h16)v.y; o.z = (h16)v.z; o.w = (h16)v.w;
        xh[i] = o;
    }
}

// -------------------------------------------------------------- fused layer
__device__ __forceinline__ void fma4(float4& a, float w, const float4& f) {
    a.x = fmaf(w, f.x, a.x); a.y = fmaf(w, f.y, a.y);
    a.z = fmaf(w, f.z, a.z); a.w = fmaf(w, f.w, a.w);
}

__device__ __forceinline__ float4 red_s(float4 v) {
    v.x += __shfl_xor(v.x, 16); v.y += __shfl_xor(v.y, 16);
    v.z += __shfl_xor(v.z, 16); v.w += __shfl_xor(v.w, 16);
    v.x += __shfl_xor(v.x, 32); v.y += __shfl_xor(v.y, 32);
    v.z += __shfl_xor(v.z, 32); v.w += __shfl_xor(v.w, 32);
    return v;
}

// load 4 consecutive halfs (8B aligned) -> float4
__device__ __forceinline__ float4 ld_half4(const h16* __restrict__ p) {
    h16x4 v = *(const h16x4*)p;
    return make_float4((float)v.x, (float)v.y, (float)v.z, (float)v.w);
}

// per-wave aggregation; lane (q,s): q = feature quad, s = edge-pair slot.
// records are (src, w) int2; node runs start 16B-aligned (padded CSR) so each
// slot loads 2 records with one int4. Features gathered as half4 (8B/lane).
__device__ __forceinline__ float4 agg_dir(const h16* __restrict__ h,
                                          const int2* __restrict__ rec,
                                          int start, int deg, int q, int s) {
    float4 a0 = {0.f,0.f,0.f,0.f}, a1 = {0.f,0.f,0.f,0.f};
    const int4* rec4 = (const int4*)(rec + start);
    int k = 0;
    for (; k + 8 <= deg; k += 8) {
        int4 p = rec4[(k >> 1) + s];          // records k+2s, k+2s+1
        float4 f0 = ld_half4(h + (size_t)p.x * 64 + q * 4);
        float4 f1 = ld_half4(h + (size_t)p.z * 64 + q * 4);
        fma4(a0, __int_as_float(p.y), f0);
        fma4(a1, __int_as_float(p.w), f1);
    }
    int r = deg - k;                          // 0..7 remaining
    if (2 * s < r) {
        int4 p = rec4[(k >> 1) + s];
        float4 f0 = ld_half4(h + (size_t)p.x * 64 + q * 4);
        fma4(a0, __int_as_float(p.y), f0);
        if (2 * s + 1 < r) {
            float4 f1 = ld_half4(h + (size_t)p.z * 64 + q * 4);
            fma4(a1, __int_as_float(p.w), f1);
        }
    }
    a0.x += a1.x; a0.y += a1.y; a0.z += a1.z; a0.w += a1.w;
    return red_s(a0);
}

__global__ __launch_bounds__(512, 8) void layer_kernel(
        const h16* __restrict__ h_in, h16* __restrict__ h_out,
        const int* __restrict__ rowptrP, const int* __restrict__ deg_out,
        const int2* __restrict__ recA,
        const int* __restrict__ colptrP, const int* __restrict__ deg_in,
        const int2* __restrict__ recT,
        const float* __restrict__ ws, const float* __restrict__ bs,
        const float* __restrict__ wd, const float* __restrict__ bd) {
    __shared__ float4 s_ws[HDIM * 16];                 // [k][q] 16KB
    __shared__ float4 s_wd[HDIM * 16];                 // 16KB
    __shared__ float4 s_accv[BLK_NODES][2][16];        // 4KB

    const int tid  = threadIdx.x;
    const int wave = tid >> 6;
    const int lane = tid & 63;
    const int q = lane & 15;
    const int s = lane >> 4;
    const int node = blockIdx.x * BLK_NODES + wave;

    // stage weights (1024 float4 each; 512 threads x 2)
    const float4* wsv = (const float4*)ws;
    const float4* wdv = (const float4*)wd;
    s_ws[tid] = wsv[tid]; s_ws[tid + 512] = wsv[tid + 512];
    s_wd[tid] = wdv[tid]; s_wd[tid + 512] = wdv[tid + 512];

    float4 aA = agg_dir(h_in, recA, rowptrP[node], deg_out[node], q, s);
    if (s == 0) s_accv[wave][0][q] = aA;
    float4 aT = agg_dir(h_in, recT, colptrP[node], deg_in[node], q, s);
    if (s == 0) s_accv[wave][1][q] = aT;

    __syncthreads();

    // GEMM epilogue: thread -> feats 4q..4q+3 of its node, k in [16s, 16s+16)
    const float* accA = (const float*)&s_accv[wave][0][0];
    const float* accT = (const float*)&s_accv[wave][1][0];
    float4 oA = {0.f,0.f,0.f,0.f}, oT = {0.f,0.f,0.f,0.f};
    const int k0 = s * 16;
#pragma unroll
    for (int i = 0; i < 16; i++) {
        int k = k0 + i;
        float vA = accA[k];
        float vT = accT[k];
        float4 wA = s_ws[k * 16 + q];
        float4 wT = s_wd[k * 16 + q];
        fma4(oA, vA, wA);
        fma4(oT, vT, wT);
    }
    float4 o;
    o.x = ALPHA_C * oA.x + BETA_C * oT.x;
    o.y = ALPHA_C * oA.y + BETA_C * oT.y;
    o.z = ALPHA_C * oA.z + BETA_C * oT.z;
    o.w = ALPHA_C * oA.w + BETA_C * oT.w;
    o = red_s(o);
    if (s == 0) {
        float4 bA = ((const float4*)bs)[q];
        float4 bD = ((const float4*)bd)[q];
        o.x = fmaxf(o.x + ALPHA_C * bA.x + BETA_C * bD.x, 0.0f);
        o.y = fmaxf(o.y + ALPHA_C * bA.y + BETA_C * bD.y, 0.0f);
        o.z = fmaxf(o.z + ALPHA_C * bA.z + BETA_C * bD.z, 0.0f);
        o.w = fmaxf(o.w + ALPHA_C * bA.w + BETA_C * bD.w, 0.0f);
        h16x4 st;
        st.x = (h16)o.x; st.y = (h16)o.y; st.z = (h16)o.z; st.w = (h16)o.w;
        *(h16x4*)(h_out + (size_t)node * 64 + q * 4) = st;
    }
}

// ---------------------------------------------------------------- max pool
__global__ __launch_bounds__(256) void pool_kernel(const h16* __restrict__ h,
                                                   const int* __restrict__ batch,
                                                   unsigned* __restrict__ g) {
    int t = blockIdx.x * 256 + threadIdx.x;
    const int ngroups = N_NODES / 16;   // 6250
    if (t >= ngroups * 64) return;
    int f = t & 63;
    int n0 = (t >> 6) * 16;
    int curg = batch[n0];
    float m = 0.0f;                      // post-ReLU values are >= 0
    for (int n = n0; n < n0 + 16; n++) {
        int b = batch[n];
        if (b != curg) {
            atomicMax(&g[curg * HDIM + f], __float_as_uint(m));
            curg = b;
            m = 0.0f;
        }
        m = fmaxf(m, (float)h[(size_t)n * HDIM + f]);
    }
    atomicMax(&g[curg * HDIM + f], __float_as_uint(m));
}

// -------------------------------------------------------------------- MLP head
__global__ __launch_bounds__(64) void mlp_kernel(const unsigned* __restrict__ g,
                                                 const float* __restrict__ wl1,
                                                 const float* __restrict__ bl1,
                                                 const float* __restrict__ wl2,
                                                 const float* __restrict__ bl2,
                                                 float* __restrict__ out) {
    int t = threadIdx.x;   // graph index, one block of 64
    float gv[HDIM];
#pragma unroll
    for (int k = 0; k < HDIM; k++) gv[k] = __uint_as_float(g[t * HDIM + k]);
    float o = bl2[0];
#pragma unroll
    for (int j = 0; j < 5; j++) {
        float hj = bl1[j];
#pragma unroll
        for (int k = 0; k < HDIM; k++) hj += gv[k] * wl1[k * 5 + j];
        hj = fmaxf(hj, 0.0f);
        o += hj * wl2[j];
    }
    out[t] = o;
}

// ------------------------------------------------------------------- launch
extern "C" void kernel_launch(void* const* d_in, const int* in_sizes, int n_in,
                              void* d_out, int out_size, void* d_ws, size_t ws_size,
                              hipStream_t stream) {
    const float* x   = (const float*)d_in[0];
    const int*   ei  = (const int*)d_in[1];
    const int*   bat = (const int*)d_in[2];
    const float* w1s = (const float*)d_in[3];
    const float* b1s = (const float*)d_in[4];
    const float* w1d = (const float*)d_in[5];
    const float* b1d = (const float*)d_in[6];
    const float* w2s = (const float*)d_in[7];
    const float* b2s = (const float*)d_in[8];
    const float* w2d = (const float*)d_in[9];
    const float* b2d = (const float*)d_in[10];
    const float* w3s = (const float*)d_in[11];
    const float* b3s = (const float*)d_in[12];
    const float* w3d = (const float*)d_in[13];
    const float* b3d = (const float*)d_in[14];
    const float* wl1 = (const float*)d_in[15];
    const float* bl1 = (const float*)d_in[16];
    const float* wl2 = (const float*)d_in[17];
    const float* bl2 = (const float*)d_in[18];
    float* out = (float*)d_out;

    // Workspace carve-up (16B-aligned chunks). bktA/bktT alias hA: buckets are
    // dead before the first layer_kernel writes hA (hA fp16 = 12.8MB fits).
    char* p = (char*)d_ws;
    int*   deg_out = (int*)p;              p += N_NODES * 4;
    int*   deg_in  = (int*)p;              p += N_NODES * 4;
    int*   rowptrP = (int*)p;              p += N_NODES * 4;
    int*   colptrP = (int*)p;              p += N_NODES * 4;
    float* r_out   = (float*)p;            p += N_NODES * 4;
    float* r_in    = (float*)p;            p += N_NODES * 4;
    int*   cntTabA = (int*)p;              p += (size_t)NB * NBLK * 4;
    int*   cntTabT = (int*)p;              p += (size_t)NB * NBLK * 4;
    int*   totTab  = (int*)p;              p += 1024 * 4;
    int*   bktStartA = (int*)p;            p += 512 * 4;
    int*   bktStartT = (int*)p;            p += 512 * 4;
    int*   padSum  = (int*)p;              p += 1024 * 4;
    int*   padStart = (int*)p;             p += 1024 * 4;
    int2*  recA    = (int2*)p;             p += (size_t)EPAD * 8;
    int2*  recT    = (int2*)p;             p += (size_t)EPAD * 8;
    int2*  bktA    = (int2*)p;             // aliased with hA (fp16)
    h16*   hA      = (h16*)p;
    int2*  bktT    = (int2*)((char*)bktA + (size_t)N_EDGES * 8);
    p = (char*)bktA + 2 * (size_t)N_EDGES * 8;   // 25.6MB region (hA uses 12.8)
    h16*   hB      = (h16*)p;              p += (size_t)N_NODES * HDIM * 2;
    h16*   xh      = (h16*)p;              p += (size_t)N_NODES * HDIM * 2;
    unsigned* g    = (unsigned*)p;         p += NGRAPH * HDIM * 4;

    hipMemsetAsync(g, 0, NGRAPH * HDIM * 4, stream);

    cast_kernel<<<(N_NODES * 16 + 255) / 256, 256, 0, stream>>>(
        (const float4*)x, (h16x4*)xh);

    bucket_count<<<NBLK, 512, 0, stream>>>(ei, cntTabA, cntTabT);
    dim3 gb2(NB, 2);
    chunk_scan<<<gb2, 256, 0, stream>>>(cntTabA, cntTabT, totTab);
    start_scan<<<1, 512, 0, stream>>>(totTab, bktStartA, bktStartT);
    bucketize_write<<<NBLK, 512, 0, stream>>>(ei, cntTabA, cntTabT,
                                              bktStartA, bktStartT, bktA, bktT);

    dim3 gb(NB, 2);
    bucket_deg<<<gb, 256, 0, stream>>>(bktStartA, bktStartT, bktA, bktT,
                                       deg_out, deg_in, r_out, r_in, padSum);
    pad_scan<<<1, 512, 0, stream>>>(padSum, padStart);
    node_ptr<<<gb, 256, 0, stream>>>(padStart, deg_out, deg_in, rowptrP, colptrP);
    bucket_scatter<<<gb, 512, 0, stream>>>(
        rowptrP, colptrP, r_out, r_in, bktStartA, bktStartT, bktA, bktT, recA, recT);

    // Three fused conv layers: xh -> hA -> hB -> hA
    layer_kernel<<<N_NODES / BLK_NODES, 512, 0, stream>>>(
        xh, hA, rowptrP, deg_out, recA, colptrP, deg_in, recT, w1s, b1s, w1d, b1d);
    layer_kernel<<<N_NODES / BLK_NODES, 512, 0, stream>>>(
        hA, hB, rowptrP, deg_out, recA, colptrP, deg_in, recT, w2s, b2s, w2d, b2d);
    layer_kernel<<<N_NODES / BLK_NODES, 512, 0, stream>>>(
        hB, hA, rowptrP, deg_out, recA, colptrP, deg_in, recT, w3s, b3s, w3d, b3d);

    const int pool_threads = (N_NODES / 16) * 64;   // 400000
    pool_kernel<<<(pool_threads + 255) / 256, 256, 0, stream>>>(hA, bat, g);

    mlp_kernel<<<1, 64, 0, stream>>>(g, wl1, bl1, wl2, bl2, out);
}

// Round 10
// 534.562 us; speedup vs baseline: 1.3024x; 1.0377x over previous
//
#include <hip/hip_runtime.h>

// Problem constants
#define N_NODES 100000
#define N_EDGES 1600000
#define EPAD    (N_EDGES + N_NODES)      // padded record capacity (even starts)
#define HDIM    64
#define NGRAPH  64
#define BLK_NODES 8
#define ALPHA_C 0.5f
#define BETA_C  0.5f
#define BW      256                      // bucket width (nodes); shift = 8
#define NB      391                      // ceil(N_NODES / BW)
#define NBLK    256                      // edge-pass blocks
#define CHUNK   ((N_EDGES + NBLK - 1) / NBLK)

// native fp16, no hip_fp16 header
typedef _Float16 h16;
typedef _Float16 h16x4 __attribute__((ext_vector_type(4)));

// ----------------------------------------- K1: per-(block,bucket) edge counts
__global__ __launch_bounds__(512) void bucket_count(const int* __restrict__ ei,
                                                    int* __restrict__ cntTabA,
                                                    int* __restrict__ cntTabT) {
    __shared__ int cA[NB], cT[NB];
    const int tid = threadIdx.x;
    for (int i = tid; i < NB; i += 512) { cA[i] = 0; cT[i] = 0; }
    __syncthreads();
    const int e0 = blockIdx.x * CHUNK, e1 = min(e0 + CHUNK, N_EDGES);
    for (int e = e0 + tid; e < e1; e += 512) {
        int r = ei[e];
        int c = ei[N_EDGES + e];
        atomicAdd(&cA[r >> 8], 1);
        atomicAdd(&cT[c >> 8], 1);
    }
    __syncthreads();
    for (int b = tid; b < NB; b += 512) {
        cntTabA[b * NBLK + blockIdx.x] = cA[b];
        cntTabT[b * NBLK + blockIdx.x] = cT[b];
    }
}

// ---------------- K2a: per-bucket LDS scan of the 256 per-block counts
__global__ __launch_bounds__(256) void chunk_scan(int* __restrict__ cntTabA,
                                                  int* __restrict__ cntTabT,
                                                  int* __restrict__ tot) {
    __shared__ int s[256];
    const int b = blockIdx.x, d = blockIdx.y, tid = threadIdx.x;
    int* tab = d ? cntTabT : cntTabA;
    int v = tab[b * NBLK + tid];
    s[tid] = v;
    __syncthreads();
    for (int off = 1; off < 256; off <<= 1) {
        int t = (tid >= off) ? s[tid - off] : 0;
        __syncthreads();
        s[tid] += t;
        __syncthreads();
    }
    tab[b * NBLK + tid] = s[tid] - v;       // exclusive within bucket
    if (tid == 255) tot[d * 512 + b] = s[255];
}

// ---------------- K2b: bucket-start scan (both dirs, one block, parallel)
__global__ __launch_bounds__(512) void start_scan(const int* __restrict__ tot,
                                                  int* __restrict__ bktStartA,
                                                  int* __restrict__ bktStartT) {
    __shared__ int s[512];
    const int tid = threadIdx.x;
    int v = (tid < NB) ? tot[tid] : 0;
    s[tid] = v;
    __syncthreads();
    for (int off = 1; off < 512; off <<= 1) {
        int t = (tid >= off) ? s[tid - off] : 0;
        __syncthreads();
        s[tid] += t;
        __syncthreads();
    }
    if (tid < NB) bktStartA[tid] = s[tid] - v;
    if (tid == 0) bktStartA[NB] = N_EDGES;
    __syncthreads();
    int v2 = (tid < NB) ? tot[512 + tid] : 0;
    s[tid] = v2;
    __syncthreads();
    for (int off = 1; off < 512; off <<= 1) {
        int t = (tid >= off) ? s[tid - off] : 0;
        __syncthreads();
        s[tid] += t;
        __syncthreads();
    }
    if (tid < NB) bktStartT[tid] = s[tid] - v2;
    if (tid == 0) bktStartT[NB] = N_EDGES;
}

// --------------------------- K3: bucketize write (bases pre-reserved)
__global__ __launch_bounds__(512) void bucketize_write(const int* __restrict__ ei,
                                                       const int* __restrict__ cntTabA,
                                                       const int* __restrict__ cntTabT,
                                                       const int* __restrict__ bktStartA,
                                                       const int* __restrict__ bktStartT,
                                                       int2* __restrict__ bktA,
                                                       int2* __restrict__ bktT) {
    __shared__ int bA[NB], bT[NB];
    const int tid = threadIdx.x;
    for (int i = tid; i < NB; i += 512) {
        bA[i] = bktStartA[i] + cntTabA[i * NBLK + blockIdx.x];
        bT[i] = bktStartT[i] + cntTabT[i * NBLK + blockIdx.x];
    }
    __syncthreads();
    const int e0 = blockIdx.x * CHUNK, e1 = min(e0 + CHUNK, N_EDGES);
    for (int e = e0 + tid; e < e1; e += 512) {
        int r = ei[e];
        int c = ei[N_EDGES + e];
        int pA = atomicAdd(&bA[r >> 8], 1);
        bktA[pA] = make_int2(r, c);          // (target, source)
        int pT = atomicAdd(&bT[c >> 8], 1);
        bktT[pT] = make_int2(c, r);          // (target, source)
    }
}

// ------------------- K4: per-bucket degrees + rsqrt norms + padded-size reduce
__global__ __launch_bounds__(256) void bucket_deg(const int* __restrict__ bktStartA,
                                                  const int* __restrict__ bktStartT,
                                                  const int2* __restrict__ bktA,
                                                  const int2* __restrict__ bktT,
                                                  int* __restrict__ deg_out,
                                                  int* __restrict__ deg_in,
                                                  float* __restrict__ r_out,
                                                  float* __restrict__ r_in,
                                                  int* __restrict__ padSum) {
    __shared__ int c[BW];
    __shared__ int red[256];
    const int b = blockIdx.x, d = blockIdx.y, tid = threadIdx.x;
    const int* bs = d ? bktStartT : bktStartA;
    const int2* bkt = d ? bktT : bktA;
    int* deg = d ? deg_in : deg_out;
    float* rr = d ? r_in : r_out;
    const int node0 = b * BW;
    c[tid] = 0;
    __syncthreads();
    const int i0 = bs[b], i1 = bs[b + 1];
    for (int i = i0 + tid; i < i1; i += 256) atomicAdd(&c[bkt[i].x - node0], 1);
    __syncthreads();
    int n = node0 + tid, dg = c[tid], pad = 0;
    if (n < N_NODES) {
        deg[n] = dg;
        rr[n] = dg > 0 ? rsqrtf((float)dg) : 0.0f;
        pad = dg + (dg & 1);
    }
    red[tid] = pad;
    __syncthreads();
    for (int off = 128; off > 0; off >>= 1) {
        if (tid < off) red[tid] += red[tid + off];
        __syncthreads();
    }
    if (tid == 0) padSum[d * 512 + b] = red[0];
}

// ---------------- K5: padded bucket-start scan (both dirs, one block, parallel)
__global__ __launch_bounds__(512) void pad_scan(const int* __restrict__ padSum,
                                                int* __restrict__ padStart) {
    __shared__ int s[512];
    const int tid = threadIdx.x;
    int v = (tid < NB) ? padSum[tid] : 0;
    s[tid] = v;
    __syncthreads();
    for (int off = 1; off < 512; off <<= 1) {
        int t = (tid >= off) ? s[tid - off] : 0;
        __syncthreads();
        s[tid] += t;
        __syncthreads();
    }
    if (tid < NB) padStart[tid] = s[tid] - v;
    __syncthreads();
    int v2 = (tid < NB) ? padSum[512 + tid] : 0;
    s[tid] = v2;
    __syncthreads();
    for (int off = 1; off < 512; off <<= 1) {
        int t = (tid >= off) ? s[tid - off] : 0;
        __syncthreads();
        s[tid] += t;
        __syncthreads();
    }
    if (tid < NB) padStart[512 + tid] = s[tid] - v2;
}

// ----------------------- K6: per-node padded CSR offsets (per-bucket LDS scan)
__global__ __launch_bounds__(256) void node_ptr(const int* __restrict__ padStart,
                                                const int* __restrict__ deg_out,
                                                const int* __restrict__ deg_in,
                                                int* __restrict__ rowptrP,
                                                int* __restrict__ colptrP) {
    __shared__ int s[256];
    const int b = blockIdx.x, d = blockIdx.y, tid = threadIdx.x;
    const int* deg = d ? deg_in : deg_out;
    int* ptr = d ? colptrP : rowptrP;
    int n = b * BW + tid;
    int pad = 0;
    if (n < N_NODES) { int dg = deg[n]; pad = dg + (dg & 1); }
    s[tid] = pad;
    __syncthreads();
    for (int off = 1; off < 256; off <<= 1) {
        int t = (tid >= off) ? s[tid - off] : 0;
        __syncthreads();
        s[tid] += t;
        __syncthreads();
    }
    if (n < N_NODES) ptr[n] = padStart[d * 512 + b] + s[tid] - pad;
}

// ------------------------------------- K7: within-bucket counting scatter
__global__ __launch_bounds__(512) void bucket_scatter(
        const int* __restrict__ rowptrP, const int* __restrict__ colptrP,
        const float* __restrict__ r_out, const float* __restrict__ r_in,
        const int* __restrict__ bktStartA, const int* __restrict__ bktStartT,
        const int2* __restrict__ bktA, const int2* __restrict__ bktT,
        int2* __restrict__ recA, int2* __restrict__ recT) {
    __shared__ int cur[BW];
    __shared__ float rwt[BW];
    const int b = blockIdx.x, d = blockIdx.y, tid = threadIdx.x;
    const int* ptr = d ? colptrP : rowptrP;
    const float* rt = d ? r_in : r_out;       // target-side scale (bucket-local)
    const float* rs = d ? r_out : r_in;       // source-side scale (gathered)
    const int* bs = d ? bktStartT : bktStartA;
    const int2* bkt = d ? bktT : bktA;
    int2* rec = d ? recT : recA;
    const int node0 = b * BW;
    if (tid < BW) {
        int n = node0 + tid;
        cur[tid] = (n < N_NODES) ? ptr[n] : 0;
        rwt[tid] = (n < N_NODES) ? rt[n] : 0.0f;
    }
    __syncthreads();
    const int i0 = bs[b], i1 = bs[b + 1];
    for (int i = i0 + tid; i < i1; i += 512) {
        int2 e = bkt[i];
        float w = rwt[e.x - node0] * rs[e.y];
        int p = atomicAdd(&cur[e.x - node0], 1);
        rec[p] = make_int2(e.y, __float_as_int(w));
    }
}

// ---------------------------------------------------- x -> fp16 cast
__global__ __launch_bounds__(256) void cast_kernel(const float4* __restrict__ x,
                                                   h16x4* __restrict__ xh) {
    int i = blockIdx.x * 256 + threadIdx.x;   // over N*64/4 float4s
    if (i < N_NODES * 16) {
        float4 v = x[i];
        h16x4 o;
        o.x = (h16)v.x; o.y = (h16)v.y; o.z = (h16)v.z; o.w = (h16)v.w;
        xh[i] = o;
    }
}

// -------------------------------------------------------------- fused layer
__device__ __forceinline__ void fma4(float4& a, float w, const float4& f) {
    a.x = fmaf(w, f.x, a.x); a.y = fmaf(w, f.y, a.y);
    a.z = fmaf(w, f.z, a.z); a.w = fmaf(w, f.w, a.w);
}

__device__ __forceinline__ float4 red_s(float4 v) {
    v.x += __shfl_xor(v.x, 16); v.y += __shfl_xor(v.y, 16);
    v.z += __shfl_xor(v.z, 16); v.w += __shfl_xor(v.w, 16);
    v.x += __shfl_xor(v.x, 32); v.y += __shfl_xor(v.y, 32);
    v.z += __shfl_xor(v.z, 32); v.w += __shfl_xor(v.w, 32);
    return v;
}

// load 4 consecutive halfs (8B aligned) -> float4
__device__ __forceinline__ float4 ld_half4(const h16* __restrict__ p) {
    h16x4 v = *(const h16x4*)p;
    return make_float4((float)v.x, (float)v.y, (float)v.z, (float)v.w);
}

// per-wave aggregation; lane (q,s): q = feature quad, s = edge-pair slot.
// records are (src, w) int2; node runs start 16B-aligned (padded CSR) so each
// slot loads 2 records with one int4. 16-edge unroll: 2 independent record
// loads + 4 independent gathers in flight per thread (latency hiding).
__device__ __forceinline__ float4 agg_dir(const h16* __restrict__ h,
                                          const int2* __restrict__ rec,
                                          int start, int deg, int q, int s) {
    float4 a0 = {0.f,0.f,0.f,0.f}, a1 = {0.f,0.f,0.f,0.f};
    float4 a2 = {0.f,0.f,0.f,0.f}, a3 = {0.f,0.f,0.f,0.f};
    const int4* rec4 = (const int4*)(rec + start);
    int k = 0;
    for (; k + 16 <= deg; k += 16) {
        int4 p0 = rec4[(k >> 1) + s];         // edges k+2s, k+2s+1
        int4 p1 = rec4[(k >> 1) + 4 + s];     // edges k+8+2s, k+8+2s+1
        float4 f0 = ld_half4(h + (size_t)p0.x * 64 + q * 4);
        float4 f1 = ld_half4(h + (size_t)p0.z * 64 + q * 4);
        float4 f2 = ld_half4(h + (size_t)p1.x * 64 + q * 4);
        float4 f3 = ld_half4(h + (size_t)p1.z * 64 + q * 4);
        fma4(a0, __int_as_float(p0.y), f0);
        fma4(a1, __int_as_float(p0.w), f1);
        fma4(a2, __int_as_float(p1.y), f2);
        fma4(a3, __int_as_float(p1.w), f3);
    }
    if (k + 8 <= deg) {
        int4 p = rec4[(k >> 1) + s];
        float4 f0 = ld_half4(h + (size_t)p.x * 64 + q * 4);
        float4 f1 = ld_half4(h + (size_t)p.z * 64 + q * 4);
        fma4(a0, __int_as_float(p.y), f0);
        fma4(a1, __int_as_float(p.w), f1);
        k += 8;
    }
    int r = deg - k;                          // 0..7 remaining
    if (2 * s < r) {
        int4 p = rec4[(k >> 1) + s];
        float4 f0 = ld_half4(h + (size_t)p.x * 64 + q * 4);
        fma4(a2, __int_as_float(p.y), f0);
        if (2 * s + 1 < r) {
            float4 f1 = ld_half4(h + (size_t)p.z * 64 + q * 4);
            fma4(a3, __int_as_float(p.w), f1);
        }
    }
    a0.x += a1.x; a0.y += a1.y; a0.z += a1.z; a0.w += a1.w;
    a2.x += a3.x; a2.y += a3.y; a2.z += a3.z; a2.w += a3.w;
    a0.x += a2.x; a0.y += a2.y; a0.z += a2.z; a0.w += a2.w;
    return red_s(a0);
}

__global__ __launch_bounds__(512, 8) void layer_kernel(
        const h16* __restrict__ h_in, h16* __restrict__ h_out,
        const int* __restrict__ rowptrP, const int* __restrict__ deg_out,
        const int2* __restrict__ recA,
        const int* __restrict__ colptrP, const int* __restrict__ deg_in,
        const int2* __restrict__ recT,
        const float* __restrict__ ws, const float* __restrict__ bs,
        const float* __restrict__ wd, const float* __restrict__ bd) {
    __shared__ float4 s_ws[HDIM * 16];                 // [k][q] 16KB
    __shared__ float4 s_wd[HDIM * 16];                 // 16KB
    __shared__ float4 s_accv[BLK_NODES][2][16];        // 4KB

    const int tid  = threadIdx.x;
    const int wave = tid >> 6;
    const int lane = tid & 63;
    const int q = lane & 15;
    const int s = lane >> 4;
    const int node = blockIdx.x * BLK_NODES + wave;

    // stage weights (1024 float4 each; 512 threads x 2)
    const float4* wsv = (const float4*)ws;
    const float4* wdv = (const float4*)wd;
    s_ws[tid] = wsv[tid]; s_ws[tid + 512] = wsv[tid + 512];
    s_wd[tid] = wdv[tid]; s_wd[tid + 512] = wdv[tid + 512];

    float4 aA = agg_dir(h_in, recA, rowptrP[node], deg_out[node], q, s);
    if (s == 0) s_accv[wave][0][q] = aA;
    float4 aT = agg_dir(h_in, recT, colptrP[node], deg_in[node], q, s);
    if (s == 0) s_accv[wave][1][q] = aT;

    __syncthreads();

    // GEMM epilogue: thread -> feats 4q..4q+3 of its node, k in [16s, 16s+16)
    const float* accA = (const float*)&s_accv[wave][0][0];
    const float* accT = (const float*)&s_accv[wave][1][0];
    float4 oA = {0.f,0.f,0.f,0.f}, oT = {0.f,0.f,0.f,0.f};
    const int k0 = s * 16;
#pragma unroll
    for (int i = 0; i < 16; i++) {
        int k = k0 + i;
        float vA = accA[k];
        float vT = accT[k];
        float4 wA = s_ws[k * 16 + q];
        float4 wT = s_wd[k * 16 + q];
        fma4(oA, vA, wA);
        fma4(oT, vT, wT);
    }
    float4 o;
    o.x = ALPHA_C * oA.x + BETA_C * oT.x;
    o.y = ALPHA_C * oA.y + BETA_C * oT.y;
    o.z = ALPHA_C * oA.z + BETA_C * oT.z;
    o.w = ALPHA_C * oA.w + BETA_C * oT.w;
    o = red_s(o);
    if (s == 0) {
        float4 bA = ((const float4*)bs)[q];
        float4 bD = ((const float4*)bd)[q];
        o.x = fmaxf(o.x + ALPHA_C * bA.x + BETA_C * bD.x, 0.0f);
        o.y = fmaxf(o.y + ALPHA_C * bA.y + BETA_C * bD.y, 0.0f);
        o.z = fmaxf(o.z + ALPHA_C * bA.z + BETA_C * bD.z, 0.0f);
        o.w = fmaxf(o.w + ALPHA_C * bA.w + BETA_C * bD.w, 0.0f);
        h16x4 st;
        st.x = (h16)o.x; st.y = (h16)o.y; st.z = (h16)o.z; st.w = (h16)o.w;
        *(h16x4*)(h_out + (size_t)node * 64 + q * 4) = st;
    }
}

// ---------------------------------------------------------------- max pool
__global__ __launch_bounds__(256) void pool_kernel(const h16* __restrict__ h,
                                                   const int* __restrict__ batch,
                                                   unsigned* __restrict__ g) {
    int t = blockIdx.x * 256 + threadIdx.x;
    const int ngroups = N_NODES / 16;   // 6250
    if (t >= ngroups * 64) return;
    int f = t & 63;
    int n0 = (t >> 6) * 16;
    int curg = batch[n0];
    float m = 0.0f;                      // post-ReLU values are >= 0
    for (int n = n0; n < n0 + 16; n++) {
        int b = batch[n];
        if (b != curg) {
            atomicMax(&g[curg * HDIM + f], __float_as_uint(m));
            curg = b;
            m = 0.0f;
        }
        m = fmaxf(m, (float)h[(size_t)n * HDIM + f]);
    }
    atomicMax(&g[curg * HDIM + f], __float_as_uint(m));
}

// -------------------------------------------------------------------- MLP head
__global__ __launch_bounds__(64) void mlp_kernel(const unsigned* __restrict__ g,
                                                 const float* __restrict__ wl1,
                                                 const float* __restrict__ bl1,
                                                 const float* __restrict__ wl2,
                                                 const float* __restrict__ bl2,
                                                 float* __restrict__ out) {
    int t = threadIdx.x;   // graph index, one block of 64
    float gv[HDIM];
#pragma unroll
    for (int k = 0; k < HDIM; k++) gv[k] = __uint_as_float(g[t * HDIM + k]);
    float o = bl2[0];
#pragma unroll
    for (int j = 0; j < 5; j++) {
        float hj = bl1[j];
#pragma unroll
        for (int k = 0; k < HDIM; k++) hj += gv[k] * wl1[k * 5 + j];
        hj = fmaxf(hj, 0.0f);
        o += hj * wl2[j];
    }
    out[t] = o;
}

// ------------------------------------------------------------------- launch
extern "C" void kernel_launch(void* const* d_in, const int* in_sizes, int n_in,
                              void* d_out, int out_size, void* d_ws, size_t ws_size,
                              hipStream_t stream) {
    const float* x   = (const float*)d_in[0];
    const int*   ei  = (const int*)d_in[1];
    const int*   bat = (const int*)d_in[2];
    const float* w1s = (const float*)d_in[3];
    const float* b1s = (const float*)d_in[4];
    const float* w1d = (const float*)d_in[5];
    const float* b1d = (const float*)d_in[6];
    const float* w2s = (const float*)d_in[7];
    const float* b2s = (const float*)d_in[8];
    const float* w2d = (const float*)d_in[9];
    const float* b2d = (const float*)d_in[10];
    const float* w3s = (const float*)d_in[11];
    const float* b3s = (const float*)d_in[12];
    const float* w3d = (const float*)d_in[13];
    const float* b3d = (const float*)d_in[14];
    const float* wl1 = (const float*)d_in[15];
    const float* bl1 = (const float*)d_in[16];
    const float* wl2 = (const float*)d_in[17];
    const float* bl2 = (const float*)d_in[18];
    float* out = (float*)d_out;

    // Workspace carve-up (16B-aligned chunks). bktA/bktT alias hA: buckets are
    // dead before the first layer_kernel writes hA (hA fp16 = 12.8MB fits).
    char* p = (char*)d_ws;
    int*   deg_out = (int*)p;              p += N_NODES * 4;
    int*   deg_in  = (int*)p;              p += N_NODES * 4;
    int*   rowptrP = (int*)p;              p += N_NODES * 4;
    int*   colptrP = (int*)p;              p += N_NODES * 4;
    float* r_out   = (float*)p;            p += N_NODES * 4;
    float* r_in    = (float*)p;            p += N_NODES * 4;
    int*   cntTabA = (int*)p;              p += (size_t)NB * NBLK * 4;
    int*   cntTabT = (int*)p;              p += (size_t)NB * NBLK * 4;
    int*   totTab  = (int*)p;              p += 1024 * 4;
    int*   bktStartA = (int*)p;            p += 512 * 4;
    int*   bktStartT = (int*)p;            p += 512 * 4;
    int*   padSum  = (int*)p;              p += 1024 * 4;
    int*   padStart = (int*)p;             p += 1024 * 4;
    int2*  recA    = (int2*)p;             p += (size_t)EPAD * 8;
    int2*  recT    = (int2*)p;             p += (size_t)EPAD * 8;
    int2*  bktA    = (int2*)p;             // aliased with hA (fp16)
    h16*   hA      = (h16*)p;
    int2*  bktT    = (int2*)((char*)bktA + (size_t)N_EDGES * 8);
    p = (char*)bktA + 2 * (size_t)N_EDGES * 8;   // 25.6MB region (hA uses 12.8)
    h16*   hB      = (h16*)p;              p += (size_t)N_NODES * HDIM * 2;
    h16*   xh      = (h16*)p;              p += (size_t)N_NODES * HDIM * 2;
    unsigned* g    = (unsigned*)p;         p += NGRAPH * HDIM * 4;

    hipMemsetAsync(g, 0, NGRAPH * HDIM * 4, stream);

    cast_kernel<<<(N_NODES * 16 + 255) / 256, 256, 0, stream>>>(
        (const float4*)x, (h16x4*)xh);

    bucket_count<<<NBLK, 512, 0, stream>>>(ei, cntTabA, cntTabT);
    dim3 gb2(NB, 2);
    chunk_scan<<<gb2, 256, 0, stream>>>(cntTabA, cntTabT, totTab);
    start_scan<<<1, 512, 0, stream>>>(totTab, bktStartA, bktStartT);
    bucketize_write<<<NBLK, 512, 0, stream>>>(ei, cntTabA, cntTabT,
                                              bktStartA, bktStartT, bktA, bktT);

    dim3 gb(NB, 2);
    bucket_deg<<<gb, 256, 0, stream>>>(bktStartA, bktStartT, bktA, bktT,
                                       deg_out, deg_in, r_out, r_in, padSum);
    pad_scan<<<1, 512, 0, stream>>>(padSum, padStart);
    node_ptr<<<gb, 256, 0, stream>>>(padStart, deg_out, deg_in, rowptrP, colptrP);
    bucket_scatter<<<gb, 512, 0, stream>>>(
        rowptrP, colptrP, r_out, r_in, bktStartA, bktStartT, bktA, bktT, recA, recT);

    // Three fused conv layers: xh -> hA -> hB -> hA
    layer_kernel<<<N_NODES / BLK_NODES, 512, 0, stream>>>(
        xh, hA, rowptrP, deg_out, recA, colptrP, deg_in, recT, w1s, b1s, w1d, b1d);
    layer_kernel<<<N_NODES / BLK_NODES, 512, 0, stream>>>(
        hA, hB, rowptrP, deg_out, recA, colptrP, deg_in, recT, w2s, b2s, w2d, b2d);
    layer_kernel<<<N_NODES / BLK_NODES, 512, 0, stream>>>(
        hB, hA, rowptrP, deg_out, recA, colptrP, deg_in, recT, w3s, b3s, w3d, b3d);

    const int pool_threads = (N_NODES / 16) * 64;   // 400000
    pool_kernel<<<(pool_threads + 255) / 256, 256, 0, stream>>>(hA, bat, g);

    mlp_kernel<<<1, 64, 0, stream>>>(g, wl1, bl1, wl2, bl2, out);
}

// Round 11
// 526.842 us; speedup vs baseline: 1.3215x; 1.0147x over previous
//
#include <hip/hip_runtime.h>

// Problem constants
#define N_NODES 100000
#define N_EDGES 1600000
#define EPAD    (N_EDGES + N_NODES)      // padded record capacity (even starts)
#define HDIM    64
#define NGRAPH  64
#define BLK_NODES 8
#define ALPHA_C 0.5f
#define BETA_C  0.5f
#define BW      256                      // bucket width (nodes); shift = 8
#define NB      391                      // ceil(N_NODES / BW)
#define NBLK    256                      // edge-pass blocks
#define CHUNK   ((N_EDGES + NBLK - 1) / NBLK)

// native fp16, no hip_fp16 header
typedef _Float16 h16;
typedef _Float16 h16x4 __attribute__((ext_vector_type(4)));

// ----------------------------------------- K1: per-(block,bucket) edge counts
__global__ __launch_bounds__(512) void bucket_count(const int* __restrict__ ei,
                                                    int* __restrict__ cntTabA,
                                                    int* __restrict__ cntTabT) {
    __shared__ int cA[NB], cT[NB];
    const int tid = threadIdx.x;
    for (int i = tid; i < NB; i += 512) { cA[i] = 0; cT[i] = 0; }
    __syncthreads();
    const int e0 = blockIdx.x * CHUNK, e1 = min(e0 + CHUNK, N_EDGES);
    for (int e = e0 + tid; e < e1; e += 512) {
        int r = ei[e];
        int c = ei[N_EDGES + e];
        atomicAdd(&cA[r >> 8], 1);
        atomicAdd(&cT[c >> 8], 1);
    }
    __syncthreads();
    for (int b = tid; b < NB; b += 512) {
        cntTabA[b * NBLK + blockIdx.x] = cA[b];
        cntTabT[b * NBLK + blockIdx.x] = cT[b];
    }
}

// ---------------- K2a: per-bucket LDS scan of the 256 per-block counts
__global__ __launch_bounds__(256) void chunk_scan(int* __restrict__ cntTabA,
                                                  int* __restrict__ cntTabT,
                                                  int* __restrict__ tot) {
    __shared__ int s[256];
    const int b = blockIdx.x, d = blockIdx.y, tid = threadIdx.x;
    int* tab = d ? cntTabT : cntTabA;
    int v = tab[b * NBLK + tid];
    s[tid] = v;
    __syncthreads();
    for (int off = 1; off < 256; off <<= 1) {
        int t = (tid >= off) ? s[tid - off] : 0;
        __syncthreads();
        s[tid] += t;
        __syncthreads();
    }
    tab[b * NBLK + tid] = s[tid] - v;       // exclusive within bucket
    if (tid == 255) tot[d * 512 + b] = s[255];
}

// ---------------- K2b: bucket-start scan (both dirs, one block, parallel)
__global__ __launch_bounds__(512) void start_scan(const int* __restrict__ tot,
                                                  int* __restrict__ bktStartA,
                                                  int* __restrict__ bktStartT) {
    __shared__ int s[512];
    const int tid = threadIdx.x;
    int v = (tid < NB) ? tot[tid] : 0;
    s[tid] = v;
    __syncthreads();
    for (int off = 1; off < 512; off <<= 1) {
        int t = (tid >= off) ? s[tid - off] : 0;
        __syncthreads();
        s[tid] += t;
        __syncthreads();
    }
    if (tid < NB) bktStartA[tid] = s[tid] - v;
    if (tid == 0) bktStartA[NB] = N_EDGES;
    __syncthreads();
    int v2 = (tid < NB) ? tot[512 + tid] : 0;
    s[tid] = v2;
    __syncthreads();
    for (int off = 1; off < 512; off <<= 1) {
        int t = (tid >= off) ? s[tid - off] : 0;
        __syncthreads();
        s[tid] += t;
        __syncthreads();
    }
    if (tid < NB) bktStartT[tid] = s[tid] - v2;
    if (tid == 0) bktStartT[NB] = N_EDGES;
}

// --------------------------- K3: bucketize write (bases pre-reserved)
__global__ __launch_bounds__(512) void bucketize_write(const int* __restrict__ ei,
                                                       const int* __restrict__ cntTabA,
                                                       const int* __restrict__ cntTabT,
                                                       const int* __restrict__ bktStartA,
                                                       const int* __restrict__ bktStartT,
                                                       int2* __restrict__ bktA,
                                                       int2* __restrict__ bktT) {
    __shared__ int bA[NB], bT[NB];
    const int tid = threadIdx.x;
    for (int i = tid; i < NB; i += 512) {
        bA[i] = bktStartA[i] + cntTabA[i * NBLK + blockIdx.x];
        bT[i] = bktStartT[i] + cntTabT[i * NBLK + blockIdx.x];
    }
    __syncthreads();
    const int e0 = blockIdx.x * CHUNK, e1 = min(e0 + CHUNK, N_EDGES);
    for (int e = e0 + tid; e < e1; e += 512) {
        int r = ei[e];
        int c = ei[N_EDGES + e];
        int pA = atomicAdd(&bA[r >> 8], 1);
        bktA[pA] = make_int2(r, c);          // (target, source)
        int pT = atomicAdd(&bT[c >> 8], 1);
        bktT[pT] = make_int2(c, r);          // (target, source)
    }
}

// ------------------- K4: per-bucket degrees + rsqrt norms + padded-size reduce
__global__ __launch_bounds__(256) void bucket_deg(const int* __restrict__ bktStartA,
                                                  const int* __restrict__ bktStartT,
                                                  const int2* __restrict__ bktA,
                                                  const int2* __restrict__ bktT,
                                                  int* __restrict__ deg_out,
                                                  int* __restrict__ deg_in,
                                                  float* __restrict__ r_out,
                                                  float* __restrict__ r_in,
                                                  int* __restrict__ padSum) {
    __shared__ int c[BW];
    __shared__ int red[256];
    const int b = blockIdx.x, d = blockIdx.y, tid = threadIdx.x;
    const int* bs = d ? bktStartT : bktStartA;
    const int2* bkt = d ? bktT : bktA;
    int* deg = d ? deg_in : deg_out;
    float* rr = d ? r_in : r_out;
    const int node0 = b * BW;
    c[tid] = 0;
    __syncthreads();
    const int i0 = bs[b], i1 = bs[b + 1];
    for (int i = i0 + tid; i < i1; i += 256) atomicAdd(&c[bkt[i].x - node0], 1);
    __syncthreads();
    int n = node0 + tid, dg = c[tid], pad = 0;
    if (n < N_NODES) {
        deg[n] = dg;
        rr[n] = dg > 0 ? rsqrtf((float)dg) : 0.0f;
        pad = dg + (dg & 1);
    }
    red[tid] = pad;
    __syncthreads();
    for (int off = 128; off > 0; off >>= 1) {
        if (tid < off) red[tid] += red[tid + off];
        __syncthreads();
    }
    if (tid == 0) padSum[d * 512 + b] = red[0];
}

// ---------------- K5: padded bucket-start scan (both dirs, one block, parallel)
__global__ __launch_bounds__(512) void pad_scan(const int* __restrict__ padSum,
                                                int* __restrict__ padStart) {
    __shared__ int s[512];
    const int tid = threadIdx.x;
    int v = (tid < NB) ? padSum[tid] : 0;
    s[tid] = v;
    __syncthreads();
    for (int off = 1; off < 512; off <<= 1) {
        int t = (tid >= off) ? s[tid - off] : 0;
        __syncthreads();
        s[tid] += t;
        __syncthreads();
    }
    if (tid < NB) padStart[tid] = s[tid] - v;
    __syncthreads();
    int v2 = (tid < NB) ? padSum[512 + tid] : 0;
    s[tid] = v2;
    __syncthreads();
    for (int off = 1; off < 512; off <<= 1) {
        int t = (tid >= off) ? s[tid - off] : 0;
        __syncthreads();
        s[tid] += t;
        __syncthreads();
    }
    if (tid < NB) padStart[512 + tid] = s[tid] - v2;
}

// ----------------------- K6: per-node padded CSR offsets (per-bucket LDS scan)
__global__ __launch_bounds__(256) void node_ptr(const int* __restrict__ padStart,
                                                const int* __restrict__ deg_out,
                                                const int* __restrict__ deg_in,
                                                int* __restrict__ rowptrP,
                                                int* __restrict__ colptrP) {
    __shared__ int s[256];
    const int b = blockIdx.x, d = blockIdx.y, tid = threadIdx.x;
    const int* deg = d ? deg_in : deg_out;
    int* ptr = d ? colptrP : rowptrP;
    int n = b * BW + tid;
    int pad = 0;
    if (n < N_NODES) { int dg = deg[n]; pad = dg + (dg & 1); }
    s[tid] = pad;
    __syncthreads();
    for (int off = 1; off < 256; off <<= 1) {
        int t = (tid >= off) ? s[tid - off] : 0;
        __syncthreads();
        s[tid] += t;
        __syncthreads();
    }
    if (n < N_NODES) ptr[n] = padStart[d * 512 + b] + s[tid] - pad;
}

// ------------------------------------- K7: within-bucket counting scatter
// record payload: (src byte-offset = src<<7, w fp32 bits) — the layer consumes
// the offset directly (one v_add per gather, no mul/shift/64-bit chain).
__global__ __launch_bounds__(512) void bucket_scatter(
        const int* __restrict__ rowptrP, const int* __restrict__ colptrP,
        const float* __restrict__ r_out, const float* __restrict__ r_in,
        const int* __restrict__ bktStartA, const int* __restrict__ bktStartT,
        const int2* __restrict__ bktA, const int2* __restrict__ bktT,
        int2* __restrict__ recA, int2* __restrict__ recT) {
    __shared__ int cur[BW];
    __shared__ float rwt[BW];
    const int b = blockIdx.x, d = blockIdx.y, tid = threadIdx.x;
    const int* ptr = d ? colptrP : rowptrP;
    const float* rt = d ? r_in : r_out;       // target-side scale (bucket-local)
    const float* rs = d ? r_out : r_in;       // source-side scale (gathered)
    const int* bs = d ? bktStartT : bktStartA;
    const int2* bkt = d ? bktT : bktA;
    int2* rec = d ? recT : recA;
    const int node0 = b * BW;
    if (tid < BW) {
        int n = node0 + tid;
        cur[tid] = (n < N_NODES) ? ptr[n] : 0;
        rwt[tid] = (n < N_NODES) ? rt[n] : 0.0f;
    }
    __syncthreads();
    const int i0 = bs[b], i1 = bs[b + 1];
    for (int i = i0 + tid; i < i1; i += 512) {
        int2 e = bkt[i];
        float w = rwt[e.x - node0] * rs[e.y];
        int p = atomicAdd(&cur[e.x - node0], 1);
        rec[p] = make_int2(e.y << 7, __float_as_int(w));   // byte offset, weight
    }
}

// ---------------------------------------------------- x -> fp16 cast
__global__ __launch_bounds__(256) void cast_kernel(const float4* __restrict__ x,
                                                   h16x4* __restrict__ xh) {
    int i = blockIdx.x * 256 + threadIdx.x;   // over N*64/4 float4s
    if (i < N_NODES * 16) {
        float4 v = x[i];
        h16x4 o;
        o.x = (h16)v.x; o.y = (h16)v.y; o.z = (h16)v.z; o.w = (h16)v.w;
        xh[i] = o;
    }
}

// -------------------------------------------------------------- fused layer
__device__ __forceinline__ void fma4(float4& a, float w, const float4& f) {
    a.x = fmaf(w, f.x, a.x); a.y = fmaf(w, f.y, a.y);
    a.z = fmaf(w, f.z, a.z); a.w = fmaf(w, f.w, a.w);
}

// mixed-precision accumulate: fp16 operand, fp32 accumulator (v_fma_mix_f32)
__device__ __forceinline__ void fma4h(float4& a, float w, h16x4 f) {
    a.x = fmaf(w, (float)f.x, a.x);
    a.y = fmaf(w, (float)f.y, a.y);
    a.z = fmaf(w, (float)f.z, a.z);
    a.w = fmaf(w, (float)f.w, a.w);
}

__device__ __forceinline__ float4 red_s(float4 v) {
    v.x += __shfl_xor(v.x, 16); v.y += __shfl_xor(v.y, 16);
    v.z += __shfl_xor(v.z, 16); v.w += __shfl_xor(v.w, 16);
    v.x += __shfl_xor(v.x, 32); v.y += __shfl_xor(v.y, 32);
    v.z += __shfl_xor(v.z, 32); v.w += __shfl_xor(v.w, 32);
    return v;
}

__device__ __forceinline__ h16x4 ld_h4(const char* __restrict__ p) {
    return *(const h16x4*)p;
}

// per-wave aggregation; lane (q,s): q = feature quad, s = edge-pair slot.
// records are (src-byte-offset, w) int2; node runs start 16B-aligned (padded
// CSR) so each slot loads 2 records with one int4. 16-edge unroll: 2 record
// loads + 4 independent 8B gathers in flight per thread.
__device__ __forceinline__ float4 agg_dir(const char* __restrict__ hb,
                                          const int2* __restrict__ rec,
                                          int start, int deg, int q, int s) {
    float4 a0 = {0.f,0.f,0.f,0.f}, a1 = {0.f,0.f,0.f,0.f};
    float4 a2 = {0.f,0.f,0.f,0.f}, a3 = {0.f,0.f,0.f,0.f};
    const int4* rec4 = (const int4*)(rec + start);
    const int qb = q * 8;                     // byte offset of this feature quad
    int k = 0;
    for (; k + 16 <= deg; k += 16) {
        int4 p0 = rec4[(k >> 1) + s];         // edges k+2s, k+2s+1
        int4 p1 = rec4[(k >> 1) + 4 + s];     // edges k+8+2s, k+8+2s+1
        h16x4 f0 = ld_h4(hb + p0.x + qb);
        h16x4 f1 = ld_h4(hb + p0.z + qb);
        h16x4 f2 = ld_h4(hb + p1.x + qb);
        h16x4 f3 = ld_h4(hb + p1.z + qb);
        fma4h(a0, __int_as_float(p0.y), f0);
        fma4h(a1, __int_as_float(p0.w), f1);
        fma4h(a2, __int_as_float(p1.y), f2);
        fma4h(a3, __int_as_float(p1.w), f3);
    }
    if (k + 8 <= deg) {
        int4 p = rec4[(k >> 1) + s];
        h16x4 f0 = ld_h4(hb + p.x + qb);
        h16x4 f1 = ld_h4(hb + p.z + qb);
        fma4h(a0, __int_as_float(p.y), f0);
        fma4h(a1, __int_as_float(p.w), f1);
        k += 8;
    }
    int r = deg - k;                          // 0..7 remaining
    if (2 * s < r) {
        int4 p = rec4[(k >> 1) + s];
        h16x4 f0 = ld_h4(hb + p.x + qb);
        fma4h(a2, __int_as_float(p.y), f0);
        if (2 * s + 1 < r) {
            h16x4 f1 = ld_h4(hb + p.z + qb);
            fma4h(a3, __int_as_float(p.w), f1);
        }
    }
    a0.x += a1.x; a0.y += a1.y; a0.z += a1.z; a0.w += a1.w;
    a2.x += a3.x; a2.y += a3.y; a2.z += a3.z; a2.w += a3.w;
    a0.x += a2.x; a0.y += a2.y; a0.z += a2.z; a0.w += a2.w;
    return red_s(a0);
}

__global__ __launch_bounds__(512, 8) void layer_kernel(
        const h16* __restrict__ h_in, h16* __restrict__ h_out,
        const int* __restrict__ rowptrP, const int* __restrict__ deg_out,
        const int2* __restrict__ recA,
        const int* __restrict__ colptrP, const int* __restrict__ deg_in,
        const int2* __restrict__ recT,
        const float* __restrict__ ws, const float* __restrict__ bs,
        const float* __restrict__ wd, const float* __restrict__ bd) {
    __shared__ float4 s_ws[HDIM * 16];                 // [k][q] 16KB
    __shared__ float4 s_wd[HDIM * 16];                 // 16KB
    __shared__ float4 s_accv[BLK_NODES][2][16];        // 4KB

    const int tid  = threadIdx.x;
    const int wave = tid >> 6;
    const int lane = tid & 63;
    const int q = lane & 15;
    const int s = lane >> 4;
    const int node = blockIdx.x * BLK_NODES + wave;

    // stage weights (1024 float4 each; 512 threads x 2)
    const float4* wsv = (const float4*)ws;
    const float4* wdv = (const float4*)wd;
    s_ws[tid] = wsv[tid]; s_ws[tid + 512] = wsv[tid + 512];
    s_wd[tid] = wdv[tid]; s_wd[tid + 512] = wdv[tid + 512];

    const char* hb = (const char*)h_in;
    float4 aA = agg_dir(hb, recA, rowptrP[node], deg_out[node], q, s);
    if (s == 0) s_accv[wave][0][q] = aA;
    float4 aT = agg_dir(hb, recT, colptrP[node], deg_in[node], q, s);
    if (s == 0) s_accv[wave][1][q] = aT;

    __syncthreads();

    // GEMM epilogue: thread -> feats 4q..4q+3 of its node, k in [16s, 16s+16)
    const float* accA = (const float*)&s_accv[wave][0][0];
    const float* accT = (const float*)&s_accv[wave][1][0];
    float4 oA = {0.f,0.f,0.f,0.f}, oT = {0.f,0.f,0.f,0.f};
    const int k0 = s * 16;
#pragma unroll
    for (int i = 0; i < 16; i++) {
        int k = k0 + i;
        float vA = accA[k];
        float vT = accT[k];
        float4 wA = s_ws[k * 16 + q];
        float4 wT = s_wd[k * 16 + q];
        fma4(oA, vA, wA);
        fma4(oT, vT, wT);
    }
    float4 o;
    o.x = ALPHA_C * oA.x + BETA_C * oT.x;
    o.y = ALPHA_C * oA.y + BETA_C * oT.y;
    o.z = ALPHA_C * oA.z + BETA_C * oT.z;
    o.w = ALPHA_C * oA.w + BETA_C * oT.w;
    o = red_s(o);
    if (s == 0) {
        float4 bA = ((const float4*)bs)[q];
        float4 bD = ((const float4*)bd)[q];
        o.x = fmaxf(o.x + ALPHA_C * bA.x + BETA_C * bD.x, 0.0f);
        o.y = fmaxf(o.y + ALPHA_C * bA.y + BETA_C * bD.y, 0.0f);
        o.z = fmaxf(o.z + ALPHA_C * bA.z + BETA_C * bD.z, 0.0f);
        o.w = fmaxf(o.w + ALPHA_C * bA.w + BETA_C * bD.w, 0.0f);
        h16x4 st;
        st.x = (h16)o.x; st.y = (h16)o.y; st.z = (h16)o.z; st.w = (h16)o.w;
        *(h16x4*)(h_out + (size_t)node * 64 + q * 4) = st;
    }
}

// ---------------------------------------------------------------- max pool
__global__ __launch_bounds__(256) void pool_kernel(const h16* __restrict__ h,
                                                   const int* __restrict__ batch,
                                                   unsigned* __restrict__ g) {
    int t = blockIdx.x * 256 + threadIdx.x;
    const int ngroups = N_NODES / 16;   // 6250
    if (t >= ngroups * 64) return;
    int f = t & 63;
    int n0 = (t >> 6) * 16;
    int curg = batch[n0];
    float m = 0.0f;                      // post-ReLU values are >= 0
    for (int n = n0; n < n0 + 16; n++) {
        int b = batch[n];
        if (b != curg) {
            atomicMax(&g[curg * HDIM + f], __float_as_uint(m));
            curg = b;
            m = 0.0f;
        }
        m = fmaxf(m, (float)h[(size_t)n * HDIM + f]);
    }
    atomicMax(&g[curg * HDIM + f], __float_as_uint(m));
}

// -------------------------------------------------------------------- MLP head
__global__ __launch_bounds__(64) void mlp_kernel(const unsigned* __restrict__ g,
                                                 const float* __restrict__ wl1,
                                                 const float* __restrict__ bl1,
                                                 const float* __restrict__ wl2,
                                                 const float* __restrict__ bl2,
                                                 float* __restrict__ out) {
    int t = threadIdx.x;   // graph index, one block of 64
    float gv[HDIM];
#pragma unroll
    for (int k = 0; k < HDIM; k++) gv[k] = __uint_as_float(g[t * HDIM + k]);
    float o = bl2[0];
#pragma unroll
    for (int j = 0; j < 5; j++) {
        float hj = bl1[j];
#pragma unroll
        for (int k = 0; k < HDIM; k++) hj += gv[k] * wl1[k * 5 + j];
        hj = fmaxf(hj, 0.0f);
        o += hj * wl2[j];
    }
    out[t] = o;
}

// ------------------------------------------------------------------- launch
extern "C" void kernel_launch(void* const* d_in, const int* in_sizes, int n_in,
                              void* d_out, int out_size, void* d_ws, size_t ws_size,
                              hipStream_t stream) {
    const float* x   = (const float*)d_in[0];
    const int*   ei  = (const int*)d_in[1];
    const int*   bat = (const int*)d_in[2];
    const float* w1s = (const float*)d_in[3];
    const float* b1s = (const float*)d_in[4];
    const float* w1d = (const float*)d_in[5];
    const float* b1d = (const float*)d_in[6];
    const float* w2s = (const float*)d_in[7];
    const float* b2s = (const float*)d_in[8];
    const float* w2d = (const float*)d_in[9];
    const float* b2d = (const float*)d_in[10];
    const float* w3s = (const float*)d_in[11];
    const float* b3s = (const float*)d_in[12];
    const float* w3d = (const float*)d_in[13];
    const float* b3d = (const float*)d_in[14];
    const float* wl1 = (const float*)d_in[15];
    const float* bl1 = (const float*)d_in[16];
    const float* wl2 = (const float*)d_in[17];
    const float* bl2 = (const float*)d_in[18];
    float* out = (float*)d_out;

    // Workspace carve-up (16B-aligned chunks). bktA/bktT alias hA: buckets are
    // dead before the first layer_kernel writes hA (hA fp16 = 12.8MB fits).
    char* p = (char*)d_ws;
    int*   deg_out = (int*)p;              p += N_NODES * 4;
    int*   deg_in  = (int*)p;              p += N_NODES * 4;
    int*   rowptrP = (int*)p;              p += N_NODES * 4;
    int*   colptrP = (int*)p;              p += N_NODES * 4;
    float* r_out   = (float*)p;            p += N_NODES * 4;
    float* r_in    = (float*)p;            p += N_NODES * 4;
    int*   cntTabA = (int*)p;              p += (size_t)NB * NBLK * 4;
    int*   cntTabT = (int*)p;              p += (size_t)NB * NBLK * 4;
    int*   totTab  = (int*)p;              p += 1024 * 4;
    int*   bktStartA = (int*)p;            p += 512 * 4;
    int*   bktStartT = (int*)p;            p += 512 * 4;
    int*   padSum  = (int*)p;              p += 1024 * 4;
    int*   padStart = (int*)p;             p += 1024 * 4;
    int2*  recA    = (int2*)p;             p += (size_t)EPAD * 8;
    int2*  recT    = (int2*)p;             p += (size_t)EPAD * 8;
    int2*  bktA    = (int2*)p;             // aliased with hA (fp16)
    h16*   hA      = (h16*)p;
    int2*  bktT    = (int2*)((char*)bktA + (size_t)N_EDGES * 8);
    p = (char*)bktA + 2 * (size_t)N_EDGES * 8;   // 25.6MB region (hA uses 12.8)
    h16*   hB      = (h16*)p;              p += (size_t)N_NODES * HDIM * 2;
    h16*   xh      = (h16*)p;              p += (size_t)N_NODES * HDIM * 2;
    unsigned* g    = (unsigned*)p;         p += NGRAPH * HDIM * 4;

    hipMemsetAsync(g, 0, NGRAPH * HDIM * 4, stream);

    cast_kernel<<<(N_NODES * 16 + 255) / 256, 256, 0, stream>>>(
        (const float4*)x, (h16x4*)xh);

    bucket_count<<<NBLK, 512, 0, stream>>>(ei, cntTabA, cntTabT);
    dim3 gb2(NB, 2);
    chunk_scan<<<gb2, 256, 0, stream>>>(cntTabA, cntTabT, totTab);
    start_scan<<<1, 512, 0, stream>>>(totTab, bktStartA, bktStartT);
    bucketize_write<<<NBLK, 512, 0, stream>>>(ei, cntTabA, cntTabT,
                                              bktStartA, bktStartT, bktA, bktT);

    dim3 gb(NB, 2);
    bucket_deg<<<gb, 256, 0, stream>>>(bktStartA, bktStartT, bktA, bktT,
                                       deg_out, deg_in, r_out, r_in, padSum);
    pad_scan<<<1, 512, 0, stream>>>(padSum, padStart);
    node_ptr<<<gb, 256, 0, stream>>>(padStart, deg_out, deg_in, rowptrP, colptrP);
    bucket_scatter<<<gb, 512, 0, stream>>>(
        rowptrP, colptrP, r_out, r_in, bktStartA, bktStartT, bktA, bktT, recA, recT);

    // Three fused conv layers: xh -> hA -> hB -> hA
    layer_kernel<<<N_NODES / BLK_NODES, 512, 0, stream>>>(
        xh, hA, rowptrP, deg_out, recA, colptrP, deg_in, recT, w1s, b1s, w1d, b1d);
    layer_kernel<<<N_NODES / BLK_NODES, 512, 0, stream>>>(
        hA, hB, rowptrP, deg_out, recA, colptrP, deg_in, recT, w2s, b2s, w2d, b2d);
    layer_kernel<<<N_NODES / BLK_NODES, 512, 0, stream>>>(
        hB, hA, rowptrP, deg_out, recA, colptrP, deg_in, recT, w3s, b3s, w3d, b3d);

    const int pool_threads = (N_NODES / 16) * 64;   // 400000
    pool_kernel<<<(pool_threads + 255) / 256, 256, 0, stream>>>(hA, bat, g);

    mlp_kernel<<<1, 64, 0, stream>>>(g, wl1, bl1, wl2, bl2, out);
}

// Round 12
// 504.784 us; speedup vs baseline: 1.3792x; 1.0437x over previous
//
#include <hip/hip_runtime.h>

// Problem constants
#define N_NODES 100000
#define N_EDGES 1600000
#define EPAD    (N_EDGES + N_NODES)      // padded record capacity (even starts)
#define HDIM    64
#define NGRAPH  64
#define BLK_NODES 8
#define BW      256                      // bucket width (nodes); shift = 8
#define NB      391                      // ceil(N_NODES / BW)
#define NBLK    256                      // edge-pass blocks
#define CHUNK   ((N_EDGES + NBLK - 1) / NBLK)
#define MTILES  (N_NODES / 16)           // 6250 GEMM m-tiles

// native fp16, no hip_fp16 header
typedef _Float16 h16;
typedef _Float16 h16x4 __attribute__((ext_vector_type(4)));
typedef _Float16 h16x8 __attribute__((ext_vector_type(8)));
typedef float    f32x4 __attribute__((ext_vector_type(4)));

// ----------------------------------------- K1: per-(block,bucket) edge counts
__global__ __launch_bounds__(512) void bucket_count(const int* __restrict__ ei,
                                                    int* __restrict__ cntTabA,
                                                    int* __restrict__ cntTabT) {
    __shared__ int cA[NB], cT[NB];
    const int tid = threadIdx.x;
    for (int i = tid; i < NB; i += 512) { cA[i] = 0; cT[i] = 0; }
    __syncthreads();
    const int e0 = blockIdx.x * CHUNK, e1 = min(e0 + CHUNK, N_EDGES);
    for (int e = e0 + tid; e < e1; e += 512) {
        int r = ei[e];
        int c = ei[N_EDGES + e];
        atomicAdd(&cA[r >> 8], 1);
        atomicAdd(&cT[c >> 8], 1);
    }
    __syncthreads();
    for (int b = tid; b < NB; b += 512) {
        cntTabA[b * NBLK + blockIdx.x] = cA[b];
        cntTabT[b * NBLK + blockIdx.x] = cT[b];
    }
}

// ---------------- K2a: per-bucket LDS scan of the 256 per-block counts
__global__ __launch_bounds__(256) void chunk_scan(int* __restrict__ cntTabA,
                                                  int* __restrict__ cntTabT,
                                                  int* __restrict__ tot) {
    __shared__ int s[256];
    const int b = blockIdx.x, d = blockIdx.y, tid = threadIdx.x;
    int* tab = d ? cntTabT : cntTabA;
    int v = tab[b * NBLK + tid];
    s[tid] = v;
    __syncthreads();
    for (int off = 1; off < 256; off <<= 1) {
        int t = (tid >= off) ? s[tid - off] : 0;
        __syncthreads();
        s[tid] += t;
        __syncthreads();
    }
    tab[b * NBLK + tid] = s[tid] - v;       // exclusive within bucket
    if (tid == 255) tot[d * 512 + b] = s[255];
}

// ---------------- K2b: bucket-start scan (both dirs, one block, parallel)
__global__ __launch_bounds__(512) void start_scan(const int* __restrict__ tot,
                                                  int* __restrict__ bktStartA,
                                                  int* __restrict__ bktStartT) {
    __shared__ int s[512];
    const int tid = threadIdx.x;
    int v = (tid < NB) ? tot[tid] : 0;
    s[tid] = v;
    __syncthreads();
    for (int off = 1; off < 512; off <<= 1) {
        int t = (tid >= off) ? s[tid - off] : 0;
        __syncthreads();
        s[tid] += t;
        __syncthreads();
    }
    if (tid < NB) bktStartA[tid] = s[tid] - v;
    if (tid == 0) bktStartA[NB] = N_EDGES;
    __syncthreads();
    int v2 = (tid < NB) ? tot[512 + tid] : 0;
    s[tid] = v2;
    __syncthreads();
    for (int off = 1; off < 512; off <<= 1) {
        int t = (tid >= off) ? s[tid - off] : 0;
        __syncthreads();
        s[tid] += t;
        __syncthreads();
    }
    if (tid < NB) bktStartT[tid] = s[tid] - v2;
    if (tid == 0) bktStartT[NB] = N_EDGES;
}

// --------------------------- K3: bucketize write (bases pre-reserved)
__global__ __launch_bounds__(512) void bucketize_write(const int* __restrict__ ei,
                                                       const int* __restrict__ cntTabA,
                                                       const int* __restrict__ cntTabT,
                                                       const int* __restrict__ bktStartA,
                                                       const int* __restrict__ bktStartT,
                                                       int2* __restrict__ bktA,
                                                       int2* __restrict__ bktT) {
    __shared__ int bA[NB], bT[NB];
    const int tid = threadIdx.x;
    for (int i = tid; i < NB; i += 512) {
        bA[i] = bktStartA[i] + cntTabA[i * NBLK + blockIdx.x];
        bT[i] = bktStartT[i] + cntTabT[i * NBLK + blockIdx.x];
    }
    __syncthreads();
    const int e0 = blockIdx.x * CHUNK, e1 = min(e0 + CHUNK, N_EDGES);
    for (int e = e0 + tid; e < e1; e += 512) {
        int r = ei[e];
        int c = ei[N_EDGES + e];
        int pA = atomicAdd(&bA[r >> 8], 1);
        bktA[pA] = make_int2(r, c);          // (target, source)
        int pT = atomicAdd(&bT[c >> 8], 1);
        bktT[pT] = make_int2(c, r);          // (target, source)
    }
}

// ------------------- K4: per-bucket degrees + rsqrt norms + padded-size reduce
__global__ __launch_bounds__(256) void bucket_deg(const int* __restrict__ bktStartA,
                                                  const int* __restrict__ bktStartT,
                                                  const int2* __restrict__ bktA,
                                                  const int2* __restrict__ bktT,
                                                  int* __restrict__ deg_out,
                                                  int* __restrict__ deg_in,
                                                  float* __restrict__ r_out,
                                                  float* __restrict__ r_in,
                                                  int* __restrict__ padSum) {
    __shared__ int c[BW];
    __shared__ int red[256];
    const int b = blockIdx.x, d = blockIdx.y, tid = threadIdx.x;
    const int* bs = d ? bktStartT : bktStartA;
    const int2* bkt = d ? bktT : bktA;
    int* deg = d ? deg_in : deg_out;
    float* rr = d ? r_in : r_out;
    const int node0 = b * BW;
    c[tid] = 0;
    __syncthreads();
    const int i0 = bs[b], i1 = bs[b + 1];
    for (int i = i0 + tid; i < i1; i += 256) atomicAdd(&c[bkt[i].x - node0], 1);
    __syncthreads();
    int n = node0 + tid, dg = c[tid], pad = 0;
    if (n < N_NODES) {
        deg[n] = dg;
        rr[n] = dg > 0 ? rsqrtf((float)dg) : 0.0f;
        pad = dg + (dg & 1);
    }
    red[tid] = pad;
    __syncthreads();
    for (int off = 128; off > 0; off >>= 1) {
        if (tid < off) red[tid] += red[tid + off];
        __syncthreads();
    }
    if (tid == 0) padSum[d * 512 + b] = red[0];
}

// ---------------- K5: padded bucket-start scan (both dirs, one block, parallel)
__global__ __launch_bounds__(512) void pad_scan(const int* __restrict__ padSum,
                                                int* __restrict__ padStart) {
    __shared__ int s[512];
    const int tid = threadIdx.x;
    int v = (tid < NB) ? padSum[tid] : 0;
    s[tid] = v;
    __syncthreads();
    for (int off = 1; off < 512; off <<= 1) {
        int t = (tid >= off) ? s[tid - off] : 0;
        __syncthreads();
        s[tid] += t;
        __syncthreads();
    }
    if (tid < NB) padStart[tid] = s[tid] - v;
    __syncthreads();
    int v2 = (tid < NB) ? padSum[512 + tid] : 0;
    s[tid] = v2;
    __syncthreads();
    for (int off = 1; off < 512; off <<= 1) {
        int t = (tid >= off) ? s[tid - off] : 0;
        __syncthreads();
        s[tid] += t;
        __syncthreads();
    }
    if (tid < NB) padStart[512 + tid] = s[tid] - v2;
}

// ----------------------- K6: per-node padded CSR offsets (per-bucket LDS scan)
__global__ __launch_bounds__(256) void node_ptr(const int* __restrict__ padStart,
                                                const int* __restrict__ deg_out,
                                                const int* __restrict__ deg_in,
                                                int* __restrict__ rowptrP,
                                                int* __restrict__ colptrP) {
    __shared__ int s[256];
    const int b = blockIdx.x, d = blockIdx.y, tid = threadIdx.x;
    const int* deg = d ? deg_in : deg_out;
    int* ptr = d ? colptrP : rowptrP;
    int n = b * BW + tid;
    int pad = 0;
    if (n < N_NODES) { int dg = deg[n]; pad = dg + (dg & 1); }
    s[tid] = pad;
    __syncthreads();
    for (int off = 1; off < 256; off <<= 1) {
        int t = (tid >= off) ? s[tid - off] : 0;
        __syncthreads();
        s[tid] += t;
        __syncthreads();
    }
    if (n < N_NODES) ptr[n] = padStart[d * 512 + b] + s[tid] - pad;
}

// ------------------------------------- K7: within-bucket counting scatter
// record payload: (src<<7, w fp32 bits)
__global__ __launch_bounds__(512) void bucket_scatter(
        const int* __restrict__ rowptrP, const int* __restrict__ colptrP,
        const float* __restrict__ r_out, const float* __restrict__ r_in,
        const int* __restrict__ bktStartA, const int* __restrict__ bktStartT,
        const int2* __restrict__ bktA, const int2* __restrict__ bktT,
        int2* __restrict__ recA, int2* __restrict__ recT) {
    __shared__ int cur[BW];
    __shared__ float rwt[BW];
    const int b = blockIdx.x, d = blockIdx.y, tid = threadIdx.x;
    const int* ptr = d ? colptrP : rowptrP;
    const float* rt = d ? r_in : r_out;       // target-side scale (bucket-local)
    const float* rs = d ? r_out : r_in;       // source-side scale (gathered)
    const int* bs = d ? bktStartT : bktStartA;
    const int2* bkt = d ? bktT : bktA;
    int2* rec = d ? recT : recA;
    const int node0 = b * BW;
    if (tid < BW) {
        int n = node0 + tid;
        cur[tid] = (n < N_NODES) ? ptr[n] : 0;
        rwt[tid] = (n < N_NODES) ? rt[n] : 0.0f;
    }
    __syncthreads();
    const int i0 = bs[b], i1 = bs[b + 1];
    for (int i = i0 + tid; i < i1; i += 512) {
        int2 e = bkt[i];
        float w = rwt[e.x - node0] * rs[e.y];
        int p = atomicAdd(&cur[e.x - node0], 1);
        rec[p] = make_int2(e.y << 7, __float_as_int(w));
    }
}

// ---------------------------------------------------- x -> fp16 cast
__global__ __launch_bounds__(256) void cast_kernel(const float4* __restrict__ x,
                                                   h16x4* __restrict__ xh) {
    int i = blockIdx.x * 256 + threadIdx.x;   // over N*64/4 float4s
    if (i < N_NODES * 16) {
        float4 v = x[i];
        h16x4 o;
        o.x = (h16)v.x; o.y = (h16)v.y; o.z = (h16)v.z; o.w = (h16)v.w;
        xh[i] = o;
    }
}

// ------------------------- weight prep: WT[l][f][k] = 0.5*Wcat^T fp16, bcat
__global__ __launch_bounds__(256) void wprep_kernel(
        const float* __restrict__ w1s, const float* __restrict__ w1d,
        const float* __restrict__ w2s, const float* __restrict__ w2d,
        const float* __restrict__ w3s, const float* __restrict__ w3d,
        const float* __restrict__ b1s, const float* __restrict__ b1d,
        const float* __restrict__ b2s, const float* __restrict__ b2d,
        const float* __restrict__ b3s, const float* __restrict__ b3d,
        h16* __restrict__ WT, float* __restrict__ bc) {
    const int l = blockIdx.y;
    const float* ws = l == 0 ? w1s : l == 1 ? w2s : w3s;
    const float* wd = l == 0 ? w1d : l == 1 ? w2d : w3d;
    int e = blockIdx.x * 256 + threadIdx.x;
    if (e < 8192) {
        int f = e >> 7, k = e & 127;
        float v = (k < 64) ? ws[k * 64 + f] : wd[(k - 64) * 64 + f];
        WT[l * 8192 + f * 128 + k] = (h16)(0.5f * v);
    }
    if (blockIdx.x == 0 && threadIdx.x < 64) {
        const float* bs = l == 0 ? b1s : l == 1 ? b2s : b3s;
        const float* bd = l == 0 ? b1d : l == 1 ? b2d : b3d;
        bc[l * 64 + threadIdx.x] = 0.5f * (bs[threadIdx.x] + bd[threadIdx.x]);
    }
}

// ------------------------------------------------ aggregation (LDS-free)
__device__ __forceinline__ void fma4h(float4& a, float w, h16x4 f) {
    a.x = fmaf(w, (float)f.x, a.x);
    a.y = fmaf(w, (float)f.y, a.y);
    a.z = fmaf(w, (float)f.z, a.z);
    a.w = fmaf(w, (float)f.w, a.w);
}

__device__ __forceinline__ float4 red_s(float4 v) {
    v.x += __shfl_xor(v.x, 16); v.y += __shfl_xor(v.y, 16);
    v.z += __shfl_xor(v.z, 16); v.w += __shfl_xor(v.w, 16);
    v.x += __shfl_xor(v.x, 32); v.y += __shfl_xor(v.y, 32);
    v.z += __shfl_xor(v.z, 32); v.w += __shfl_xor(v.w, 32);
    return v;
}

__device__ __forceinline__ h16x4 ld_h4(const char* __restrict__ p) {
    return *(const h16x4*)p;
}

// per-wave aggregation; lane (q,s): q = feature quad, s = edge-pair slot.
// records hold src<<7; sh=0 for 128B rows (xh), sh=1 for 256B rows (acc/h).
__device__ __forceinline__ float4 agg_dir(const char* __restrict__ hb,
                                          const int2* __restrict__ rec,
                                          int start, int deg, int q, int s, int sh) {
    float4 a0 = {0.f,0.f,0.f,0.f}, a1 = {0.f,0.f,0.f,0.f};
    float4 a2 = {0.f,0.f,0.f,0.f}, a3 = {0.f,0.f,0.f,0.f};
    const int4* rec4 = (const int4*)(rec + start);
    const int qb = q * 8;
    int k = 0;
    for (; k + 16 <= deg; k += 16) {
        int4 p0 = rec4[(k >> 1) + s];
        int4 p1 = rec4[(k >> 1) + 4 + s];
        h16x4 f0 = ld_h4(hb + (p0.x << sh) + qb);
        h16x4 f1 = ld_h4(hb + (p0.z << sh) + qb);
        h16x4 f2 = ld_h4(hb + (p1.x << sh) + qb);
        h16x4 f3 = ld_h4(hb + (p1.z << sh) + qb);
        fma4h(a0, __int_as_float(p0.y), f0);
        fma4h(a1, __int_as_float(p0.w), f1);
        fma4h(a2, __int_as_float(p1.y), f2);
        fma4h(a3, __int_as_float(p1.w), f3);
    }
    if (k + 8 <= deg) {
        int4 p = rec4[(k >> 1) + s];
        h16x4 f0 = ld_h4(hb + (p.x << sh) + qb);
        h16x4 f1 = ld_h4(hb + (p.z << sh) + qb);
        fma4h(a0, __int_as_float(p.y), f0);
        fma4h(a1, __int_as_float(p.w), f1);
        k += 8;
    }
    int r = deg - k;
    if (2 * s < r) {
        int4 p = rec4[(k >> 1) + s];
        h16x4 f0 = ld_h4(hb + (p.x << sh) + qb);
        fma4h(a2, __int_as_float(p.y), f0);
        if (2 * s + 1 < r) {
            h16x4 f1 = ld_h4(hb + (p.z << sh) + qb);
            fma4h(a3, __int_as_float(p.w), f1);
        }
    }
    a0.x += a1.x; a0.y += a1.y; a0.z += a1.z; a0.w += a1.w;
    a2.x += a3.x; a2.y += a3.y; a2.z += a3.z; a2.w += a3.w;
    a0.x += a2.x; a0.y += a2.y; a0.z += a2.z; a0.w += a2.w;
    return red_s(a0);
}

// no LDS, no barrier: gather both dirs, write acc fp16 [node][128] (A||T)
__global__ __launch_bounds__(512) void agg_kernel(
        const char* __restrict__ h_in, char* __restrict__ acc_out, int sh,
        const int* __restrict__ rowptrP, const int* __restrict__ deg_out,
        const int2* __restrict__ recA,
        const int* __restrict__ colptrP, const int* __restrict__ deg_in,
        const int2* __restrict__ recT) {
    const int tid  = threadIdx.x;
    const int wave = tid >> 6;
    const int lane = tid & 63;
    const int q = lane & 15;
    const int s = lane >> 4;
    const int node = blockIdx.x * BLK_NODES + wave;

    float4 aA = agg_dir(h_in, recA, rowptrP[node], deg_out[node], q, s, sh);
    float4 aT = agg_dir(h_in, recT, colptrP[node], deg_in[node], q, s, sh);
    if (s == 0) {
        h16x4 pA, pT;
        pA.x = (h16)aA.x; pA.y = (h16)aA.y; pA.z = (h16)aA.z; pA.w = (h16)aA.w;
        pT.x = (h16)aT.x; pT.y = (h16)aT.y; pT.z = (h16)aT.z; pT.w = (h16)aT.w;
        char* row = acc_out + (size_t)node * 256;
        *(h16x4*)(row + q * 8) = pA;
        *(h16x4*)(row + 128 + q * 8) = pT;
    }
}

// --------------------------------------- GEMM via MFMA, h written in place
// acc rows are 256B ([128] fp16); h = ReLU(acc @ WT^T + bc) written into the
// first 128B of each row. A: m=lane&15, k=(lane>>4)*8+j; B from WT[n][k]
// (n=lane&15); D: col=lane&15, row=(lane>>4)*4+reg.
__global__ __launch_bounds__(256) void gemm_kernel(char* __restrict__ acc,
                                                   const h16* __restrict__ WT,
                                                   const float* __restrict__ bc) {
    const int lane = threadIdx.x & 63;
    const int wid = (blockIdx.x * 256 + threadIdx.x) >> 6;
    const int nW = gridDim.x * 4;
    const int m = lane & 15, t = lane >> 4;

    h16x8 bfrag[4][4];
    float bb[4];
#pragma unroll
    for (int nt = 0; nt < 4; nt++) {
        bb[nt] = bc[nt * 16 + m];
#pragma unroll
        for (int kk = 0; kk < 4; kk++)
            bfrag[nt][kk] = *(const h16x8*)(WT + (nt * 16 + m) * 128 + kk * 32 + t * 8);
    }

    for (int tile = wid; tile < MTILES; tile += nW) {
        char* arow = acc + (size_t)tile * 16 * 256;
        h16x8 afrag[4];
#pragma unroll
        for (int kk = 0; kk < 4; kk++)
            afrag[kk] = *(const h16x8*)(arow + m * 256 + kk * 64 + t * 16);
#pragma unroll
        for (int nt = 0; nt < 4; nt++) {
            f32x4 c = {0.f, 0.f, 0.f, 0.f};
#pragma unroll
            for (int kk = 0; kk < 4; kk++)
                c = __builtin_amdgcn_mfma_f32_16x16x32_f16(afrag[kk], bfrag[nt][kk], c, 0, 0, 0);
#pragma unroll
            for (int r = 0; r < 4; r++) {
                float o = fmaxf(c[r] + bb[nt], 0.0f);
                *(h16*)(arow + (t * 4 + r) * 256 + (nt * 16 + m) * 2) = (h16)o;
            }
        }
    }
}

// ---------------------------------------------------------------- max pool
// h rows live in acc buffer: 128 halves per row (first 64 are h)
__global__ __launch_bounds__(256) void pool_kernel(const h16* __restrict__ h,
                                                   const int* __restrict__ batch,
                                                   unsigned* __restrict__ g) {
    int t = blockIdx.x * 256 + threadIdx.x;
    const int ngroups = N_NODES / 16;   // 6250
    if (t >= ngroups * 64) return;
    int f = t & 63;
    int n0 = (t >> 6) * 16;
    int curg = batch[n0];
    float m = 0.0f;                      // post-ReLU values are >= 0
    for (int n = n0; n < n0 + 16; n++) {
        int b = batch[n];
        if (b != curg) {
            atomicMax(&g[curg * HDIM + f], __float_as_uint(m));
            curg = b;
            m = 0.0f;
        }
        m = fmaxf(m, (float)h[(size_t)n * 128 + f]);
    }
    atomicMax(&g[curg * HDIM + f], __float_as_uint(m));
}

// -------------------------------------------------------------------- MLP head
__global__ __launch_bounds__(64) void mlp_kernel(const unsigned* __restrict__ g,
                                                 const float* __restrict__ wl1,
                                                 const float* __restrict__ bl1,
                                                 const float* __restrict__ wl2,
                                                 const float* __restrict__ bl2,
                                                 float* __restrict__ out) {
    int t = threadIdx.x;   // graph index, one block of 64
    float gv[HDIM];
#pragma unroll
    for (int k = 0; k < HDIM; k++) gv[k] = __uint_as_float(g[t * HDIM + k]);
    float o = bl2[0];
#pragma unroll
    for (int j = 0; j < 5; j++) {
        float hj = bl1[j];
#pragma unroll
        for (int k = 0; k < HDIM; k++) hj += gv[k] * wl1[k * 5 + j];
        hj = fmaxf(hj, 0.0f);
        o += hj * wl2[j];
    }
    out[t] = o;
}

// ------------------------------------------------------------------- launch
extern "C" void kernel_launch(void* const* d_in, const int* in_sizes, int n_in,
                              void* d_out, int out_size, void* d_ws, size_t ws_size,
                              hipStream_t stream) {
    const float* x   = (const float*)d_in[0];
    const int*   ei  = (const int*)d_in[1];
    const int*   bat = (const int*)d_in[2];
    const float* w1s = (const float*)d_in[3];
    const float* b1s = (const float*)d_in[4];
    const float* w1d = (const float*)d_in[5];
    const float* b1d = (const float*)d_in[6];
    const float* w2s = (const float*)d_in[7];
    const float* b2s = (const float*)d_in[8];
    const float* w2d = (const float*)d_in[9];
    const float* b2d = (const float*)d_in[10];
    const float* w3s = (const float*)d_in[11];
    const float* b3s = (const float*)d_in[12];
    const float* w3d = (const float*)d_in[13];
    const float* b3d = (const float*)d_in[14];
    const float* wl1 = (const float*)d_in[15];
    const float* bl1 = (const float*)d_in[16];
    const float* wl2 = (const float*)d_in[17];
    const float* bl2 = (const float*)d_in[18];
    float* out = (float*)d_out;

    // Workspace. bufP (25.6MB) = bkt region (bkt dead before layer1 agg).
    // bufQ (25.6MB): first half doubles as xh (dead before layer2 agg writes).
    char* p = (char*)d_ws;
    int*   deg_out = (int*)p;              p += N_NODES * 4;
    int*   deg_in  = (int*)p;              p += N_NODES * 4;
    int*   rowptrP = (int*)p;              p += N_NODES * 4;
    int*   colptrP = (int*)p;              p += N_NODES * 4;
    float* r_out   = (float*)p;            p += N_NODES * 4;
    float* r_in    = (float*)p;            p += N_NODES * 4;
    int*   cntTabA = (int*)p;              p += (size_t)NB * NBLK * 4;
    int*   cntTabT = (int*)p;              p += (size_t)NB * NBLK * 4;
    int*   totTab  = (int*)p;              p += 1024 * 4;
    int*   bktStartA = (int*)p;            p += 512 * 4;
    int*   bktStartT = (int*)p;            p += 512 * 4;
    int*   padSum  = (int*)p;              p += 1024 * 4;
    int*   padStart = (int*)p;             p += 1024 * 4;
    int2*  recA    = (int2*)p;             p += (size_t)EPAD * 8;
    int2*  recT    = (int2*)p;             p += (size_t)EPAD * 8;
    char*  bufP    = p;                    // 25.6MB: bktA | bktT during prep
    int2*  bktA    = (int2*)p;
    int2*  bktT    = (int2*)(p + (size_t)N_EDGES * 8);
    p += 2 * (size_t)N_EDGES * 8;
    char*  bufQ    = p;                    // 25.6MB: xh in first half
    h16*   xh      = (h16*)p;
    p += 2 * (size_t)N_EDGES * 8;
    unsigned* g    = (unsigned*)p;         p += NGRAPH * HDIM * 4;
    h16*   WT      = (h16*)p;              p += 3 * 8192 * 2;
    float* bc      = (float*)p;            p += 3 * 64 * 4;

    hipMemsetAsync(g, 0, NGRAPH * HDIM * 4, stream);

    cast_kernel<<<(N_NODES * 16 + 255) / 256, 256, 0, stream>>>(
        (const float4*)x, (h16x4*)xh);
    dim3 gw(32, 3);
    wprep_kernel<<<gw, 256, 0, stream>>>(w1s, w1d, w2s, w2d, w3s, w3d,
                                         b1s, b1d, b2s, b2d, b3s, b3d, WT, bc);

    bucket_count<<<NBLK, 512, 0, stream>>>(ei, cntTabA, cntTabT);
    dim3 gb2(NB, 2);
    chunk_scan<<<gb2, 256, 0, stream>>>(cntTabA, cntTabT, totTab);
    start_scan<<<1, 512, 0, stream>>>(totTab, bktStartA, bktStartT);
    bucketize_write<<<NBLK, 512, 0, stream>>>(ei, cntTabA, cntTabT,
                                              bktStartA, bktStartT, bktA, bktT);

    dim3 gb(NB, 2);
    bucket_deg<<<gb, 256, 0, stream>>>(bktStartA, bktStartT, bktA, bktT,
                                       deg_out, deg_in, r_out, r_in, padSum);
    pad_scan<<<1, 512, 0, stream>>>(padSum, padStart);
    node_ptr<<<gb, 256, 0, stream>>>(padStart, deg_out, deg_in, rowptrP, colptrP);
    bucket_scatter<<<gb, 512, 0, stream>>>(
        rowptrP, colptrP, r_out, r_in, bktStartA, bktStartT, bktA, bktT, recA, recT);

    const int agrid = N_NODES / BLK_NODES;
    // Layer 1: xh (128B rows) -> bufP
    agg_kernel<<<agrid, 512, 0, stream>>>((const char*)xh, bufP, 0,
                                          rowptrP, deg_out, recA, colptrP, deg_in, recT);
    gemm_kernel<<<256, 256, 0, stream>>>(bufP, WT, bc);
    // Layer 2: bufP (256B rows) -> bufQ
    agg_kernel<<<agrid, 512, 0, stream>>>(bufP, bufQ, 1,
                                          rowptrP, deg_out, recA, colptrP, deg_in, recT);
    gemm_kernel<<<256, 256, 0, stream>>>(bufQ, WT + 8192, bc + 64);
    // Layer 3: bufQ -> bufP
    agg_kernel<<<agrid, 512, 0, stream>>>(bufQ, bufP, 1,
                                          rowptrP, deg_out, recA, colptrP, deg_in, recT);
    gemm_kernel<<<256, 256, 0, stream>>>(bufP, WT + 16384, bc + 128);

    const int pool_threads = (N_NODES / 16) * 64;   // 400000
    pool_kernel<<<(pool_threads + 255) / 256, 256, 0, stream>>>((const h16*)bufP, bat, g);

    mlp_kernel<<<1, 64, 0, stream>>>(g, wl1, bl1, wl2, bl2, out);
}

// Round 13
// 493.186 us; speedup vs baseline: 1.4117x; 1.0235x over previous
//
#include <hip/hip_runtime.h>

// Problem constants
#define N_NODES 100000
#define N_EDGES 1600000
#define EPAD    (N_EDGES + N_NODES)      // padded record capacity (even starts)
#define HDIM    64
#define NGRAPH  64
#define BW      256                      // bucket width (nodes); shift = 8
#define NB      391                      // ceil(N_NODES / BW)
#define NBLK    256                      // edge-pass blocks
#define CHUNK   ((N_EDGES + NBLK - 1) / NBLK)
#define MTILES  (N_NODES / 16)           // 6250 GEMM m-tiles

// native fp16, no hip_fp16 header
typedef _Float16 h16;
typedef _Float16 h16x4 __attribute__((ext_vector_type(4)));
typedef _Float16 h16x8 __attribute__((ext_vector_type(8)));
typedef float    f32x4 __attribute__((ext_vector_type(4)));

// ----------------------------------------- K1: per-(block,bucket) edge counts
__global__ __launch_bounds__(512) void bucket_count(const int* __restrict__ ei,
                                                    int* __restrict__ cntTabA,
                                                    int* __restrict__ cntTabT) {
    __shared__ int cA[NB], cT[NB];
    const int tid = threadIdx.x;
    for (int i = tid; i < NB; i += 512) { cA[i] = 0; cT[i] = 0; }
    __syncthreads();
    const int e0 = blockIdx.x * CHUNK, e1 = min(e0 + CHUNK, N_EDGES);
    for (int e = e0 + tid; e < e1; e += 512) {
        int r = ei[e];
        int c = ei[N_EDGES + e];
        atomicAdd(&cA[r >> 8], 1);
        atomicAdd(&cT[c >> 8], 1);
    }
    __syncthreads();
    for (int b = tid; b < NB; b += 512) {
        cntTabA[b * NBLK + blockIdx.x] = cA[b];
        cntTabT[b * NBLK + blockIdx.x] = cT[b];
    }
}

// ---------------- K2a: per-bucket LDS scan of the 256 per-block counts
__global__ __launch_bounds__(256) void chunk_scan(int* __restrict__ cntTabA,
                                                  int* __restrict__ cntTabT,
                                                  int* __restrict__ tot) {
    __shared__ int s[256];
    const int b = blockIdx.x, d = blockIdx.y, tid = threadIdx.x;
    int* tab = d ? cntTabT : cntTabA;
    int v = tab[b * NBLK + tid];
    s[tid] = v;
    __syncthreads();
    for (int off = 1; off < 256; off <<= 1) {
        int t = (tid >= off) ? s[tid - off] : 0;
        __syncthreads();
        s[tid] += t;
        __syncthreads();
    }
    tab[b * NBLK + tid] = s[tid] - v;       // exclusive within bucket
    if (tid == 255) tot[d * 512 + b] = s[255];
}

// ---------------- K2b: bucket-start scan (both dirs, one block, parallel)
__global__ __launch_bounds__(512) void start_scan(const int* __restrict__ tot,
                                                  int* __restrict__ bktStartA,
                                                  int* __restrict__ bktStartT) {
    __shared__ int s[512];
    const int tid = threadIdx.x;
    int v = (tid < NB) ? tot[tid] : 0;
    s[tid] = v;
    __syncthreads();
    for (int off = 1; off < 512; off <<= 1) {
        int t = (tid >= off) ? s[tid - off] : 0;
        __syncthreads();
        s[tid] += t;
        __syncthreads();
    }
    if (tid < NB) bktStartA[tid] = s[tid] - v;
    if (tid == 0) bktStartA[NB] = N_EDGES;
    __syncthreads();
    int v2 = (tid < NB) ? tot[512 + tid] : 0;
    s[tid] = v2;
    __syncthreads();
    for (int off = 1; off < 512; off <<= 1) {
        int t = (tid >= off) ? s[tid - off] : 0;
        __syncthreads();
        s[tid] += t;
        __syncthreads();
    }
    if (tid < NB) bktStartT[tid] = s[tid] - v2;
    if (tid == 0) bktStartT[NB] = N_EDGES;
}

// --------------------------- K3: bucketize write (bases pre-reserved)
__global__ __launch_bounds__(512) void bucketize_write(const int* __restrict__ ei,
                                                       const int* __restrict__ cntTabA,
                                                       const int* __restrict__ cntTabT,
                                                       const int* __restrict__ bktStartA,
                                                       const int* __restrict__ bktStartT,
                                                       int2* __restrict__ bktA,
                                                       int2* __restrict__ bktT) {
    __shared__ int bA[NB], bT[NB];
    const int tid = threadIdx.x;
    for (int i = tid; i < NB; i += 512) {
        bA[i] = bktStartA[i] + cntTabA[i * NBLK + blockIdx.x];
        bT[i] = bktStartT[i] + cntTabT[i * NBLK + blockIdx.x];
    }
    __syncthreads();
    const int e0 = blockIdx.x * CHUNK, e1 = min(e0 + CHUNK, N_EDGES);
    for (int e = e0 + tid; e < e1; e += 512) {
        int r = ei[e];
        int c = ei[N_EDGES + e];
        int pA = atomicAdd(&bA[r >> 8], 1);
        bktA[pA] = make_int2(r, c);          // (target, source)
        int pT = atomicAdd(&bT[c >> 8], 1);
        bktT[pT] = make_int2(c, r);          // (target, source)
    }
}

// ------------------- K4: per-bucket degrees + rsqrt norms + padded-size reduce
__global__ __launch_bounds__(256) void bucket_deg(const int* __restrict__ bktStartA,
                                                  const int* __restrict__ bktStartT,
                                                  const int2* __restrict__ bktA,
                                                  const int2* __restrict__ bktT,
                                                  int* __restrict__ deg_out,
                                                  int* __restrict__ deg_in,
                                                  float* __restrict__ r_out,
                                                  float* __restrict__ r_in,
                                                  int* __restrict__ padSum) {
    __shared__ int c[BW];
    __shared__ int red[256];
    const int b = blockIdx.x, d = blockIdx.y, tid = threadIdx.x;
    const int* bs = d ? bktStartT : bktStartA;
    const int2* bkt = d ? bktT : bktA;
    int* deg = d ? deg_in : deg_out;
    float* rr = d ? r_in : r_out;
    const int node0 = b * BW;
    c[tid] = 0;
    __syncthreads();
    const int i0 = bs[b], i1 = bs[b + 1];
    for (int i = i0 + tid; i < i1; i += 256) atomicAdd(&c[bkt[i].x - node0], 1);
    __syncthreads();
    int n = node0 + tid, dg = c[tid], pad = 0;
    if (n < N_NODES) {
        deg[n] = dg;
        rr[n] = dg > 0 ? rsqrtf((float)dg) : 0.0f;
        pad = dg + (dg & 1);
    }
    red[tid] = pad;
    __syncthreads();
    for (int off = 128; off > 0; off >>= 1) {
        if (tid < off) red[tid] += red[tid + off];
        __syncthreads();
    }
    if (tid == 0) padSum[d * 512 + b] = red[0];
}

// ---------------- K5: padded bucket-start scan (both dirs, one block, parallel)
__global__ __launch_bounds__(512) void pad_scan(const int* __restrict__ padSum,
                                                int* __restrict__ padStart) {
    __shared__ int s[512];
    const int tid = threadIdx.x;
    int v = (tid < NB) ? padSum[tid] : 0;
    s[tid] = v;
    __syncthreads();
    for (int off = 1; off < 512; off <<= 1) {
        int t = (tid >= off) ? s[tid - off] : 0;
        __syncthreads();
        s[tid] += t;
        __syncthreads();
    }
    if (tid < NB) padStart[tid] = s[tid] - v;
    __syncthreads();
    int v2 = (tid < NB) ? padSum[512 + tid] : 0;
    s[tid] = v2;
    __syncthreads();
    for (int off = 1; off < 512; off <<= 1) {
        int t = (tid >= off) ? s[tid - off] : 0;
        __syncthreads();
        s[tid] += t;
        __syncthreads();
    }
    if (tid < NB) padStart[512 + tid] = s[tid] - v2;
}

// ----------------------- K6: per-node padded CSR offsets (per-bucket LDS scan)
__global__ __launch_bounds__(256) void node_ptr(const int* __restrict__ padStart,
                                                const int* __restrict__ deg_out,
                                                const int* __restrict__ deg_in,
                                                int* __restrict__ rowptrP,
                                                int* __restrict__ colptrP) {
    __shared__ int s[256];
    const int b = blockIdx.x, d = blockIdx.y, tid = threadIdx.x;
    const int* deg = d ? deg_in : deg_out;
    int* ptr = d ? colptrP : rowptrP;
    int n = b * BW + tid;
    int pad = 0;
    if (n < N_NODES) { int dg = deg[n]; pad = dg + (dg & 1); }
    s[tid] = pad;
    __syncthreads();
    for (int off = 1; off < 256; off <<= 1) {
        int t = (tid >= off) ? s[tid - off] : 0;
        __syncthreads();
        s[tid] += t;
        __syncthreads();
    }
    if (n < N_NODES) ptr[n] = padStart[d * 512 + b] + s[tid] - pad;
}

// ------------------------------------- K7: within-bucket counting scatter
// record payload: (src<<7, w fp32 bits)
__global__ __launch_bounds__(512) void bucket_scatter(
        const int* __restrict__ rowptrP, const int* __restrict__ colptrP,
        const float* __restrict__ r_out, const float* __restrict__ r_in,
        const int* __restrict__ bktStartA, const int* __restrict__ bktStartT,
        const int2* __restrict__ bktA, const int2* __restrict__ bktT,
        int2* __restrict__ recA, int2* __restrict__ recT) {
    __shared__ int cur[BW];
    __shared__ float rwt[BW];
    const int b = blockIdx.x, d = blockIdx.y, tid = threadIdx.x;
    const int* ptr = d ? colptrP : rowptrP;
    const float* rt = d ? r_in : r_out;       // target-side scale (bucket-local)
    const float* rs = d ? r_out : r_in;       // source-side scale (gathered)
    const int* bs = d ? bktStartT : bktStartA;
    const int2* bkt = d ? bktT : bktA;
    int2* rec = d ? recT : recA;
    const int node0 = b * BW;
    if (tid < BW) {
        int n = node0 + tid;
        cur[tid] = (n < N_NODES) ? ptr[n] : 0;
        rwt[tid] = (n < N_NODES) ? rt[n] : 0.0f;
    }
    __syncthreads();
    const int i0 = bs[b], i1 = bs[b + 1];
    for (int i = i0 + tid; i < i1; i += 512) {
        int2 e = bkt[i];
        float w = rwt[e.x - node0] * rs[e.y];
        int p = atomicAdd(&cur[e.x - node0], 1);
        rec[p] = make_int2(e.y << 7, __float_as_int(w));
    }
}

// ---------------------------------------------------- x -> fp16 cast
__global__ __launch_bounds__(256) void cast_kernel(const float4* __restrict__ x,
                                                   h16x4* __restrict__ xh) {
    int i = blockIdx.x * 256 + threadIdx.x;   // over N*64/4 float4s
    if (i < N_NODES * 16) {
        float4 v = x[i];
        h16x4 o;
        o.x = (h16)v.x; o.y = (h16)v.y; o.z = (h16)v.z; o.w = (h16)v.w;
        xh[i] = o;
    }
}

// ------------------------- weight prep: WT[l][f][k] = 0.5*Wcat^T fp16, bcat
__global__ __launch_bounds__(256) void wprep_kernel(
        const float* __restrict__ w1s, const float* __restrict__ w1d,
        const float* __restrict__ w2s, const float* __restrict__ w2d,
        const float* __restrict__ w3s, const float* __restrict__ w3d,
        const float* __restrict__ b1s, const float* __restrict__ b1d,
        const float* __restrict__ b2s, const float* __restrict__ b2d,
        const float* __restrict__ b3s, const float* __restrict__ b3d,
        h16* __restrict__ WT, float* __restrict__ bc) {
    const int l = blockIdx.y;
    const float* ws = l == 0 ? w1s : l == 1 ? w2s : w3s;
    const float* wd = l == 0 ? w1d : l == 1 ? w2d : w3d;
    int e = blockIdx.x * 256 + threadIdx.x;
    if (e < 8192) {
        int f = e >> 7, k = e & 127;
        float v = (k < 64) ? ws[k * 64 + f] : wd[(k - 64) * 64 + f];
        WT[l * 8192 + f * 128 + k] = (h16)(0.5f * v);
    }
    if (blockIdx.x == 0 && threadIdx.x < 64) {
        const float* bs = l == 0 ? b1s : l == 1 ? b2s : b3s;
        const float* bd = l == 0 ? b1d : l == 1 ? b2d : b3d;
        bc[l * 64 + threadIdx.x] = 0.5f * (bs[threadIdx.x] + bd[threadIdx.x]);
    }
}

// ------------------------------------------------ aggregation (LDS-free)
__device__ __forceinline__ void fma4h(float4& a, float w, h16x4 f) {
    a.x = fmaf(w, (float)f.x, a.x);
    a.y = fmaf(w, (float)f.y, a.y);
    a.z = fmaf(w, (float)f.z, a.z);
    a.w = fmaf(w, (float)f.w, a.w);
}

__device__ __forceinline__ float4 red_s(float4 v) {
    v.x += __shfl_xor(v.x, 16); v.y += __shfl_xor(v.y, 16);
    v.z += __shfl_xor(v.z, 16); v.w += __shfl_xor(v.w, 16);
    v.x += __shfl_xor(v.x, 32); v.y += __shfl_xor(v.y, 32);
    v.z += __shfl_xor(v.z, 32); v.w += __shfl_xor(v.w, 32);
    return v;
}

__device__ __forceinline__ h16x4 ld_h4(const char* __restrict__ p) {
    return *(const h16x4*)p;
}

// per-wave aggregation; lane (q,s): q = feature quad, s = edge-pair slot.
// records hold src<<7; sh=0 for 128B rows (xh), sh=1 for 256B rows (acc/h).
__device__ __forceinline__ float4 agg_dir(const char* __restrict__ hb,
                                          const int2* __restrict__ rec,
                                          int start, int deg, int q, int s, int sh) {
    float4 a0 = {0.f,0.f,0.f,0.f}, a1 = {0.f,0.f,0.f,0.f};
    float4 a2 = {0.f,0.f,0.f,0.f}, a3 = {0.f,0.f,0.f,0.f};
    const int4* rec4 = (const int4*)(rec + start);
    const int qb = q * 8;
    int k = 0;
    for (; k + 16 <= deg; k += 16) {
        int4 p0 = rec4[(k >> 1) + s];
        int4 p1 = rec4[(k >> 1) + 4 + s];
        h16x4 f0 = ld_h4(hb + (p0.x << sh) + qb);
        h16x4 f1 = ld_h4(hb + (p0.z << sh) + qb);
        h16x4 f2 = ld_h4(hb + (p1.x << sh) + qb);
        h16x4 f3 = ld_h4(hb + (p1.z << sh) + qb);
        fma4h(a0, __int_as_float(p0.y), f0);
        fma4h(a1, __int_as_float(p0.w), f1);
        fma4h(a2, __int_as_float(p1.y), f2);
        fma4h(a3, __int_as_float(p1.w), f3);
    }
    if (k + 8 <= deg) {
        int4 p = rec4[(k >> 1) + s];
        h16x4 f0 = ld_h4(hb + (p.x << sh) + qb);
        h16x4 f1 = ld_h4(hb + (p.z << sh) + qb);
        fma4h(a0, __int_as_float(p.y), f0);
        fma4h(a1, __int_as_float(p.w), f1);
        k += 8;
    }
    int r = deg - k;
    if (2 * s < r) {
        int4 p = rec4[(k >> 1) + s];
        h16x4 f0 = ld_h4(hb + (p.x << sh) + qb);
        fma4h(a2, __int_as_float(p.y), f0);
        if (2 * s + 1 < r) {
            h16x4 f1 = ld_h4(hb + (p.z << sh) + qb);
            fma4h(a3, __int_as_float(p.w), f1);
        }
    }
    a0.x += a1.x; a0.y += a1.y; a0.z += a1.z; a0.w += a1.w;
    a2.x += a3.x; a2.y += a3.y; a2.z += a3.z; a2.w += a3.w;
    a0.x += a2.x; a0.y += a2.y; a0.z += a2.z; a0.w += a2.w;
    return red_s(a0);
}

// no LDS, no barrier: ONE WAVE PER (node, dir). The two dirs write disjoint
// 128B halves of the acc row, so they are fully independent; finer wave
// granularity averages out degree variance (4-wave blocks).
__global__ __launch_bounds__(256) void agg_kernel(
        const char* __restrict__ h_in, char* __restrict__ acc_out, int sh,
        const int* __restrict__ rowptrP, const int* __restrict__ deg_out,
        const int2* __restrict__ recA,
        const int* __restrict__ colptrP, const int* __restrict__ deg_in,
        const int2* __restrict__ recT) {
    const int tid  = threadIdx.x;
    const int wid  = (blockIdx.x << 2) + (tid >> 6);   // global wave id
    const int lane = tid & 63;
    const int node = wid >> 1;
    const int dir  = wid & 1;
    const int q = lane & 15;
    const int s = lane >> 4;

    const int* ptr = dir ? colptrP : rowptrP;
    const int* deg = dir ? deg_in : deg_out;
    const int2* rec = dir ? recT : recA;

    float4 a = agg_dir(h_in, rec, ptr[node], deg[node], q, s, sh);
    if (s == 0) {
        h16x4 pk;
        pk.x = (h16)a.x; pk.y = (h16)a.y; pk.z = (h16)a.z; pk.w = (h16)a.w;
        *(h16x4*)(acc_out + (size_t)node * 256 + dir * 128 + q * 8) = pk;
    }
}

// --------------------------------------- GEMM via MFMA, h written in place
// acc rows are 256B ([128] fp16); h = ReLU(acc @ WT^T + bc) written into the
// first 128B of each row. A: m=lane&15, k=(lane>>4)*8+j; B from WT[n][k]
// (n=lane&15); D: col=lane&15, row=(lane>>4)*4+reg.
__global__ __launch_bounds__(256) void gemm_kernel(char* __restrict__ acc,
                                                   const h16* __restrict__ WT,
                                                   const float* __restrict__ bc) {
    const int lane = threadIdx.x & 63;
    const int wid = (blockIdx.x * 256 + threadIdx.x) >> 6;
    const int nW = gridDim.x * 4;
    const int m = lane & 15, t = lane >> 4;

    h16x8 bfrag[4][4];
    float bb[4];
#pragma unroll
    for (int nt = 0; nt < 4; nt++) {
        bb[nt] = bc[nt * 16 + m];
#pragma unroll
        for (int kk = 0; kk < 4; kk++)
            bfrag[nt][kk] = *(const h16x8*)(WT + (nt * 16 + m) * 128 + kk * 32 + t * 8);
    }

    for (int tile = wid; tile < MTILES; tile += nW) {
        char* arow = acc + (size_t)tile * 16 * 256;
        h16x8 afrag[4];
#pragma unroll
        for (int kk = 0; kk < 4; kk++)
            afrag[kk] = *(const h16x8*)(arow + m * 256 + kk * 64 + t * 16);
#pragma unroll
        for (int nt = 0; nt < 4; nt++) {
            f32x4 c = {0.f, 0.f, 0.f, 0.f};
#pragma unroll
            for (int kk = 0; kk < 4; kk++)
                c = __builtin_amdgcn_mfma_f32_16x16x32_f16(afrag[kk], bfrag[nt][kk], c, 0, 0, 0);
#pragma unroll
            for (int r = 0; r < 4; r++) {
                float o = fmaxf(c[r] + bb[nt], 0.0f);
                *(h16*)(arow + (t * 4 + r) * 256 + (nt * 16 + m) * 2) = (h16)o;
            }
        }
    }
}

// ---------------------------------------------------------------- max pool
// h rows live in acc buffer: 128 halves per row (first 64 are h)
__global__ __launch_bounds__(256) void pool_kernel(const h16* __restrict__ h,
                                                   const int* __restrict__ batch,
                                                   unsigned* __restrict__ g) {
    int t = blockIdx.x * 256 + threadIdx.x;
    const int ngroups = N_NODES / 16;   // 6250
    if (t >= ngroups * 64) return;
    int f = t & 63;
    int n0 = (t >> 6) * 16;
    int curg = batch[n0];
    float m = 0.0f;                      // post-ReLU values are >= 0
    for (int n = n0; n < n0 + 16; n++) {
        int b = batch[n];
        if (b != curg) {
            atomicMax(&g[curg * HDIM + f], __float_as_uint(m));
            curg = b;
            m = 0.0f;
        }
        m = fmaxf(m, (float)h[(size_t)n * 128 + f]);
    }
    atomicMax(&g[curg * HDIM + f], __float_as_uint(m));
}

// -------------------------------------------------------------------- MLP head
__global__ __launch_bounds__(64) void mlp_kernel(const unsigned* __restrict__ g,
                                                 const float* __restrict__ wl1,
                                                 const float* __restrict__ bl1,
                                                 const float* __restrict__ wl2,
                                                 const float* __restrict__ bl2,
                                                 float* __restrict__ out) {
    int t = threadIdx.x;   // graph index, one block of 64
    float gv[HDIM];
#pragma unroll
    for (int k = 0; k < HDIM; k++) gv[k] = __uint_as_float(g[t * HDIM + k]);
    float o = bl2[0];
#pragma unroll
    for (int j = 0; j < 5; j++) {
        float hj = bl1[j];
#pragma unroll
        for (int k = 0; k < HDIM; k++) hj += gv[k] * wl1[k * 5 + j];
        hj = fmaxf(hj, 0.0f);
        o += hj * wl2[j];
    }
    out[t] = o;
}

// ------------------------------------------------------------------- launch
extern "C" void kernel_launch(void* const* d_in, const int* in_sizes, int n_in,
                              void* d_out, int out_size, void* d_ws, size_t ws_size,
                              hipStream_t stream) {
    const float* x   = (const float*)d_in[0];
    const int*   ei  = (const int*)d_in[1];
    const int*   bat = (const int*)d_in[2];
    const float* w1s = (const float*)d_in[3];
    const float* b1s = (const float*)d_in[4];
    const float* w1d = (const float*)d_in[5];
    const float* b1d = (const float*)d_in[6];
    const float* w2s = (const float*)d_in[7];
    const float* b2s = (const float*)d_in[8];
    const float* w2d = (const float*)d_in[9];
    const float* b2d = (const float*)d_in[10];
    const float* w3s = (const float*)d_in[11];
    const float* b3s = (const float*)d_in[12];
    const float* w3d = (const float*)d_in[13];
    const float* b3d = (const float*)d_in[14];
    const float* wl1 = (const float*)d_in[15];
    const float* bl1 = (const float*)d_in[16];
    const float* wl2 = (const float*)d_in[17];
    const float* bl2 = (const float*)d_in[18];
    float* out = (float*)d_out;

    // Workspace. bufP (25.6MB) = bkt region (bkt dead before layer1 agg).
    // bufQ (25.6MB): first half doubles as xh (dead before layer2 agg writes).
    char* p = (char*)d_ws;
    int*   deg_out = (int*)p;              p += N_NODES * 4;
    int*   deg_in  = (int*)p;              p += N_NODES * 4;
    int*   rowptrP = (int*)p;              p += N_NODES * 4;
    int*   colptrP = (int*)p;              p += N_NODES * 4;
    float* r_out   = (float*)p;            p += N_NODES * 4;
    float* r_in    = (float*)p;            p += N_NODES * 4;
    int*   cntTabA = (int*)p;              p += (size_t)NB * NBLK * 4;
    int*   cntTabT = (int*)p;              p += (size_t)NB * NBLK * 4;
    int*   totTab  = (int*)p;              p += 1024 * 4;
    int*   bktStartA = (int*)p;            p += 512 * 4;
    int*   bktStartT = (int*)p;            p += 512 * 4;
    int*   padSum  = (int*)p;              p += 1024 * 4;
    int*   padStart = (int*)p;             p += 1024 * 4;
    int2*  recA    = (int2*)p;             p += (size_t)EPAD * 8;
    int2*  recT    = (int2*)p;             p += (size_t)EPAD * 8;
    char*  bufP    = p;                    // 25.6MB: bktA | bktT during prep
    int2*  bktA    = (int2*)p;
    int2*  bktT    = (int2*)(p + (size_t)N_EDGES * 8);
    p += 2 * (size_t)N_EDGES * 8;
    char*  bufQ    = p;                    // 25.6MB: xh in first half
    h16*   xh      = (h16*)p;
    p += 2 * (size_t)N_EDGES * 8;
    unsigned* g    = (unsigned*)p;         p += NGRAPH * HDIM * 4;
    h16*   WT      = (h16*)p;              p += 3 * 8192 * 2;
    float* bc      = (float*)p;            p += 3 * 64 * 4;

    hipMemsetAsync(g, 0, NGRAPH * HDIM * 4, stream);

    cast_kernel<<<(N_NODES * 16 + 255) / 256, 256, 0, stream>>>(
        (const float4*)x, (h16x4*)xh);
    dim3 gw(32, 3);
    wprep_kernel<<<gw, 256, 0, stream>>>(w1s, w1d, w2s, w2d, w3s, w3d,
                                         b1s, b1d, b2s, b2d, b3s, b3d, WT, bc);

    bucket_count<<<NBLK, 512, 0, stream>>>(ei, cntTabA, cntTabT);
    dim3 gb2(NB, 2);
    chunk_scan<<<gb2, 256, 0, stream>>>(cntTabA, cntTabT, totTab);
    start_scan<<<1, 512, 0, stream>>>(totTab, bktStartA, bktStartT);
    bucketize_write<<<NBLK, 512, 0, stream>>>(ei, cntTabA, cntTabT,
                                              bktStartA, bktStartT, bktA, bktT);

    dim3 gb(NB, 2);
    bucket_deg<<<gb, 256, 0, stream>>>(bktStartA, bktStartT, bktA, bktT,
                                       deg_out, deg_in, r_out, r_in, padSum);
    pad_scan<<<1, 512, 0, stream>>>(padSum, padStart);
    node_ptr<<<gb, 256, 0, stream>>>(padStart, deg_out, deg_in, rowptrP, colptrP);
    bucket_scatter<<<gb, 512, 0, stream>>>(
        rowptrP, colptrP, r_out, r_in, bktStartA, bktStartT, bktA, bktT, recA, recT);

    const int agrid = N_NODES * 2 / 4;    // one wave per (node,dir), 4 waves/block
    // Layer 1: xh (128B rows) -> bufP
    agg_kernel<<<agrid, 256, 0, stream>>>((const char*)xh, bufP, 0,
                                          rowptrP, deg_out, recA, colptrP, deg_in, recT);
    gemm_kernel<<<256, 256, 0, stream>>>(bufP, WT, bc);
    // Layer 2: bufP (256B rows) -> bufQ
    agg_kernel<<<agrid, 256, 0, stream>>>(bufP, bufQ, 1,
                                          rowptrP, deg_out, recA, colptrP, deg_in, recT);
    gemm_kernel<<<256, 256, 0, stream>>>(bufQ, WT + 8192, bc + 64);
    // Layer 3: bufQ -> bufP
    agg_kernel<<<agrid, 256, 0, stream>>>(bufQ, bufP, 1,
                                          rowptrP, deg_out, recA, colptrP, deg_in, recT);
    gemm_kernel<<<256, 256, 0, stream>>>(bufP, WT + 16384, bc + 128);

    const int pool_threads = (N_NODES / 16) * 64;   // 400000
    pool_kernel<<<(pool_threads + 255) / 256, 256, 0, stream>>>((const h16*)bufP, bat, g);

    mlp_kernel<<<1, 64, 0, stream>>>(g, wl1, bl1, wl2, bl2, out);
}

// Round 14
// 488.953 us; speedup vs baseline: 1.4239x; 1.0087x over previous
//
#include <hip/hip_runtime.h>

// Problem constants
#define N_NODES 100000
#define N_EDGES 1600000
#define EPAD    (N_EDGES + NB * BW)      // rec capacity w/ per-bucket slack
#define HDIM    64
#define NGRAPH  64
#define BW      256                      // bucket width (nodes); shift = 8
#define NB      391                      // ceil(N_NODES / BW)
#define NBLK    256                      // edge-pass blocks
#define CHUNK   ((N_EDGES + NBLK - 1) / NBLK)
#define MTILES  (N_NODES / 16)           // 6250 GEMM m-tiles

// native fp16, no hip_fp16 header
typedef _Float16 h16;
typedef _Float16 h16x4 __attribute__((ext_vector_type(4)));
typedef _Float16 h16x8 __attribute__((ext_vector_type(8)));
typedef float    f32x4 __attribute__((ext_vector_type(4)));

// ----------------------------------------- K1: per-(block,bucket) edge counts
__global__ __launch_bounds__(512) void bucket_count(const int* __restrict__ ei,
                                                    int* __restrict__ cntTabA,
                                                    int* __restrict__ cntTabT) {
    __shared__ int cA[NB], cT[NB];
    const int tid = threadIdx.x;
    for (int i = tid; i < NB; i += 512) { cA[i] = 0; cT[i] = 0; }
    __syncthreads();
    const int e0 = blockIdx.x * CHUNK, e1 = min(e0 + CHUNK, N_EDGES);
    for (int e = e0 + tid; e < e1; e += 512) {
        int r = ei[e];
        int c = ei[N_EDGES + e];
        atomicAdd(&cA[r >> 8], 1);
        atomicAdd(&cT[c >> 8], 1);
    }
    __syncthreads();
    for (int b = tid; b < NB; b += 512) {
        cntTabA[b * NBLK + blockIdx.x] = cA[b];
        cntTabT[b * NBLK + blockIdx.x] = cT[b];
    }
}

// ---------------- K2a: per-bucket LDS scan of the 256 per-block counts
__global__ __launch_bounds__(256) void chunk_scan(int* __restrict__ cntTabA,
                                                  int* __restrict__ cntTabT,
                                                  int* __restrict__ tot) {
    __shared__ int s[256];
    const int b = blockIdx.x, d = blockIdx.y, tid = threadIdx.x;
    int* tab = d ? cntTabT : cntTabA;
    int v = tab[b * NBLK + tid];
    s[tid] = v;
    __syncthreads();
    for (int off = 1; off < 256; off <<= 1) {
        int t = (tid >= off) ? s[tid - off] : 0;
        __syncthreads();
        s[tid] += t;
        __syncthreads();
    }
    tab[b * NBLK + tid] = s[tid] - v;       // exclusive within bucket
    if (tid == 255) tot[d * 512 + b] = s[255];
}

// ---------------- K2b: bucket-start scan (both dirs, one block, parallel)
__global__ __launch_bounds__(512) void start_scan(const int* __restrict__ tot,
                                                  int* __restrict__ bktStartA,
                                                  int* __restrict__ bktStartT) {
    __shared__ int s[512];
    const int tid = threadIdx.x;
    int v = (tid < NB) ? tot[tid] : 0;
    s[tid] = v;
    __syncthreads();
    for (int off = 1; off < 512; off <<= 1) {
        int t = (tid >= off) ? s[tid - off] : 0;
        __syncthreads();
        s[tid] += t;
        __syncthreads();
    }
    if (tid < NB) bktStartA[tid] = s[tid] - v;
    if (tid == 0) bktStartA[NB] = N_EDGES;
    __syncthreads();
    int v2 = (tid < NB) ? tot[512 + tid] : 0;
    s[tid] = v2;
    __syncthreads();
    for (int off = 1; off < 512; off <<= 1) {
        int t = (tid >= off) ? s[tid - off] : 0;
        __syncthreads();
        s[tid] += t;
        __syncthreads();
    }
    if (tid < NB) bktStartT[tid] = s[tid] - v2;
    if (tid == 0) bktStartT[NB] = N_EDGES;
}

// --------------------------- K3: bucketize write (bases pre-reserved)
__global__ __launch_bounds__(512) void bucketize_write(const int* __restrict__ ei,
                                                       const int* __restrict__ cntTabA,
                                                       const int* __restrict__ cntTabT,
                                                       const int* __restrict__ bktStartA,
                                                       const int* __restrict__ bktStartT,
                                                       int2* __restrict__ bktA,
                                                       int2* __restrict__ bktT) {
    __shared__ int bA[NB], bT[NB];
    const int tid = threadIdx.x;
    for (int i = tid; i < NB; i += 512) {
        bA[i] = bktStartA[i] + cntTabA[i * NBLK + blockIdx.x];
        bT[i] = bktStartT[i] + cntTabT[i * NBLK + blockIdx.x];
    }
    __syncthreads();
    const int e0 = blockIdx.x * CHUNK, e1 = min(e0 + CHUNK, N_EDGES);
    for (int e = e0 + tid; e < e1; e += 512) {
        int r = ei[e];
        int c = ei[N_EDGES + e];
        int pA = atomicAdd(&bA[r >> 8], 1);
        bktA[pA] = make_int2(r, c);          // (target, source)
        int pT = atomicAdd(&bT[c >> 8], 1);
        bktT[pT] = make_int2(c, r);          // (target, source)
    }
}

// ----- K4: per-bucket degrees + rsqrt + padded node ptrs (slack allocation)
// rec region for bucket b starts at bktStart[b] + b*BW (pad slack <= BW),
// so node offsets need no cross-bucket scan.
__global__ __launch_bounds__(256) void bucket_deg_ptr(
        const int* __restrict__ bktStartA, const int* __restrict__ bktStartT,
        const int2* __restrict__ bktA, const int2* __restrict__ bktT,
        int* __restrict__ deg_out, int* __restrict__ deg_in,
        float* __restrict__ r_out, float* __restrict__ r_in,
        int* __restrict__ rowptrP, int* __restrict__ colptrP) {
    __shared__ int c[BW];
    __shared__ int s[256];
    const int b = blockIdx.x, d = blockIdx.y, tid = threadIdx.x;
    const int* bs = d ? bktStartT : bktStartA;
    const int2* bkt = d ? bktT : bktA;
    int* deg = d ? deg_in : deg_out;
    float* rr = d ? r_in : r_out;
    int* ptr = d ? colptrP : rowptrP;
    const int node0 = b * BW;
    c[tid] = 0;
    __syncthreads();
    const int i0 = bs[b], i1 = bs[b + 1];
    for (int i = i0 + tid; i < i1; i += 256) atomicAdd(&c[bkt[i].x - node0], 1);
    __syncthreads();
    int n = node0 + tid, dg = c[tid];
    int pad = dg + (dg & 1);
    if (n < N_NODES) {
        deg[n] = dg;
        rr[n] = dg > 0 ? rsqrtf((float)dg) : 0.0f;
    } else pad = 0;
    s[tid] = pad;
    __syncthreads();
    for (int off = 1; off < 256; off <<= 1) {
        int t = (tid >= off) ? s[tid - off] : 0;
        __syncthreads();
        s[tid] += t;
        __syncthreads();
    }
    if (n < N_NODES) ptr[n] = i0 + b * BW + (s[tid] - pad);
}

// ------------------------------------- K7: within-bucket counting scatter
// record payload: (src<<7, w fp32 bits)
__global__ __launch_bounds__(512) void bucket_scatter(
        const int* __restrict__ rowptrP, const int* __restrict__ colptrP,
        const float* __restrict__ r_out, const float* __restrict__ r_in,
        const int* __restrict__ bktStartA, const int* __restrict__ bktStartT,
        const int2* __restrict__ bktA, const int2* __restrict__ bktT,
        int2* __restrict__ recA, int2* __restrict__ recT) {
    __shared__ int cur[BW];
    __shared__ float rwt[BW];
    const int b = blockIdx.x, d = blockIdx.y, tid = threadIdx.x;
    const int* ptr = d ? colptrP : rowptrP;
    const float* rt = d ? r_in : r_out;       // target-side scale (bucket-local)
    const float* rs = d ? r_out : r_in;       // source-side scale (gathered)
    const int* bs = d ? bktStartT : bktStartA;
    const int2* bkt = d ? bktT : bktA;
    int2* rec = d ? recT : recA;
    const int node0 = b * BW;
    if (tid < BW) {
        int n = node0 + tid;
        cur[tid] = (n < N_NODES) ? ptr[n] : 0;
        rwt[tid] = (n < N_NODES) ? rt[n] : 0.0f;
    }
    __syncthreads();
    const int i0 = bs[b], i1 = bs[b + 1];
    for (int i = i0 + tid; i < i1; i += 512) {
        int2 e = bkt[i];
        float w = rwt[e.x - node0] * rs[e.y];
        int p = atomicAdd(&cur[e.x - node0], 1);
        rec[p] = make_int2(e.y << 7, __float_as_int(w));
    }
}

// ---------------------------------------- x -> fp16 cast (+ zero pooled g)
__global__ __launch_bounds__(256) void cast_kernel(const float4* __restrict__ x,
                                                   h16x4* __restrict__ xh,
                                                   unsigned* __restrict__ g) {
    if (blockIdx.x == 0) {
        for (int j = threadIdx.x; j < NGRAPH * HDIM; j += 256) g[j] = 0u;
    }
    int i = blockIdx.x * 256 + threadIdx.x;   // over N*64/4 float4s
    if (i < N_NODES * 16) {
        float4 v = x[i];
        h16x4 o;
        o.x = (h16)v.x; o.y = (h16)v.y; o.z = (h16)v.z; o.w = (h16)v.w;
        xh[i] = o;
    }
}

// ------------------------- weight prep: WT[l][f][k] = 0.5*Wcat^T fp16, bcat
__global__ __launch_bounds__(256) void wprep_kernel(
        const float* __restrict__ w1s, const float* __restrict__ w1d,
        const float* __restrict__ w2s, const float* __restrict__ w2d,
        const float* __restrict__ w3s, const float* __restrict__ w3d,
        const float* __restrict__ b1s, const float* __restrict__ b1d,
        const float* __restrict__ b2s, const float* __restrict__ b2d,
        const float* __restrict__ b3s, const float* __restrict__ b3d,
        h16* __restrict__ WT, float* __restrict__ bc) {
    const int l = blockIdx.y;
    const float* ws = l == 0 ? w1s : l == 1 ? w2s : w3s;
    const float* wd = l == 0 ? w1d : l == 1 ? w2d : w3d;
    int e = blockIdx.x * 256 + threadIdx.x;
    if (e < 8192) {
        int f = e >> 7, k = e & 127;
        float v = (k < 64) ? ws[k * 64 + f] : wd[(k - 64) * 64 + f];
        WT[l * 8192 + f * 128 + k] = (h16)(0.5f * v);
    }
    if (blockIdx.x == 0 && threadIdx.x < 64) {
        const float* bs = l == 0 ? b1s : l == 1 ? b2s : b3s;
        const float* bd = l == 0 ? b1d : l == 1 ? b2d : b3d;
        bc[l * 64 + threadIdx.x] = 0.5f * (bs[threadIdx.x] + bd[threadIdx.x]);
    }
}

// ------------------------------------------------ aggregation (LDS-free)
__device__ __forceinline__ void fma4h(float4& a, float w, h16x4 f) {
    a.x = fmaf(w, (float)f.x, a.x);
    a.y = fmaf(w, (float)f.y, a.y);
    a.z = fmaf(w, (float)f.z, a.z);
    a.w = fmaf(w, (float)f.w, a.w);
}

__device__ __forceinline__ float4 red_s(float4 v) {
    v.x += __shfl_xor(v.x, 16); v.y += __shfl_xor(v.y, 16);
    v.z += __shfl_xor(v.z, 16); v.w += __shfl_xor(v.w, 16);
    v.x += __shfl_xor(v.x, 32); v.y += __shfl_xor(v.y, 32);
    v.z += __shfl_xor(v.z, 32); v.w += __shfl_xor(v.w, 32);
    return v;
}

__device__ __forceinline__ h16x4 ld_h4(const char* __restrict__ p) {
    return *(const h16x4*)p;
}

// per-wave aggregation; lane (q,s): q = feature quad, s = edge-pair slot.
// records hold src<<7; sh=0 for 128B rows (xh), sh=1 for 256B rows (acc/h).
__device__ __forceinline__ float4 agg_dir(const char* __restrict__ hb,
                                          const int2* __restrict__ rec,
                                          int start, int deg, int q, int s, int sh) {
    float4 a0 = {0.f,0.f,0.f,0.f}, a1 = {0.f,0.f,0.f,0.f};
    float4 a2 = {0.f,0.f,0.f,0.f}, a3 = {0.f,0.f,0.f,0.f};
    const int4* rec4 = (const int4*)(rec + start);
    const int qb = q * 8;
    int k = 0;
    for (; k + 16 <= deg; k += 16) {
        int4 p0 = rec4[(k >> 1) + s];
        int4 p1 = rec4[(k >> 1) + 4 + s];
        h16x4 f0 = ld_h4(hb + (p0.x << sh) + qb);
        h16x4 f1 = ld_h4(hb + (p0.z << sh) + qb);
        h16x4 f2 = ld_h4(hb + (p1.x << sh) + qb);
        h16x4 f3 = ld_h4(hb + (p1.z << sh) + qb);
        fma4h(a0, __int_as_float(p0.y), f0);
        fma4h(a1, __int_as_float(p0.w), f1);
        fma4h(a2, __int_as_float(p1.y), f2);
        fma4h(a3, __int_as_float(p1.w), f3);
    }
    if (k + 8 <= deg) {
        int4 p = rec4[(k >> 1) + s];
        h16x4 f0 = ld_h4(hb + (p.x << sh) + qb);
        h16x4 f1 = ld_h4(hb + (p.z << sh) + qb);
        fma4h(a0, __int_as_float(p.y), f0);
        fma4h(a1, __int_as_float(p.w), f1);
        k += 8;
    }
    int r = deg - k;
    if (2 * s < r) {
        int4 p = rec4[(k >> 1) + s];
        h16x4 f0 = ld_h4(hb + (p.x << sh) + qb);
        fma4h(a2, __int_as_float(p.y), f0);
        if (2 * s + 1 < r) {
            h16x4 f1 = ld_h4(hb + (p.z << sh) + qb);
            fma4h(a3, __int_as_float(p.w), f1);
        }
    }
    a0.x += a1.x; a0.y += a1.y; a0.z += a1.z; a0.w += a1.w;
    a2.x += a3.x; a2.y += a3.y; a2.z += a3.z; a2.w += a3.w;
    a0.x += a2.x; a0.y += a2.y; a0.z += a2.z; a0.w += a2.w;
    return red_s(a0);
}

// no LDS, no barrier: one wave per (node, dir); dirs write disjoint halves.
__global__ __launch_bounds__(256) void agg_kernel(
        const char* __restrict__ h_in, char* __restrict__ acc_out, int sh,
        const int* __restrict__ rowptrP, const int* __restrict__ deg_out,
        const int2* __restrict__ recA,
        const int* __restrict__ colptrP, const int* __restrict__ deg_in,
        const int2* __restrict__ recT) {
    const int tid  = threadIdx.x;
    const int wid  = (blockIdx.x << 2) + (tid >> 6);   // global wave id
    const int lane = tid & 63;
    const int node = wid >> 1;
    const int dir  = wid & 1;
    const int q = lane & 15;
    const int s = lane >> 4;

    const int* ptr = dir ? colptrP : rowptrP;
    const int* deg = dir ? deg_in : deg_out;
    const int2* rec = dir ? recT : recA;

    float4 a = agg_dir(h_in, rec, ptr[node], deg[node], q, s, sh);
    if (s == 0) {
        h16x4 pk;
        pk.x = (h16)a.x; pk.y = (h16)a.y; pk.z = (h16)a.z; pk.w = (h16)a.w;
        *(h16x4*)(acc_out + (size_t)node * 256 + dir * 128 + q * 8) = pk;
    }
}

// --------------------------------------- GEMM via MFMA, h written in place
// acc rows are 256B ([128] fp16); h = ReLU(acc @ WT^T + bc) written into the
// first 128B of each row. Optional fused max-pool (layer 3): batch is sorted,
// so most 16-node tiles map to one graph -> shfl-reduce + 1 atomic per feat.
__global__ __launch_bounds__(256) void gemm_kernel(char* __restrict__ acc,
                                                   const h16* __restrict__ WT,
                                                   const float* __restrict__ bc,
                                                   const int* __restrict__ batch,
                                                   unsigned* __restrict__ g,
                                                   int do_pool) {
    const int lane = threadIdx.x & 63;
    const int wid = (blockIdx.x * 256 + threadIdx.x) >> 6;
    const int nW = gridDim.x * 4;
    const int m = lane & 15, t = lane >> 4;

    h16x8 bfrag[4][4];
    float bb[4];
#pragma unroll
    for (int nt = 0; nt < 4; nt++) {
        bb[nt] = bc[nt * 16 + m];
#pragma unroll
        for (int kk = 0; kk < 4; kk++)
            bfrag[nt][kk] = *(const h16x8*)(WT + (nt * 16 + m) * 128 + kk * 32 + t * 8);
    }

    for (int tile = wid; tile < MTILES; tile += nW) {
        char* arow = acc + (size_t)tile * 16 * 256;
        const int node0 = tile * 16;
        int b0 = 0, b15 = 0;
        if (do_pool) { b0 = batch[node0]; b15 = batch[node0 + 15]; }
        h16x8 afrag[4];
#pragma unroll
        for (int kk = 0; kk < 4; kk++)
            afrag[kk] = *(const h16x8*)(arow + m * 256 + kk * 64 + t * 16);
#pragma unroll
        for (int nt = 0; nt < 4; nt++) {
            f32x4 c = {0.f, 0.f, 0.f, 0.f};
#pragma unroll
            for (int kk = 0; kk < 4; kk++)
                c = __builtin_amdgcn_mfma_f32_16x16x32_f16(afrag[kk], bfrag[nt][kk], c, 0, 0, 0);
            float ov[4];
#pragma unroll
            for (int r = 0; r < 4; r++) {
                ov[r] = fmaxf(c[r] + bb[nt], 0.0f);
                *(h16*)(arow + (t * 4 + r) * 256 + (nt * 16 + m) * 2) = (h16)ov[r];
            }
            if (do_pool) {
                if (b0 == b15) {
                    float mx = fmaxf(fmaxf(ov[0], ov[1]), fmaxf(ov[2], ov[3]));
                    mx = fmaxf(mx, __shfl_xor(mx, 16));
                    mx = fmaxf(mx, __shfl_xor(mx, 32));
                    if (t == 0)
                        atomicMax(&g[b0 * HDIM + nt * 16 + m], __float_as_uint(mx));
                } else {
#pragma unroll
                    for (int r = 0; r < 4; r++)
                        atomicMax(&g[batch[node0 + t * 4 + r] * HDIM + nt * 16 + m],
                                  __float_as_uint(ov[r]));
                }
            }
        }
    }
}

// -------------------------------------------------------------------- MLP head
__global__ __launch_bounds__(64) void mlp_kernel(const unsigned* __restrict__ g,
                                                 const float* __restrict__ wl1,
                                                 const float* __restrict__ bl1,
                                                 const float* __restrict__ wl2,
                                                 const float* __restrict__ bl2,
                                                 float* __restrict__ out) {
    int t = threadIdx.x;   // graph index, one block of 64
    float gv[HDIM];
#pragma unroll
    for (int k = 0; k < HDIM; k++) gv[k] = __uint_as_float(g[t * HDIM + k]);
    float o = bl2[0];
#pragma unroll
    for (int j = 0; j < 5; j++) {
        float hj = bl1[j];
#pragma unroll
        for (int k = 0; k < HDIM; k++) hj += gv[k] * wl1[k * 5 + j];
        hj = fmaxf(hj, 0.0f);
        o += hj * wl2[j];
    }
    out[t] = o;
}

// ------------------------------------------------------------------- launch
extern "C" void kernel_launch(void* const* d_in, const int* in_sizes, int n_in,
                              void* d_out, int out_size, void* d_ws, size_t ws_size,
                              hipStream_t stream) {
    const float* x   = (const float*)d_in[0];
    const int*   ei  = (const int*)d_in[1];
    const int*   bat = (const int*)d_in[2];
    const float* w1s = (const float*)d_in[3];
    const float* b1s = (const float*)d_in[4];
    const float* w1d = (const float*)d_in[5];
    const float* b1d = (const float*)d_in[6];
    const float* w2s = (const float*)d_in[7];
    const float* b2s = (const float*)d_in[8];
    const float* w2d = (const float*)d_in[9];
    const float* b2d = (const float*)d_in[10];
    const float* w3s = (const float*)d_in[11];
    const float* b3s = (const float*)d_in[12];
    const float* w3d = (const float*)d_in[13];
    const float* b3d = (const float*)d_in[14];
    const float* wl1 = (const float*)d_in[15];
    const float* bl1 = (const float*)d_in[16];
    const float* wl2 = (const float*)d_in[17];
    const float* bl2 = (const float*)d_in[18];
    float* out = (float*)d_out;

    // Workspace. bufP (25.6MB) = bkt region (bkt dead before layer1 agg).
    // bufQ (25.6MB): first half doubles as xh (dead before layer2 agg writes).
    char* p = (char*)d_ws;
    int*   deg_out = (int*)p;              p += N_NODES * 4;
    int*   deg_in  = (int*)p;              p += N_NODES * 4;
    int*   rowptrP = (int*)p;              p += N_NODES * 4;
    int*   colptrP = (int*)p;              p += N_NODES * 4;
    float* r_out   = (float*)p;            p += N_NODES * 4;
    float* r_in    = (float*)p;            p += N_NODES * 4;
    int*   cntTabA = (int*)p;              p += (size_t)NB * NBLK * 4;
    int*   cntTabT = (int*)p;              p += (size_t)NB * NBLK * 4;
    int*   totTab  = (int*)p;              p += 1024 * 4;
    int*   bktStartA = (int*)p;            p += 512 * 4;
    int*   bktStartT = (int*)p;            p += 512 * 4;
    int2*  recA    = (int2*)p;             p += (size_t)EPAD * 8;
    int2*  recT    = (int2*)p;             p += (size_t)EPAD * 8;
    char*  bufP    = p;                    // 25.6MB: bktA | bktT during prep
    int2*  bktA    = (int2*)p;
    int2*  bktT    = (int2*)(p + (size_t)N_EDGES * 8);
    p += 2 * (size_t)N_EDGES * 8;
    char*  bufQ    = p;                    // 25.6MB: xh in first half
    h16*   xh      = (h16*)p;
    p += 2 * (size_t)N_EDGES * 8;
    unsigned* g    = (unsigned*)p;         p += NGRAPH * HDIM * 4;
    h16*   WT      = (h16*)p;              p += 3 * 8192 * 2;
    float* bc      = (float*)p;            p += 3 * 64 * 4;

    cast_kernel<<<(N_NODES * 16 + 255) / 256, 256, 0, stream>>>(
        (const float4*)x, (h16x4*)xh, g);
    dim3 gw(32, 3);
    wprep_kernel<<<gw, 256, 0, stream>>>(w1s, w1d, w2s, w2d, w3s, w3d,
                                         b1s, b1d, b2s, b2d, b3s, b3d, WT, bc);

    bucket_count<<<NBLK, 512, 0, stream>>>(ei, cntTabA, cntTabT);
    dim3 gb2(NB, 2);
    chunk_scan<<<gb2, 256, 0, stream>>>(cntTabA, cntTabT, totTab);
    start_scan<<<1, 512, 0, stream>>>(totTab, bktStartA, bktStartT);
    bucketize_write<<<NBLK, 512, 0, stream>>>(ei, cntTabA, cntTabT,
                                              bktStartA, bktStartT, bktA, bktT);

    dim3 gb(NB, 2);
    bucket_deg_ptr<<<gb, 256, 0, stream>>>(bktStartA, bktStartT, bktA, bktT,
                                           deg_out, deg_in, r_out, r_in,
                                           rowptrP, colptrP);
    bucket_scatter<<<gb, 512, 0, stream>>>(
        rowptrP, colptrP, r_out, r_in, bktStartA, bktStartT, bktA, bktT, recA, recT);

    const int agrid = N_NODES * 2 / 4;    // one wave per (node,dir), 4 waves/block
    // Layer 1: xh (128B rows) -> bufP
    agg_kernel<<<agrid, 256, 0, stream>>>((const char*)xh, bufP, 0,
                                          rowptrP, deg_out, recA, colptrP, deg_in, recT);
    gemm_kernel<<<256, 256, 0, stream>>>(bufP, WT, bc, bat, g, 0);
    // Layer 2: bufP (256B rows) -> bufQ
    agg_kernel<<<agrid, 256, 0, stream>>>(bufP, bufQ, 1,
                                          rowptrP, deg_out, recA, colptrP, deg_in, recT);
    gemm_kernel<<<256, 256, 0, stream>>>(bufQ, WT + 8192, bc + 64, bat, g, 0);
    // Layer 3: bufQ -> bufP, fused max-pool
    agg_kernel<<<agrid, 256, 0, stream>>>(bufQ, bufP, 1,
                                          rowptrP, deg_out, recA, colptrP, deg_in, recT);
    gemm_kernel<<<256, 256, 0, stream>>>(bufP, WT + 16384, bc + 128, bat, g, 1);

    mlp_kernel<<<1, 64, 0, stream>>>(g, wl1, bl1, wl2, bl2, out);
}